// Round 1
// baseline (2588.594 us; speedup 1.0000x reference)
//
#include <hip/hip_runtime.h>
#include <hip/hip_cooperative_groups.h>

namespace cg = cooperative_groups;

typedef __attribute__((ext_vector_type(8))) short short8;
typedef __attribute__((ext_vector_type(4))) float f32x4;
typedef __attribute__((ext_vector_type(8))) unsigned short ushort8;
typedef __attribute__((ext_vector_type(4))) unsigned short ushort4v;

__device__ __forceinline__ unsigned short f2bf(float f) {
  union { float f; unsigned u; } v; v.f = f;
  unsigned u = v.u;
  u += 0x7fffu + ((u >> 16) & 1u);
  return (unsigned short)(u >> 16);
}
__device__ __forceinline__ float sigm(float x) { return 1.f / (1.f + __expf(-x)); }
__device__ __forceinline__ float ftanh(float x) { return 1.f - 2.f / (__expf(2.f * x) + 1.f); }

// async global->LDS, 16B per lane. LDS dest is wave-uniform base + lane*16.
__device__ __forceinline__ void gl16(const unsigned short* g, unsigned short* l) {
  __builtin_amdgcn_global_load_lds((const __attribute__((address_space(1))) void*)g,
                                   (__attribute__((address_space(3))) void*)l, 16, 0, 0);
}

#define LSTR 40  // LDS row stride (elems): 32 data + 8 pad

// ---------------------------------------------------------------------------
// Prep: build bf16 transposed/permuted weights, zero state buffers.
// WcombT: (2048 rows n', 800 cols k) bf16. n' = j*4+gate  (orig col n = gate*512+j)
// Wk2T:   (320 rows n, 512 cols k) bf16. n<256->W_key, 256->W_g, 257..260->W_y
// WencT:  (128 rows n, 1024 cols k) bf16 = W_enc^T
// ---------------------------------------------------------------------------
__global__ void k_prep(const float* __restrict__ W_lstm, const float* __restrict__ U_lstm,
                       const float* __restrict__ W_enc, const float* __restrict__ W_key,
                       const float* __restrict__ W_g, const float* __restrict__ W_y,
                       const float* __restrict__ b_key, const float* __restrict__ b_g,
                       const float* __restrict__ b_y,
                       unsigned short* __restrict__ WcombT, unsigned short* __restrict__ Wk2T,
                       unsigned short* __restrict__ WencT, float* __restrict__ bias2,
                       unsigned short* __restrict__ xinA, unsigned short* __restrict__ xinB,
                       float* __restrict__ h, float* __restrict__ z_full) {
  const int N1 = 2048 * 800, N2 = 320 * 512, N3 = 128 * 1024, N4 = 320,
            N5 = 512 * 800, N7 = 512 * 512, N8 = 512 * 128;
  int i = blockIdx.x * 256 + threadIdx.x;
  if (i < N1) {
    int np = i / 800, k = i - np * 800;
    int j = np >> 2, gate = np & 3, n = gate * 512 + j;
    float v = 0.f;
    if (k < 257) v = W_lstm[k * 2048 + n];
    else if (k >= 288) v = U_lstm[(k - 288) * 2048 + n];
    WcombT[i] = f2bf(v);
    return;
  }
  i -= N1;
  if (i < N2) {
    int n = i / 512, k = i - n * 512;
    float v = 0.f;
    if (n < 256) v = W_key[k * 256 + n];
    else if (n == 256) v = W_g[k];
    else if (n < 261) v = W_y[k * 4 + (n - 257)];
    Wk2T[i] = f2bf(v);
    return;
  }
  i -= N2;
  if (i < N3) {
    int n = i / 1024, k = i - n * 1024;
    WencT[i] = f2bf(W_enc[k * 128 + n]);
    return;
  }
  i -= N3;
  if (i < N4) {
    float v = (i < 256) ? b_key[i] : (i == 256 ? b_g[0] : (i < 261 ? b_y[i - 257] : 0.f));
    bias2[i] = v;
    return;
  }
  i -= N4;
  if (i < N5) { xinA[i] = 0; return; }
  i -= N5;
  if (i < N5) { xinB[i] = 0; return; }
  i -= N5;
  if (i < N7) { h[i] = 0.f; return; }
  i -= N7;
  if (i < N8) {
    int b = i >> 7, z = i & 127;
    z_full[(b * 33 + 32) * 128 + z] = 0.f;  // null slot
  }
}

// ---------------------------------------------------------------------------
// Encoder GEMM: z = relu(x @ W_enc + b_enc). 64Mx128N tile per block, BK=32,
// K=1024, 512 threads (8 waves/CU for latency hiding), double-buffered.
// ---------------------------------------------------------------------------
__global__ __launch_bounds__(512) void k_enc(const float* __restrict__ x,
                                             const unsigned short* __restrict__ WencT,
                                             const float* __restrict__ b_enc,
                                             float* __restrict__ zbuf) {
  __shared__ __align__(16) unsigned short As[2][64 * LSTR];
  __shared__ __align__(16) unsigned short Bs[2][128 * LSTR];
  int tid = threadIdx.x;
  int m0 = blockIdx.x * 64;
  int lane = tid & 63, wid = tid >> 6;        // 8 waves
  int wm = (wid >> 2) * 32, wn = (wid & 3) * 32;
  int q = lane >> 4, r = lane & 15;
  int ldrowA = tid >> 3, ldcA = (tid & 7) * 4;  // A: 64x32 f32, 4/thread
  int ldrowB = tid >> 2, ldcB = (tid & 3) * 8;  // B: 128x32 bf16, 8/thread
  const float4* Ag = reinterpret_cast<const float4*>(x + (size_t)(m0 + ldrowA) * 1024);
  const uint4* Bg = reinterpret_cast<const uint4*>(WencT + (size_t)ldrowB * 1024);
  float4 ra = Ag[ldcA >> 2];
  uint4 rb = Bg[ldcB >> 3];
  f32x4 acc[2][2] = {};
  int s = 0;
  {
    ushort4v t4;
    t4[0] = f2bf(ra.x); t4[1] = f2bf(ra.y); t4[2] = f2bf(ra.z); t4[3] = f2bf(ra.w);
    *reinterpret_cast<ushort4v*>(&As[0][ldrowA * LSTR + ldcA]) = t4;
    *reinterpret_cast<uint4*>(&Bs[0][ldrowB * LSTR + ldcB]) = rb;
  }
  __syncthreads();
  for (int kk = 0; kk < 32; ++kk) {
    if (kk < 31) {
      int k0 = (kk + 1) * 32;
      ra = Ag[(k0 + ldcA) >> 2];
      rb = Bg[(k0 + ldcB) >> 3];
    }
    short8 a0 = *reinterpret_cast<const short8*>(&As[s][(wm + r) * LSTR + q * 8]);
    short8 a1 = *reinterpret_cast<const short8*>(&As[s][(wm + 16 + r) * LSTR + q * 8]);
    short8 b0 = *reinterpret_cast<const short8*>(&Bs[s][(wn + r) * LSTR + q * 8]);
    short8 b1 = *reinterpret_cast<const short8*>(&Bs[s][(wn + 16 + r) * LSTR + q * 8]);
    acc[0][0] = __builtin_amdgcn_mfma_f32_16x16x32_bf16(a0, b0, acc[0][0], 0, 0, 0);
    acc[0][1] = __builtin_amdgcn_mfma_f32_16x16x32_bf16(a0, b1, acc[0][1], 0, 0, 0);
    acc[1][0] = __builtin_amdgcn_mfma_f32_16x16x32_bf16(a1, b0, acc[1][0], 0, 0, 0);
    acc[1][1] = __builtin_amdgcn_mfma_f32_16x16x32_bf16(a1, b1, acc[1][1], 0, 0, 0);
    if (kk < 31) {
      ushort4v t4;
      t4[0] = f2bf(ra.x); t4[1] = f2bf(ra.y); t4[2] = f2bf(ra.z); t4[3] = f2bf(ra.w);
      *reinterpret_cast<ushort4v*>(&As[s ^ 1][ldrowA * LSTR + ldcA]) = t4;
      *reinterpret_cast<uint4*>(&Bs[s ^ 1][ldrowB * LSTR + ldcB]) = rb;
      s ^= 1;
    }
    __syncthreads();
  }
#pragma unroll
  for (int mt = 0; mt < 2; ++mt)
#pragma unroll
    for (int nt = 0; nt < 2; ++nt)
#pragma unroll
      for (int e = 0; e < 4; ++e) {
        int row = m0 + wm + mt * 16 + q * 4 + e;
        int col = wn + nt * 16 + r;
        zbuf[(size_t)row * 128 + col] = fmaxf(acc[mt][nt][e] + b_enc[col], 0.f);
      }
}

// ---------------------------------------------------------------------------
// LayerNorm over the BATCH axis per (t,z).
// ---------------------------------------------------------------------------
__global__ __launch_bounds__(256) void k_ln(const float* __restrict__ zbuf,
                                            const float* __restrict__ gamma,
                                            const float* __restrict__ beta,
                                            float* __restrict__ z_full) {
  int bid = blockIdx.x;
  int tstep = bid >> 3;
  int z0 = (bid & 7) * 16;
  int tid = threadIdx.x;
  int zl = tid & 15, bg = tid >> 4;
  __shared__ float ps[256], qs[256];
  __shared__ float muS[16], rsS[16];
  float s = 0.f, ss = 0.f;
  for (int ii = 0; ii < 32; ++ii) {
    int b = bg * 32 + ii;
    float v = zbuf[(size_t)(b * 32 + tstep) * 128 + z0 + zl];
    s += v; ss += v * v;
  }
  ps[tid] = s; qs[tid] = ss;
  __syncthreads();
  if (tid < 16) {
    float S = 0.f, Q = 0.f;
    for (int g2 = 0; g2 < 16; ++g2) { S += ps[g2 * 16 + tid]; Q += qs[g2 * 16 + tid]; }
    float mu = S / 512.f;
    float var = Q / 512.f - mu * mu;
    muS[tid] = mu;
    rsS[tid] = rsqrtf(var + 1e-8f);
  }
  __syncthreads();
  float ga = gamma[z0 + zl], be = beta[z0 + zl];
  float mu = muS[zl], rs = rsS[zl];
  for (int ii = 0; ii < 32; ++ii) {
    int b = bg * 32 + ii;
    float v = zbuf[(size_t)(b * 32 + tstep) * 128 + z0 + zl];
    z_full[(size_t)(b * 33 + tstep) * 128 + z0 + zl] = (v - mu) * rs * ga + be;
  }
}

// ---------------------------------------------------------------------------
// Attention precompute: sim depends only on z_full, so w_k and wck = sum(wk*ck)
// for ALL t are computed once. Block = batch b.
// ---------------------------------------------------------------------------
__global__ __launch_bounds__(256) void k_attnpre(const float* __restrict__ z_full,
                                                 const float* __restrict__ cgain,
                                                 const float* __restrict__ cbias,
                                                 float* __restrict__ wk_tbl,
                                                 float* __restrict__ wck_tbl) {
  __shared__ float zs[33 * 128];
  __shared__ float sim[33 * 33];
  int b = blockIdx.x, tid = threadIdx.x;
  const float* zb = z_full + (size_t)b * 33 * 128;
  for (int i = tid; i < 33 * 128; i += 256) zs[i] = zb[i];
  __syncthreads();
  for (int p = tid; p < 33 * 33; p += 256) {
    int t = p / 33, n = p - t * 33;
    float s = 0.f;
    if (n < t) {
#pragma unroll 8
      for (int k2 = 0; k2 < 128; ++k2) s += zs[t * 128 + k2] * zs[n * 128 + k2];
    }
    sim[p] = s;
  }
  __syncthreads();
  if (tid >= 1 && tid < 33) {
    int t = tid;
    float cg = cgain[0], cb2 = cbias[0];
    float m = -3.0e38f;
    for (int n = 0; n < t; ++n) m = fmaxf(m, sim[t * 33 + n]);
    float ssum = 0.f;
    for (int n = 0; n < t; ++n) ssum += __expf(sim[t * 33 + n] - m);
    float inv = 1.f / ssum;
    float wck = 0.f;
    for (int n = 0; n < t; ++n) {
      float wk = __expf(sim[t * 33 + n] - m) * inv;
      wk_tbl[((size_t)b * 33 + t) * 33 + n] = wk;
      float ck = 1.f / (1.f + __expf(-(sim[t * 33 + n] * cg + cb2)));
      wck += wk * ck;
    }
    wck_tbl[b * 33 + t] = wck;
  }
}

// ---------------------------------------------------------------------------
// Persistent cooperative kernel: all 33 recurrent steps in one launch.
// 256 blocks x 256 threads, 1 block/CU.
//   - gates-B slice (64 n' x 800 k bf16, 100 KiB) pinned in LDS for all steps
//   - activation tile streamed via global_load_lds, counted vmcnt(5) pipeline
//   - h-carry kept in registers across steps
//   - phase B: blocks 0..39 head GEMM (BK=64), blocks 40..255 attention reads
// ---------------------------------------------------------------------------
__global__ __launch_bounds__(256) void k_loop(
    unsigned short* __restrict__ xinA, unsigned short* __restrict__ xinB,
    const unsigned short* __restrict__ WT, const float* __restrict__ b_lstm,
    float* __restrict__ h, unsigned short* __restrict__ hbf,
    const unsigned short* __restrict__ Wk2T, const float* __restrict__ bias2,
    float* __restrict__ Mk, float* __restrict__ logits,
    const float* __restrict__ Wg, const float* __restrict__ bg,
    const float* __restrict__ wk_tbl, const float* __restrict__ wck_tbl,
    float* __restrict__ out) {
  __shared__ __align__(16) unsigned short Bres[64 * 800];  // 102400 B, resident
  __shared__ __align__(16) unsigned char scr[40960];       // A-chunks / Cs / head / read
  cg::grid_group grid = cg::this_grid();
  const int tid = threadIdx.x, bid = blockIdx.x;
  const int lane = tid & 63, w = tid >> 6;
  const int q = lane >> 4, r = lane & 15;
  const int wm = (w >> 1) * 32, wn = (w & 1) * 32;
  const int nn = bid & 31, mi = bid >> 5;  // gates tile
  const int m0 = mi * 64, n0g = nn * 64;

  // ---- pin gates weight slice in LDS (linear copy of WT rows n0g..n0g+63) ----
  for (int l = 0; l < 25; ++l) {
    int u = w * 12800 + l * 512;
    gl16(WT + (size_t)n0g * 800 + u + lane * 8, Bres + u);
  }

  // per-thread A-chunk coords (chunk = [64 rows][160 cols] bf16, linear in LDS)
  int arow[5], acol[5];
#pragma unroll
  for (int l = 0; l < 5; ++l) {
    int e = w * 2560 + l * 512 + lane * 8;
    arow[l] = e / 160; acol[l] = e - (e / 160) * 160;
  }

  const int jl = tid & 15, jg = nn * 16 + jl, rl0 = tid >> 4;
  const float bL0 = b_lstm[jg], bL1 = b_lstm[512 + jg],
              bL2 = b_lstm[1024 + jg], bL3 = b_lstm[1536 + jg];
  float hreg[4] = {0.f, 0.f, 0.f, 0.f};

  const int mi2 = bid / 5, ni2 = bid - mi2 * 5;  // head-GEMM tile (bid<40)

  asm volatile("s_waitcnt vmcnt(0)" ::: "memory");
  __syncthreads();

  for (int t = 0; t < 33; ++t) {
    const unsigned short* cur = (t & 1) ? xinB : xinA;
    unsigned short* nxt = (t & 1) ? xinA : xinB;

    // ================= phase A: gates GEMM (64x64, K=800) + LSTM cell ========
    unsigned short* A0 = (unsigned short*)scr;
    unsigned short* A1 = (unsigned short*)(scr + 20480);
#pragma unroll
    for (int l = 0; l < 5; ++l)  // prologue: chunk 0
      gl16(cur + (size_t)(m0 + arow[l]) * 800 + acol[l], A0 + w * 2560 + l * 512);
    f32x4 acc[2][2] = {};
    for (int c = 0; c < 5; ++c) {
      const unsigned short* Ac = (c & 1) ? A1 : A0;
      if (c < 4) {
        unsigned short* An = (c & 1) ? A0 : A1;
#pragma unroll
        for (int l = 0; l < 5; ++l)
          gl16(cur + (size_t)(m0 + arow[l]) * 800 + (c + 1) * 160 + acol[l],
               An + w * 2560 + l * 512);
        asm volatile("s_waitcnt vmcnt(5)" ::: "memory");  // chunk c landed
      } else {
        asm volatile("s_waitcnt vmcnt(0)" ::: "memory");
      }
      __builtin_amdgcn_s_barrier();
#pragma unroll
      for (int ks = 0; ks < 5; ++ks) {
        short8 a0 = *(const short8*)&Ac[(wm + r) * 160 + ks * 32 + q * 8];
        short8 a1 = *(const short8*)&Ac[(wm + 16 + r) * 160 + ks * 32 + q * 8];
        short8 b0 = *(const short8*)&Bres[(wn + r) * 800 + c * 160 + ks * 32 + q * 8];
        short8 b1 = *(const short8*)&Bres[(wn + 16 + r) * 800 + c * 160 + ks * 32 + q * 8];
        acc[0][0] = __builtin_amdgcn_mfma_f32_16x16x32_bf16(a0, b0, acc[0][0], 0, 0, 0);
        acc[0][1] = __builtin_amdgcn_mfma_f32_16x16x32_bf16(a0, b1, acc[0][1], 0, 0, 0);
        acc[1][0] = __builtin_amdgcn_mfma_f32_16x16x32_bf16(a1, b0, acc[1][0], 0, 0, 0);
        acc[1][1] = __builtin_amdgcn_mfma_f32_16x16x32_bf16(a1, b1, acc[1][1], 0, 0, 0);
      }
      asm volatile("s_waitcnt lgkmcnt(0)" ::: "memory");
      __builtin_amdgcn_s_barrier();  // buffer reuse guard
    }
    // ---- fused LSTM cell (h-carry in registers) ----
    float* Cs = (float*)scr;
#pragma unroll
    for (int mt = 0; mt < 2; ++mt)
#pragma unroll
      for (int nt = 0; nt < 2; ++nt)
#pragma unroll
        for (int e = 0; e < 4; ++e)
          Cs[(wm + mt * 16 + q * 4 + e) * 65 + wn + nt * 16 + r] = acc[mt][nt][e];
    __syncthreads();
#pragma unroll
    for (int it = 0; it < 4; ++it) {
      int rl = it * 16 + rl0;
      int brow = m0 + rl;
      float gi = Cs[rl * 65 + jl * 4 + 0] + bL0;
      float gf = Cs[rl * 65 + jl * 4 + 1] + bL1;
      float gc = Cs[rl * 65 + jl * 4 + 2] + bL2;
      float go = Cs[rl * 65 + jl * 4 + 3] + bL3;
      float cnew = sigm(gf) * hreg[it] + sigm(gi) * ftanh(gc);
      float hnew = sigm(go) * ftanh(cnew);
      hreg[it] = hnew;
      h[brow * 512 + jg] = hnew;
      hbf[brow * 512 + jg] = f2bf(hnew);
      nxt[brow * 800 + 288 + jg] = f2bf(cnew);
    }
    grid.sync();

    // ================= phase B ==============================================
    if (bid < 40) {
      // head GEMM 64x64, K=512, BK=64, reg-prefetch double buffer
      const int LSTR2 = 72;
      unsigned short* As2 = (unsigned short*)scr;            // 2 x 4608 shorts
      unsigned short* Bs2 = (unsigned short*)(scr + 18432);  // 2 x 4608 shorts
      int m0b = mi2 * 64, n0b = ni2 * 64;
      int ldrow = tid >> 2, ldc = (tid & 3) * 16;
      const uint4* Ag = (const uint4*)(hbf + (size_t)(m0b + ldrow) * 512);
      const uint4* Bg = (const uint4*)(Wk2T + (size_t)(n0b + ldrow) * 512);
      uint4 ra0 = Ag[ldc >> 3], ra1 = Ag[(ldc >> 3) + 1];
      uint4 rb0 = Bg[ldc >> 3], rb1 = Bg[(ldc >> 3) + 1];
      f32x4 acc2[2][2] = {};
      int s = 0;
      *(uint4*)&As2[ldrow * LSTR2 + ldc] = ra0;
      *(uint4*)&As2[ldrow * LSTR2 + ldc + 8] = ra1;
      *(uint4*)&Bs2[ldrow * LSTR2 + ldc] = rb0;
      *(uint4*)&Bs2[ldrow * LSTR2 + ldc + 8] = rb1;
      __syncthreads();
      for (int kk = 0; kk < 8; ++kk) {
        if (kk < 7) {
          int k0 = (kk + 1) * 64;
          ra0 = Ag[(k0 + ldc) >> 3]; ra1 = Ag[((k0 + ldc) >> 3) + 1];
          rb0 = Bg[(k0 + ldc) >> 3]; rb1 = Bg[((k0 + ldc) >> 3) + 1];
        }
#pragma unroll
        for (int ks = 0; ks < 2; ++ks) {
          short8 a0 = *(const short8*)&As2[s * 4608 + (wm + r) * LSTR2 + ks * 32 + q * 8];
          short8 a1 = *(const short8*)&As2[s * 4608 + (wm + 16 + r) * LSTR2 + ks * 32 + q * 8];
          short8 b0 = *(const short8*)&Bs2[s * 4608 + (wn + r) * LSTR2 + ks * 32 + q * 8];
          short8 b1 = *(const short8*)&Bs2[s * 4608 + (wn + 16 + r) * LSTR2 + ks * 32 + q * 8];
          acc2[0][0] = __builtin_amdgcn_mfma_f32_16x16x32_bf16(a0, b0, acc2[0][0], 0, 0, 0);
          acc2[0][1] = __builtin_amdgcn_mfma_f32_16x16x32_bf16(a0, b1, acc2[0][1], 0, 0, 0);
          acc2[1][0] = __builtin_amdgcn_mfma_f32_16x16x32_bf16(a1, b0, acc2[1][0], 0, 0, 0);
          acc2[1][1] = __builtin_amdgcn_mfma_f32_16x16x32_bf16(a1, b1, acc2[1][1], 0, 0, 0);
        }
        if (kk < 7) {
          s ^= 1;
          *(uint4*)&As2[s * 4608 + ldrow * LSTR2 + ldc] = ra0;
          *(uint4*)&As2[s * 4608 + ldrow * LSTR2 + ldc + 8] = ra1;
          *(uint4*)&Bs2[s * 4608 + ldrow * LSTR2 + ldc] = rb0;
          *(uint4*)&Bs2[s * 4608 + ldrow * LSTR2 + ldc + 8] = rb1;
        }
        __syncthreads();
      }
#pragma unroll
      for (int mt = 0; mt < 2; ++mt)
#pragma unroll
        for (int nt = 0; nt < 2; ++nt)
#pragma unroll
          for (int e2 = 0; e2 < 4; ++e2) {
            int row = m0b + wm + mt * 16 + q * 4 + e2;
            int np = n0b + wn + nt * 16 + r;
            float v = acc2[mt][nt][e2] + bias2[np];
            if (np < 256) Mk[(size_t)(row * 33 + t) * 256 + np] = fmaxf(v, 0.f);
            else if (np >= 257 && np < 261) logits[row * 4 + (np - 257)] = v;
          }
    } else if (t > 0 && t < 32) {
      // attention read: g gate + weighted = sum_{n<t} wk * Mk -> key_r for t+1
      float* wkS = (float*)scr;
      float* red4 = (float*)(scr + 512);
      for (int rr = 0; rr < 3; ++rr) {
        int b = (bid - 40) + 216 * rr;
        if (b < 512) {
          float sd = h[b * 512 + tid] * Wg[tid] + h[b * 512 + 256 + tid] * Wg[256 + tid];
#pragma unroll
          for (int off = 32; off > 0; off >>= 1) sd += __shfl_down(sd, off);
          if (lane == 0) red4[w] = sd;
          if (tid < t) wkS[tid] = wk_tbl[((size_t)b * 33 + t) * 33 + tid];
          __syncthreads();
          float g = 1.f / (1.f + __expf(-(red4[0] + red4[1] + red4[2] + red4[3] + bg[0])));
          float p0 = 0.f, p1 = 0.f, p2 = 0.f, p3 = 0.f;
          int n = 0;
          for (; n + 4 <= t; n += 4) {
            p0 += wkS[n] * Mk[((size_t)b * 33 + n) * 256 + tid];
            p1 += wkS[n + 1] * Mk[((size_t)b * 33 + n + 1) * 256 + tid];
            p2 += wkS[n + 2] * Mk[((size_t)b * 33 + n + 2) * 256 + tid];
            p3 += wkS[n + 3] * Mk[((size_t)b * 33 + n + 3) * 256 + tid];
          }
          for (; n < t; ++n) p0 += wkS[n] * Mk[((size_t)b * 33 + n) * 256 + tid];
          nxt[b * 800 + tid] = f2bf(g * ((p0 + p1) + (p2 + p3)));
          if (tid == 0) nxt[b * 800 + 256] = f2bf(g * wck_tbl[b * 33 + t]);
          __syncthreads();
        }
      }
    }
    grid.sync();
  }
  // final 4-wide softmax (block 0)
  if (bid == 0) {
    for (int r2 = tid; r2 < 512; r2 += 256) {
      float a = logits[r2 * 4], b2 = logits[r2 * 4 + 1],
            c2 = logits[r2 * 4 + 2], d2 = logits[r2 * 4 + 3];
      float m = fmaxf(fmaxf(a, b2), fmaxf(c2, d2));
      float ea = __expf(a - m), eb = __expf(b2 - m), ec = __expf(c2 - m), ed = __expf(d2 - m);
      float ssum = ea + eb + ec + ed;
      out[r2 * 4] = ea / ssum; out[r2 * 4 + 1] = eb / ssum;
      out[r2 * 4 + 2] = ec / ssum; out[r2 * 4 + 3] = ed / ssum;
    }
  }
}

// ---------------------------------------------------------------------------
// Fallback per-step kernels (used only if cooperative launch is unavailable).
// ---------------------------------------------------------------------------
__global__ __launch_bounds__(256) void k_gates(const unsigned short* __restrict__ xin,
                                               const unsigned short* __restrict__ WT,
                                               const float* __restrict__ b_lstm,
                                               float* __restrict__ h,
                                               unsigned short* __restrict__ hbf,
                                               unsigned short* __restrict__ xin_nxt) {
  __shared__ __align__(16) unsigned short As[2][64 * LSTR];
  __shared__ __align__(16) unsigned short Bs[2][64 * LSTR];
  __shared__ float Cs[64 * 65];
  int tid = threadIdx.x;
  int nn = blockIdx.x;
  int m0 = blockIdx.y * 64;
  int n0 = nn * 64;
  int lane = tid & 63, wid = tid >> 6;
  int wm = (wid >> 1) * 32, wn = (wid & 1) * 32;
  int q = lane >> 4, r = lane & 15;
  int ldrow = tid >> 2, ldc = (tid & 3) * 8;
  const uint4* Ag = reinterpret_cast<const uint4*>(xin + (size_t)(m0 + ldrow) * 800);
  const uint4* Bg = reinterpret_cast<const uint4*>(WT + (size_t)(n0 + ldrow) * 800);
  uint4 ra = Ag[ldc >> 3], rb = Bg[ldc >> 3];
  f32x4 acc[2][2] = {};
  int s = 0;
  *reinterpret_cast<uint4*>(&As[0][ldrow * LSTR + ldc]) = ra;
  *reinterpret_cast<uint4*>(&Bs[0][ldrow * LSTR + ldc]) = rb;
  __syncthreads();
  for (int kk = 0; kk < 25; ++kk) {
    if (kk < 24) {
      int k0 = (kk + 1) * 32;
      ra = Ag[(k0 + ldc) >> 3];
      rb = Bg[(k0 + ldc) >> 3];
    }
    short8 a0 = *reinterpret_cast<const short8*>(&As[s][(wm + r) * LSTR + q * 8]);
    short8 a1 = *reinterpret_cast<const short8*>(&As[s][(wm + 16 + r) * LSTR + q * 8]);
    short8 b0 = *reinterpret_cast<const short8*>(&Bs[s][(wn + r) * LSTR + q * 8]);
    short8 b1 = *reinterpret_cast<const short8*>(&Bs[s][(wn + 16 + r) * LSTR + q * 8]);
    acc[0][0] = __builtin_amdgcn_mfma_f32_16x16x32_bf16(a0, b0, acc[0][0], 0, 0, 0);
    acc[0][1] = __builtin_amdgcn_mfma_f32_16x16x32_bf16(a0, b1, acc[0][1], 0, 0, 0);
    acc[1][0] = __builtin_amdgcn_mfma_f32_16x16x32_bf16(a1, b0, acc[1][0], 0, 0, 0);
    acc[1][1] = __builtin_amdgcn_mfma_f32_16x16x32_bf16(a1, b1, acc[1][1], 0, 0, 0);
    if (kk < 24) {
      *reinterpret_cast<uint4*>(&As[s ^ 1][ldrow * LSTR + ldc]) = ra;
      *reinterpret_cast<uint4*>(&Bs[s ^ 1][ldrow * LSTR + ldc]) = rb;
      s ^= 1;
    }
    __syncthreads();
  }
#pragma unroll
  for (int mt = 0; mt < 2; ++mt)
#pragma unroll
    for (int nt = 0; nt < 2; ++nt)
#pragma unroll
      for (int e = 0; e < 4; ++e)
        Cs[(wm + mt * 16 + q * 4 + e) * 65 + wn + nt * 16 + r] = acc[mt][nt][e];
  __syncthreads();
#pragma unroll
  for (int it = 0; it < 4; ++it) {
    int id = it * 256 + tid;
    int rl = id >> 4, jl = id & 15;
    int brow = m0 + rl;
    int j = nn * 16 + jl;
    float gi = Cs[rl * 65 + jl * 4 + 0] + b_lstm[j];
    float gf = Cs[rl * 65 + jl * 4 + 1] + b_lstm[512 + j];
    float gg = Cs[rl * 65 + jl * 4 + 2] + b_lstm[1024 + j];
    float go = Cs[rl * 65 + jl * 4 + 3] + b_lstm[1536 + j];
    float hold = h[brow * 512 + j];
    float cnew = sigm(gf) * hold + sigm(gi) * ftanh(gg);
    float hnew = sigm(go) * ftanh(cnew);
    h[brow * 512 + j] = hnew;
    hbf[brow * 512 + j] = f2bf(hnew);
    xin_nxt[brow * 800 + 288 + j] = f2bf(cnew);
  }
}

__global__ __launch_bounds__(256) void k_head(const unsigned short* __restrict__ hbf,
                                              const unsigned short* __restrict__ Wk2T,
                                              const float* __restrict__ bias2,
                                              float* __restrict__ Mk,
                                              float* __restrict__ logits,
                                              const float* __restrict__ h,
                                              const float* __restrict__ Wg,
                                              const float* __restrict__ bg,
                                              const float* __restrict__ wk_tbl,
                                              const float* __restrict__ wck_tbl,
                                              unsigned short* __restrict__ xin_nxt,
                                              int t) {
  __shared__ __align__(16) unsigned short As[2][64 * LSTR];
  __shared__ __align__(16) unsigned short Bs[2][64 * LSTR];
  __shared__ float wkS[33];
  __shared__ float red[256];
  int bid = blockIdx.x;
  int tid = threadIdx.x;
  if (bid < 40) {
    int mi = bid / 5, ni = bid - mi * 5;
    int m0 = mi * 64, n0 = ni * 64;
    int lane = tid & 63, wid = tid >> 6;
    int wm = (wid >> 1) * 32, wn = (wid & 1) * 32;
    int q = lane >> 4, r = lane & 15;
    int ldrow = tid >> 2, ldc = (tid & 3) * 8;
    const uint4* Ag = reinterpret_cast<const uint4*>(hbf + (size_t)(m0 + ldrow) * 512);
    const uint4* Bg = reinterpret_cast<const uint4*>(Wk2T + (size_t)(n0 + ldrow) * 512);
    uint4 ra = Ag[ldc >> 3], rb = Bg[ldc >> 3];
    f32x4 acc[2][2] = {};
    int s = 0;
    *reinterpret_cast<uint4*>(&As[0][ldrow * LSTR + ldc]) = ra;
    *reinterpret_cast<uint4*>(&Bs[0][ldrow * LSTR + ldc]) = rb;
    __syncthreads();
    for (int kk = 0; kk < 16; ++kk) {
      if (kk < 15) {
        int k0 = (kk + 1) * 32;
        ra = Ag[(k0 + ldc) >> 3];
        rb = Bg[(k0 + ldc) >> 3];
      }
      short8 a0 = *reinterpret_cast<const short8*>(&As[s][(wm + r) * LSTR + q * 8]);
      short8 a1 = *reinterpret_cast<const short8*>(&As[s][(wm + 16 + r) * LSTR + q * 8]);
      short8 b0 = *reinterpret_cast<const short8*>(&Bs[s][(wn + r) * LSTR + q * 8]);
      short8 b1 = *reinterpret_cast<const short8*>(&Bs[s][(wn + 16 + r) * LSTR + q * 8]);
      acc[0][0] = __builtin_amdgcn_mfma_f32_16x16x32_bf16(a0, b0, acc[0][0], 0, 0, 0);
      acc[0][1] = __builtin_amdgcn_mfma_f32_16x16x32_bf16(a0, b1, acc[0][1], 0, 0, 0);
      acc[1][0] = __builtin_amdgcn_mfma_f32_16x16x32_bf16(a1, b0, acc[1][0], 0, 0, 0);
      acc[1][1] = __builtin_amdgcn_mfma_f32_16x16x32_bf16(a1, b1, acc[1][1], 0, 0, 0);
      if (kk < 15) {
        *reinterpret_cast<uint4*>(&As[s ^ 1][ldrow * LSTR + ldc]) = ra;
        *reinterpret_cast<uint4*>(&Bs[s ^ 1][ldrow * LSTR + ldc]) = rb;
        s ^= 1;
      }
      __syncthreads();
    }
#pragma unroll
    for (int mt = 0; mt < 2; ++mt)
#pragma unroll
      for (int nt = 0; nt < 2; ++nt)
#pragma unroll
        for (int e = 0; e < 4; ++e) {
          int row = m0 + wm + mt * 16 + q * 4 + e;
          int np = n0 + wn + nt * 16 + r;
          float v = acc[mt][nt][e] + bias2[np];
          if (np < 256) Mk[(size_t)(row * 33 + t) * 256 + np] = fmaxf(v, 0.f);
          else if (np >= 257 && np < 261) logits[row * 4 + (np - 257)] = v;
        }
  } else {
    if (t == 0 || t == 32) return;
    int b = bid - 40;
    float s = h[b * 512 + tid] * Wg[tid] + h[b * 512 + 256 + tid] * Wg[256 + tid];
    red[tid] = s;
    if (tid < t) wkS[tid] = wk_tbl[((size_t)b * 33 + t) * 33 + tid];
    __syncthreads();
    for (int off = 128; off > 0; off >>= 1) {
      if (tid < off) red[tid] += red[tid + off];
      __syncthreads();
    }
    float g = 1.f / (1.f + __expf(-(red[0] + bg[0])));
    float acc = 0.f;
    for (int n = 0; n < t; ++n) acc += wkS[n] * Mk[((size_t)b * 33 + n) * 256 + tid];
    xin_nxt[b * 800 + tid] = f2bf(g * acc);
    if (tid == 0) xin_nxt[b * 800 + 256] = f2bf(g * wck_tbl[b * 33 + t]);
  }
}

__global__ void k_softmax(const float* __restrict__ logits, float* __restrict__ out) {
  int tid = threadIdx.x;
  for (int r2 = tid; r2 < 512; r2 += 256) {
    float a = logits[r2 * 4], b = logits[r2 * 4 + 1], c = logits[r2 * 4 + 2], d = logits[r2 * 4 + 3];
    float m = fmaxf(fmaxf(a, b), fmaxf(c, d));
    float ea = __expf(a - m), eb = __expf(b - m), ec = __expf(c - m), ed = __expf(d - m);
    float s = ea + eb + ec + ed;
    out[r2 * 4] = ea / s; out[r2 * 4 + 1] = eb / s;
    out[r2 * 4 + 2] = ec / s; out[r2 * 4 + 3] = ed / s;
  }
}

extern "C" void kernel_launch(void* const* d_in, const int* in_sizes, int n_in,
                              void* d_out, int out_size, void* d_ws, size_t ws_size,
                              hipStream_t stream) {
  const float* x_seq = (const float*)d_in[0];
  const float* W_enc = (const float*)d_in[1];
  const float* b_enc = (const float*)d_in[2];
  const float* W_lstm = (const float*)d_in[3];
  const float* U_lstm = (const float*)d_in[4];
  const float* b_lstm = (const float*)d_in[5];
  const float* W_key = (const float*)d_in[6];
  const float* b_key = (const float*)d_in[7];
  const float* W_g = (const float*)d_in[8];
  const float* b_g = (const float*)d_in[9];
  const float* W_y = (const float*)d_in[10];
  const float* b_y = (const float*)d_in[11];
  const float* gamma = (const float*)d_in[12];
  const float* beta = (const float*)d_in[13];
  const float* cg_ = (const float*)d_in[14];
  const float* cb = (const float*)d_in[15];

  char* p = (char*)d_ws;
  auto alloc = [&](size_t bytes) {
    char* r = p;
    p += (bytes + 255) & ~(size_t)255;
    return r;
  };
  float* zbuf = (float*)alloc((size_t)16384 * 128 * 4);
  float* z_full = (float*)alloc((size_t)512 * 33 * 128 * 4);
  unsigned short* WcombT = (unsigned short*)alloc((size_t)2048 * 800 * 2);
  unsigned short* WencT = (unsigned short*)alloc((size_t)128 * 1024 * 2);
  unsigned short* Wk2T = (unsigned short*)alloc((size_t)320 * 512 * 2);
  float* bias2 = (float*)alloc(320 * 4);
  unsigned short* xinA = (unsigned short*)alloc((size_t)512 * 800 * 2);
  unsigned short* xinB = (unsigned short*)alloc((size_t)512 * 800 * 2);
  float* h = (float*)alloc((size_t)512 * 512 * 4);
  unsigned short* hbf = (unsigned short*)alloc((size_t)512 * 512 * 2);
  float* Mk = (float*)alloc((size_t)512 * 33 * 256 * 4);
  float* logits = (float*)alloc((size_t)512 * 4 * 4);
  float* wk_tbl = (float*)alloc((size_t)512 * 33 * 33 * 4);
  float* wck_tbl = (float*)alloc((size_t)512 * 33 * 4);
  float* outp = (float*)d_out;

  const int prep_total = 2048 * 800 + 320 * 512 + 128 * 1024 + 320 + 2 * 512 * 800 + 512 * 512 + 512 * 128;
  k_prep<<<(prep_total + 255) / 256, 256, 0, stream>>>(
      W_lstm, U_lstm, W_enc, W_key, W_g, W_y, b_key, b_g, b_y,
      WcombT, Wk2T, WencT, bias2, xinA, xinB, h, z_full);
  k_enc<<<256, 512, 0, stream>>>(x_seq, WencT, b_enc, zbuf);
  k_ln<<<256, 256, 0, stream>>>(zbuf, gamma, beta, z_full);
  k_attnpre<<<512, 256, 0, stream>>>(z_full, cg_, cb, wk_tbl, wck_tbl);

  void* cargs[15];
  cargs[0] = &xinA;  cargs[1] = &xinB;   cargs[2] = &WcombT; cargs[3] = &b_lstm;
  cargs[4] = &h;     cargs[5] = &hbf;    cargs[6] = &Wk2T;   cargs[7] = &bias2;
  cargs[8] = &Mk;    cargs[9] = &logits; cargs[10] = &W_g;   cargs[11] = &b_g;
  cargs[12] = &wk_tbl; cargs[13] = &wck_tbl; cargs[14] = &outp;
  hipError_t ce = hipLaunchCooperativeKernel((const void*)k_loop, dim3(256), dim3(256),
                                             cargs, 0u, stream);
  if (ce != hipSuccess) {
    // fallback: per-step launches (previous verified path)
    for (int t = 0; t < 33; ++t) {
      unsigned short* cur = (t & 1) ? xinB : xinA;
      unsigned short* nxt = (t & 1) ? xinA : xinB;
      k_gates<<<dim3(32, 8), 256, 0, stream>>>(cur, WcombT, b_lstm, h, hbf, nxt);
      k_head<<<552, 256, 0, stream>>>(hbf, Wk2T, bias2, Mk, logits, h,
                                      W_g, b_g, wk_tbl, wck_tbl, nxt, t);
    }
    k_softmax<<<1, 256, 0, stream>>>(logits, outp);
  }
}

// Round 3
// 1797.476 us; speedup vs baseline: 1.4401x; 1.4401x over previous
//
#include <hip/hip_runtime.h>

typedef __attribute__((ext_vector_type(8))) short short8;
typedef __attribute__((ext_vector_type(4))) float f32x4;
typedef __attribute__((ext_vector_type(8))) unsigned short ushort8;
typedef __attribute__((ext_vector_type(4))) unsigned short ushort4v;

__device__ __forceinline__ unsigned short f2bf(float f) {
  union { float f; unsigned u; } v; v.f = f;
  unsigned u = v.u;
  u += 0x7fffu + ((u >> 16) & 1u);
  return (unsigned short)(u >> 16);
}
__device__ __forceinline__ float sigm(float x) { return 1.f / (1.f + __expf(-x)); }
__device__ __forceinline__ float ftanh(float x) { return 1.f - 2.f / (__expf(2.f * x) + 1.f); }

// async global->LDS, 16B per lane. LDS dest must be WAVE-UNIFORM base; HW adds lane*16.
__device__ __forceinline__ void gl16(const unsigned short* g, unsigned short* l) {
  __builtin_amdgcn_global_load_lds((const __attribute__((address_space(1))) void*)g,
                                   (__attribute__((address_space(3))) void*)l, 16, 0, 0);
}

// Lightweight grid barrier (sense-reversing, agent scope). bar[0]=cnt, bar[64]=gen.
__device__ __forceinline__ void gbar(unsigned* cnt, unsigned* gen) {
  __syncthreads();
  if (threadIdx.x == 0) {
    __threadfence();  // release: per-XCD L2 writeback for cross-XCD visibility
    unsigned g = __hip_atomic_load(gen, __ATOMIC_RELAXED, __HIP_MEMORY_SCOPE_AGENT);
    unsigned a = __hip_atomic_fetch_add(cnt, 1u, __ATOMIC_ACQ_REL, __HIP_MEMORY_SCOPE_AGENT);
    if (a == 255u) {
      __hip_atomic_store(cnt, 0u, __ATOMIC_RELAXED, __HIP_MEMORY_SCOPE_AGENT);
      __hip_atomic_store(gen, g + 1u, __ATOMIC_RELEASE, __HIP_MEMORY_SCOPE_AGENT);
    } else {
      while (__hip_atomic_load(gen, __ATOMIC_RELAXED, __HIP_MEMORY_SCOPE_AGENT) == g)
        __builtin_amdgcn_s_sleep(1);
    }
    __threadfence();  // acquire: invalidate stale L2 lines
  }
  __syncthreads();
}

#define LSTR 40  // LDS row stride (elems): 32 data + 8 pad -> rows advance 20 banks

// ---------------------------------------------------------------------------
// Prep: build bf16 transposed/permuted weights, zero state buffers + barrier.
// WcombT: (2048 rows n', 800 cols k) bf16. n' = j*4+gate  (orig col n = gate*512+j)
// Wk2T:   (320 rows n, 512 cols k) bf16. n<256->W_key, 256->W_g, 257..260->W_y
// WencT:  (128 rows n, 1024 cols k) bf16 = W_enc^T
// ---------------------------------------------------------------------------
__global__ void k_prep(const float* __restrict__ W_lstm, const float* __restrict__ U_lstm,
                       const float* __restrict__ W_enc, const float* __restrict__ W_key,
                       const float* __restrict__ W_g, const float* __restrict__ W_y,
                       const float* __restrict__ b_key, const float* __restrict__ b_g,
                       const float* __restrict__ b_y,
                       unsigned short* __restrict__ WcombT, unsigned short* __restrict__ Wk2T,
                       unsigned short* __restrict__ WencT, float* __restrict__ bias2,
                       unsigned short* __restrict__ xinA, unsigned short* __restrict__ xinB,
                       float* __restrict__ h, float* __restrict__ z_full,
                       unsigned* __restrict__ bar) {
  const int N1 = 2048 * 800, N2 = 320 * 512, N3 = 128 * 1024, N4 = 320,
            N5 = 512 * 800, N7 = 512 * 512, N8 = 512 * 128, N9 = 256;
  int i = blockIdx.x * 256 + threadIdx.x;
  if (i < N1) {
    int np = i / 800, k = i - np * 800;
    int j = np >> 2, gate = np & 3, n = gate * 512 + j;
    float v = 0.f;
    if (k < 257) v = W_lstm[k * 2048 + n];
    else if (k >= 288) v = U_lstm[(k - 288) * 2048 + n];
    WcombT[i] = f2bf(v);
    return;
  }
  i -= N1;
  if (i < N2) {
    int n = i / 512, k = i - n * 512;
    float v = 0.f;
    if (n < 256) v = W_key[k * 256 + n];
    else if (n == 256) v = W_g[k];
    else if (n < 261) v = W_y[k * 4 + (n - 257)];
    Wk2T[i] = f2bf(v);
    return;
  }
  i -= N2;
  if (i < N3) {
    int n = i / 1024, k = i - n * 1024;
    WencT[i] = f2bf(W_enc[k * 128 + n]);
    return;
  }
  i -= N3;
  if (i < N4) {
    float v = (i < 256) ? b_key[i] : (i == 256 ? b_g[0] : (i < 261 ? b_y[i - 257] : 0.f));
    bias2[i] = v;
    return;
  }
  i -= N4;
  if (i < N5) { xinA[i] = 0; return; }
  i -= N5;
  if (i < N5) { xinB[i] = 0; return; }
  i -= N5;
  if (i < N7) { h[i] = 0.f; return; }
  i -= N7;
  if (i < N8) {
    int b = i >> 7, z = i & 127;
    z_full[(b * 33 + 32) * 128 + z] = 0.f;  // null slot
    return;
  }
  i -= N8;
  if (i < N9) bar[i] = 0;
}

// ---------------------------------------------------------------------------
// Encoder GEMM: z = relu(x @ W_enc + b_enc). 64Mx128N tile, BK=32, K=1024,
// 512 threads (8 waves/CU), double-buffered. (proven in round 1)
// ---------------------------------------------------------------------------
__global__ __launch_bounds__(512) void k_enc(const float* __restrict__ x,
                                             const unsigned short* __restrict__ WencT,
                                             const float* __restrict__ b_enc,
                                             float* __restrict__ zbuf) {
  __shared__ __align__(16) unsigned short As[2][64 * LSTR];
  __shared__ __align__(16) unsigned short Bs[2][128 * LSTR];
  int tid = threadIdx.x;
  int m0 = blockIdx.x * 64;
  int lane = tid & 63, wid = tid >> 6;
  int wm = (wid >> 2) * 32, wn = (wid & 3) * 32;
  int q = lane >> 4, r = lane & 15;
  int ldrowA = tid >> 3, ldcA = (tid & 7) * 4;
  int ldrowB = tid >> 2, ldcB = (tid & 3) * 8;
  const float4* Ag = reinterpret_cast<const float4*>(x + (size_t)(m0 + ldrowA) * 1024);
  const uint4* Bg = reinterpret_cast<const uint4*>(WencT + (size_t)ldrowB * 1024);
  float4 ra = Ag[ldcA >> 2];
  uint4 rb = Bg[ldcB >> 3];
  f32x4 acc[2][2] = {};
  int s = 0;
  {
    ushort4v t4;
    t4[0] = f2bf(ra.x); t4[1] = f2bf(ra.y); t4[2] = f2bf(ra.z); t4[3] = f2bf(ra.w);
    *reinterpret_cast<ushort4v*>(&As[0][ldrowA * LSTR + ldcA]) = t4;
    *reinterpret_cast<uint4*>(&Bs[0][ldrowB * LSTR + ldcB]) = rb;
  }
  __syncthreads();
  for (int kk = 0; kk < 32; ++kk) {
    if (kk < 31) {
      int k0 = (kk + 1) * 32;
      ra = Ag[(k0 + ldcA) >> 2];
      rb = Bg[(k0 + ldcB) >> 3];
    }
    short8 a0 = *reinterpret_cast<const short8*>(&As[s][(wm + r) * LSTR + q * 8]);
    short8 a1 = *reinterpret_cast<const short8*>(&As[s][(wm + 16 + r) * LSTR + q * 8]);
    short8 b0 = *reinterpret_cast<const short8*>(&Bs[s][(wn + r) * LSTR + q * 8]);
    short8 b1 = *reinterpret_cast<const short8*>(&Bs[s][(wn + 16 + r) * LSTR + q * 8]);
    acc[0][0] = __builtin_amdgcn_mfma_f32_16x16x32_bf16(a0, b0, acc[0][0], 0, 0, 0);
    acc[0][1] = __builtin_amdgcn_mfma_f32_16x16x32_bf16(a0, b1, acc[0][1], 0, 0, 0);
    acc[1][0] = __builtin_amdgcn_mfma_f32_16x16x32_bf16(a1, b0, acc[1][0], 0, 0, 0);
    acc[1][1] = __builtin_amdgcn_mfma_f32_16x16x32_bf16(a1, b1, acc[1][1], 0, 0, 0);
    if (kk < 31) {
      ushort4v t4;
      t4[0] = f2bf(ra.x); t4[1] = f2bf(ra.y); t4[2] = f2bf(ra.z); t4[3] = f2bf(ra.w);
      *reinterpret_cast<ushort4v*>(&As[s ^ 1][ldrowA * LSTR + ldcA]) = t4;
      *reinterpret_cast<uint4*>(&Bs[s ^ 1][ldrowB * LSTR + ldcB]) = rb;
      s ^= 1;
    }
    __syncthreads();
  }
#pragma unroll
  for (int mt = 0; mt < 2; ++mt)
#pragma unroll
    for (int nt = 0; nt < 2; ++nt)
#pragma unroll
      for (int e = 0; e < 4; ++e) {
        int row = m0 + wm + mt * 16 + q * 4 + e;
        int col = wn + nt * 16 + r;
        zbuf[(size_t)row * 128 + col] = fmaxf(acc[mt][nt][e] + b_enc[col], 0.f);
      }
}

// ---------------------------------------------------------------------------
// LayerNorm over the BATCH axis per (t,z).
// ---------------------------------------------------------------------------
__global__ __launch_bounds__(256) void k_ln(const float* __restrict__ zbuf,
                                            const float* __restrict__ gamma,
                                            const float* __restrict__ beta,
                                            float* __restrict__ z_full) {
  int bid = blockIdx.x;
  int tstep = bid >> 3;
  int z0 = (bid & 7) * 16;
  int tid = threadIdx.x;
  int zl = tid & 15, bg = tid >> 4;
  __shared__ float ps[256], qs[256];
  __shared__ float muS[16], rsS[16];
  float s = 0.f, ss = 0.f;
  for (int ii = 0; ii < 32; ++ii) {
    int b = bg * 32 + ii;
    float v = zbuf[(size_t)(b * 32 + tstep) * 128 + z0 + zl];
    s += v; ss += v * v;
  }
  ps[tid] = s; qs[tid] = ss;
  __syncthreads();
  if (tid < 16) {
    float S = 0.f, Q = 0.f;
    for (int g2 = 0; g2 < 16; ++g2) { S += ps[g2 * 16 + tid]; Q += qs[g2 * 16 + tid]; }
    float mu = S / 512.f;
    float var = Q / 512.f - mu * mu;
    muS[tid] = mu;
    rsS[tid] = rsqrtf(var + 1e-8f);
  }
  __syncthreads();
  float ga = gamma[z0 + zl], be = beta[z0 + zl];
  float mu = muS[zl], rs = rsS[zl];
  for (int ii = 0; ii < 32; ++ii) {
    int b = bg * 32 + ii;
    float v = zbuf[(size_t)(b * 32 + tstep) * 128 + z0 + zl];
    z_full[(size_t)(b * 33 + tstep) * 128 + z0 + zl] = (v - mu) * rs * ga + be;
  }
}

// ---------------------------------------------------------------------------
// Attention precompute (w_k and wck for all t, once).
// ---------------------------------------------------------------------------
__global__ __launch_bounds__(256) void k_attnpre(const float* __restrict__ z_full,
                                                 const float* __restrict__ cgain,
                                                 const float* __restrict__ cbias,
                                                 float* __restrict__ wk_tbl,
                                                 float* __restrict__ wck_tbl) {
  __shared__ float zs[33 * 128];
  __shared__ float sim[33 * 33];
  int b = blockIdx.x, tid = threadIdx.x;
  const float* zb = z_full + (size_t)b * 33 * 128;
  for (int i = tid; i < 33 * 128; i += 256) zs[i] = zb[i];
  __syncthreads();
  for (int p = tid; p < 33 * 33; p += 256) {
    int t = p / 33, n = p - t * 33;
    float s = 0.f;
    if (n < t) {
#pragma unroll 8
      for (int k2 = 0; k2 < 128; ++k2) s += zs[t * 128 + k2] * zs[n * 128 + k2];
    }
    sim[p] = s;
  }
  __syncthreads();
  if (tid >= 1 && tid < 33) {
    int t = tid;
    float cg = cgain[0], cb2 = cbias[0];
    float m = -3.0e38f;
    for (int n = 0; n < t; ++n) m = fmaxf(m, sim[t * 33 + n]);
    float ssum = 0.f;
    for (int n = 0; n < t; ++n) ssum += __expf(sim[t * 33 + n] - m);
    float inv = 1.f / ssum;
    float wck = 0.f;
    for (int n = 0; n < t; ++n) {
      float wk = __expf(sim[t * 33 + n] - m) * inv;
      wk_tbl[((size_t)b * 33 + t) * 33 + n] = wk;
      float ck = 1.f / (1.f + __expf(-(sim[t * 33 + n] * cg + cb2)));
      wck += wk * ck;
    }
    wck_tbl[b * 33 + t] = wck;
  }
}

// ---------------------------------------------------------------------------
// Persistent kernel: round-1-proven structure, grid.sync -> custom gbar.
// 256 blocks x 256 threads, 1 block/CU.
//   - gates-B slice (64 n' x 800 k bf16, 100 KiB) pinned in LDS for all steps
//   - activation tile streamed via global_load_lds (wave-uniform LDS bases)
//   - h-carry kept in registers across steps
//   - phase B: blocks 0..39 head GEMM (BK=64), blocks 40..255 attention reads
// ---------------------------------------------------------------------------
__global__ __launch_bounds__(256) void k_loop(
    unsigned short* __restrict__ xinA, unsigned short* __restrict__ xinB,
    const unsigned short* __restrict__ WT, const float* __restrict__ b_lstm,
    float* __restrict__ h, unsigned short* __restrict__ hbf,
    const unsigned short* __restrict__ Wk2T, const float* __restrict__ bias2,
    float* __restrict__ Mk, float* __restrict__ logits,
    const float* __restrict__ Wg, const float* __restrict__ bg,
    const float* __restrict__ wk_tbl, const float* __restrict__ wck_tbl,
    float* __restrict__ out, unsigned* __restrict__ bar) {
  __shared__ __align__(16) unsigned short Bres[64 * 800];  // 102400 B, resident
  __shared__ __align__(16) unsigned char scr[40960];       // A-chunks / Cs / head / read
  unsigned* cnt = bar;
  unsigned* gen = bar + 64;
  const int tid = threadIdx.x, bid = blockIdx.x;
  const int lane = tid & 63, w = tid >> 6;
  const int q = lane >> 4, r = lane & 15;
  const int wm = (w >> 1) * 32, wn = (w & 1) * 32;
  const int nn = bid & 31, mi = bid >> 5;  // gates tile
  const int m0 = mi * 64, n0g = nn * 64;

  // ---- pin gates weight slice in LDS (linear copy of WT rows n0g..n0g+63) ----
  for (int l = 0; l < 25; ++l) {
    int u = w * 12800 + l * 512;
    gl16(WT + (size_t)n0g * 800 + u + lane * 8, Bres + u);
  }

  // per-thread A-chunk coords (chunk = [64 rows][160 cols] bf16, linear in LDS)
  int arow[5], acol[5];
#pragma unroll
  for (int l = 0; l < 5; ++l) {
    int e = w * 2560 + l * 512 + lane * 8;
    arow[l] = e / 160; acol[l] = e - (e / 160) * 160;
  }

  const int jl = tid & 15, jg = nn * 16 + jl, rl0 = tid >> 4;
  const float bL0 = b_lstm[jg], bL1 = b_lstm[512 + jg],
              bL2 = b_lstm[1024 + jg], bL3 = b_lstm[1536 + jg];
  float hreg[4] = {0.f, 0.f, 0.f, 0.f};

  const int mi2 = bid / 5, ni2 = bid - mi2 * 5;  // head-GEMM tile (bid<40)

  asm volatile("s_waitcnt vmcnt(0)" ::: "memory");
  __syncthreads();

  for (int t = 0; t < 33; ++t) {
    const unsigned short* cur = (t & 1) ? xinB : xinA;
    unsigned short* nxt = (t & 1) ? xinA : xinB;

    // ================= phase A: gates GEMM (64x64, K=800) + LSTM cell ========
    unsigned short* A0 = (unsigned short*)scr;
    unsigned short* A1 = (unsigned short*)(scr + 20480);
#pragma unroll
    for (int l = 0; l < 5; ++l)  // prologue: chunk 0
      gl16(cur + (size_t)(m0 + arow[l]) * 800 + acol[l], A0 + w * 2560 + l * 512);
    f32x4 acc[2][2] = {};
    for (int c = 0; c < 5; ++c) {
      const unsigned short* Ac = (c & 1) ? A1 : A0;
      if (c < 4) {
        unsigned short* An = (c & 1) ? A0 : A1;
#pragma unroll
        for (int l = 0; l < 5; ++l)
          gl16(cur + (size_t)(m0 + arow[l]) * 800 + (c + 1) * 160 + acol[l],
               An + w * 2560 + l * 512);
        asm volatile("s_waitcnt vmcnt(5)" ::: "memory");  // chunk c landed
      } else {
        asm volatile("s_waitcnt vmcnt(0)" ::: "memory");
      }
      __builtin_amdgcn_s_barrier();
#pragma unroll
      for (int ks = 0; ks < 5; ++ks) {
        short8 a0 = *(const short8*)&Ac[(wm + r) * 160 + ks * 32 + q * 8];
        short8 a1 = *(const short8*)&Ac[(wm + 16 + r) * 160 + ks * 32 + q * 8];
        short8 b0 = *(const short8*)&Bres[(wn + r) * 800 + c * 160 + ks * 32 + q * 8];
        short8 b1 = *(const short8*)&Bres[(wn + 16 + r) * 800 + c * 160 + ks * 32 + q * 8];
        acc[0][0] = __builtin_amdgcn_mfma_f32_16x16x32_bf16(a0, b0, acc[0][0], 0, 0, 0);
        acc[0][1] = __builtin_amdgcn_mfma_f32_16x16x32_bf16(a0, b1, acc[0][1], 0, 0, 0);
        acc[1][0] = __builtin_amdgcn_mfma_f32_16x16x32_bf16(a1, b0, acc[1][0], 0, 0, 0);
        acc[1][1] = __builtin_amdgcn_mfma_f32_16x16x32_bf16(a1, b1, acc[1][1], 0, 0, 0);
      }
      asm volatile("s_waitcnt lgkmcnt(0)" ::: "memory");
      __builtin_amdgcn_s_barrier();  // buffer reuse guard
    }
    // ---- fused LSTM cell (h-carry in registers) ----
    float* Cs = (float*)scr;
#pragma unroll
    for (int mt = 0; mt < 2; ++mt)
#pragma unroll
      for (int nt = 0; nt < 2; ++nt)
#pragma unroll
        for (int e = 0; e < 4; ++e)
          Cs[(wm + mt * 16 + q * 4 + e) * 65 + wn + nt * 16 + r] = acc[mt][nt][e];
    __syncthreads();
#pragma unroll
    for (int it = 0; it < 4; ++it) {
      int rl = it * 16 + rl0;
      int brow = m0 + rl;
      float gi = Cs[rl * 65 + jl * 4 + 0] + bL0;
      float gf = Cs[rl * 65 + jl * 4 + 1] + bL1;
      float gc = Cs[rl * 65 + jl * 4 + 2] + bL2;
      float go = Cs[rl * 65 + jl * 4 + 3] + bL3;
      float cnew = sigm(gf) * hreg[it] + sigm(gi) * ftanh(gc);
      float hnew = sigm(go) * ftanh(cnew);
      hreg[it] = hnew;
      h[brow * 512 + jg] = hnew;
      hbf[brow * 512 + jg] = f2bf(hnew);
      nxt[brow * 800 + 288 + jg] = f2bf(cnew);
    }
    gbar(cnt, gen);

    // ================= phase B ==============================================
    if (bid < 40) {
      // head GEMM 64x64, K=512, BK=64, reg-prefetch double buffer
      const int LSTR2 = 72;
      unsigned short* As2 = (unsigned short*)scr;            // 2 x 4608 shorts
      unsigned short* Bs2 = (unsigned short*)(scr + 18432);  // 2 x 4608 shorts
      int m0b = mi2 * 64, n0b = ni2 * 64;
      int ldrow = tid >> 2, ldc = (tid & 3) * 16;
      const uint4* Ag = (const uint4*)(hbf + (size_t)(m0b + ldrow) * 512);
      const uint4* Bg = (const uint4*)(Wk2T + (size_t)(n0b + ldrow) * 512);
      uint4 ra0 = Ag[ldc >> 3], ra1 = Ag[(ldc >> 3) + 1];
      uint4 rb0 = Bg[ldc >> 3], rb1 = Bg[(ldc >> 3) + 1];
      f32x4 acc2[2][2] = {};
      int s = 0;
      *(uint4*)&As2[ldrow * LSTR2 + ldc] = ra0;
      *(uint4*)&As2[ldrow * LSTR2 + ldc + 8] = ra1;
      *(uint4*)&Bs2[ldrow * LSTR2 + ldc] = rb0;
      *(uint4*)&Bs2[ldrow * LSTR2 + ldc + 8] = rb1;
      __syncthreads();
      for (int kk = 0; kk < 8; ++kk) {
        if (kk < 7) {
          int k0 = (kk + 1) * 64;
          ra0 = Ag[(k0 + ldc) >> 3]; ra1 = Ag[((k0 + ldc) >> 3) + 1];
          rb0 = Bg[(k0 + ldc) >> 3]; rb1 = Bg[((k0 + ldc) >> 3) + 1];
        }
#pragma unroll
        for (int ks = 0; ks < 2; ++ks) {
          short8 a0 = *(const short8*)&As2[s * 4608 + (wm + r) * LSTR2 + ks * 32 + q * 8];
          short8 a1 = *(const short8*)&As2[s * 4608 + (wm + 16 + r) * LSTR2 + ks * 32 + q * 8];
          short8 b0 = *(const short8*)&Bs2[s * 4608 + (wn + r) * LSTR2 + ks * 32 + q * 8];
          short8 b1 = *(const short8*)&Bs2[s * 4608 + (wn + 16 + r) * LSTR2 + ks * 32 + q * 8];
          acc2[0][0] = __builtin_amdgcn_mfma_f32_16x16x32_bf16(a0, b0, acc2[0][0], 0, 0, 0);
          acc2[0][1] = __builtin_amdgcn_mfma_f32_16x16x32_bf16(a0, b1, acc2[0][1], 0, 0, 0);
          acc2[1][0] = __builtin_amdgcn_mfma_f32_16x16x32_bf16(a1, b0, acc2[1][0], 0, 0, 0);
          acc2[1][1] = __builtin_amdgcn_mfma_f32_16x16x32_bf16(a1, b1, acc2[1][1], 0, 0, 0);
        }
        if (kk < 7) {
          s ^= 1;
          *(uint4*)&As2[s * 4608 + ldrow * LSTR2 + ldc] = ra0;
          *(uint4*)&As2[s * 4608 + ldrow * LSTR2 + ldc + 8] = ra1;
          *(uint4*)&Bs2[s * 4608 + ldrow * LSTR2 + ldc] = rb0;
          *(uint4*)&Bs2[s * 4608 + ldrow * LSTR2 + ldc + 8] = rb1;
        }
        __syncthreads();
      }
#pragma unroll
      for (int mt = 0; mt < 2; ++mt)
#pragma unroll
        for (int nt = 0; nt < 2; ++nt)
#pragma unroll
          for (int e2 = 0; e2 < 4; ++e2) {
            int row = m0b + wm + mt * 16 + q * 4 + e2;
            int np = n0b + wn + nt * 16 + r;
            float v = acc2[mt][nt][e2] + bias2[np];
            if (np < 256) Mk[(size_t)(row * 33 + t) * 256 + np] = fmaxf(v, 0.f);
            else if (np >= 257 && np < 261) logits[row * 4 + (np - 257)] = v;
          }
    } else if (t > 0 && t < 32) {
      // attention read: g gate + weighted = sum_{n<t} wk * Mk -> key_r for t+1
      float* wkS = (float*)scr;
      float* red4 = (float*)(scr + 512);
      for (int rr = 0; rr < 3; ++rr) {
        int b = (bid - 40) + 216 * rr;
        if (b < 512) {
          float sd = h[b * 512 + tid] * Wg[tid] + h[b * 512 + 256 + tid] * Wg[256 + tid];
#pragma unroll
          for (int off = 32; off > 0; off >>= 1) sd += __shfl_down(sd, off);
          if (lane == 0) red4[w] = sd;
          if (tid < t) wkS[tid] = wk_tbl[((size_t)b * 33 + t) * 33 + tid];
          __syncthreads();
          float g = 1.f / (1.f + __expf(-(red4[0] + red4[1] + red4[2] + red4[3] + bg[0])));
          float p0 = 0.f, p1 = 0.f, p2 = 0.f, p3 = 0.f;
          int n = 0;
          for (; n + 4 <= t; n += 4) {
            p0 += wkS[n] * Mk[((size_t)b * 33 + n) * 256 + tid];
            p1 += wkS[n + 1] * Mk[((size_t)b * 33 + n + 1) * 256 + tid];
            p2 += wkS[n + 2] * Mk[((size_t)b * 33 + n + 2) * 256 + tid];
            p3 += wkS[n + 3] * Mk[((size_t)b * 33 + n + 3) * 256 + tid];
          }
          for (; n < t; ++n) p0 += wkS[n] * Mk[((size_t)b * 33 + n) * 256 + tid];
          nxt[b * 800 + tid] = f2bf(g * ((p0 + p1) + (p2 + p3)));
          if (tid == 0) nxt[b * 800 + 256] = f2bf(g * wck_tbl[b * 33 + t]);
          __syncthreads();
        }
      }
    }
    gbar(cnt, gen);
  }
  // final 4-wide softmax (block 0)
  if (bid == 0) {
    for (int r2 = tid; r2 < 512; r2 += 256) {
      float a = logits[r2 * 4], b2 = logits[r2 * 4 + 1],
            c2 = logits[r2 * 4 + 2], d2 = logits[r2 * 4 + 3];
      float m = fmaxf(fmaxf(a, b2), fmaxf(c2, d2));
      float ea = __expf(a - m), eb = __expf(b2 - m), ec = __expf(c2 - m), ed = __expf(d2 - m);
      float ssum = ea + eb + ec + ed;
      out[r2 * 4] = ea / ssum; out[r2 * 4 + 1] = eb / ssum;
      out[r2 * 4 + 2] = ec / ssum; out[r2 * 4 + 3] = ed / ssum;
    }
  }
}

// ---------------------------------------------------------------------------
// Fallback per-step kernels (used only if cooperative launch is unavailable).
// ---------------------------------------------------------------------------
__global__ __launch_bounds__(256) void k_gates(const unsigned short* __restrict__ xin,
                                               const unsigned short* __restrict__ WT,
                                               const float* __restrict__ b_lstm,
                                               float* __restrict__ h,
                                               unsigned short* __restrict__ hbf,
                                               unsigned short* __restrict__ xin_nxt) {
  __shared__ __align__(16) unsigned short As[2][64 * LSTR];
  __shared__ __align__(16) unsigned short Bs[2][64 * LSTR];
  __shared__ float Cs[64 * 65];
  int tid = threadIdx.x;
  int nn = blockIdx.x;
  int m0 = blockIdx.y * 64;
  int n0 = nn * 64;
  int lane = tid & 63, wid = tid >> 6;
  int wm = (wid >> 1) * 32, wn = (wid & 1) * 32;
  int q = lane >> 4, r = lane & 15;
  int ldrow = tid >> 2, ldc = (tid & 3) * 8;
  const uint4* Ag = reinterpret_cast<const uint4*>(xin + (size_t)(m0 + ldrow) * 800);
  const uint4* Bg = reinterpret_cast<const uint4*>(WT + (size_t)(n0 + ldrow) * 800);
  uint4 ra = Ag[ldc >> 3], rb = Bg[ldc >> 3];
  f32x4 acc[2][2] = {};
  int s = 0;
  *reinterpret_cast<uint4*>(&As[0][ldrow * LSTR + ldc]) = ra;
  *reinterpret_cast<uint4*>(&Bs[0][ldrow * LSTR + ldc]) = rb;
  __syncthreads();
  for (int kk = 0; kk < 25; ++kk) {
    if (kk < 24) {
      int k0 = (kk + 1) * 32;
      ra = Ag[(k0 + ldc) >> 3];
      rb = Bg[(k0 + ldc) >> 3];
    }
    short8 a0 = *reinterpret_cast<const short8*>(&As[s][(wm + r) * LSTR + q * 8]);
    short8 a1 = *reinterpret_cast<const short8*>(&As[s][(wm + 16 + r) * LSTR + q * 8]);
    short8 b0 = *reinterpret_cast<const short8*>(&Bs[s][(wn + r) * LSTR + q * 8]);
    short8 b1 = *reinterpret_cast<const short8*>(&Bs[s][(wn + 16 + r) * LSTR + q * 8]);
    acc[0][0] = __builtin_amdgcn_mfma_f32_16x16x32_bf16(a0, b0, acc[0][0], 0, 0, 0);
    acc[0][1] = __builtin_amdgcn_mfma_f32_16x16x32_bf16(a0, b1, acc[0][1], 0, 0, 0);
    acc[1][0] = __builtin_amdgcn_mfma_f32_16x16x32_bf16(a1, b0, acc[1][0], 0, 0, 0);
    acc[1][1] = __builtin_amdgcn_mfma_f32_16x16x32_bf16(a1, b1, acc[1][1], 0, 0, 0);
    if (kk < 24) {
      *reinterpret_cast<uint4*>(&As[s ^ 1][ldrow * LSTR + ldc]) = ra;
      *reinterpret_cast<uint4*>(&Bs[s ^ 1][ldrow * LSTR + ldc]) = rb;
      s ^= 1;
    }
    __syncthreads();
  }
#pragma unroll
  for (int mt = 0; mt < 2; ++mt)
#pragma unroll
    for (int nt = 0; nt < 2; ++nt)
#pragma unroll
      for (int e = 0; e < 4; ++e)
        Cs[(wm + mt * 16 + q * 4 + e) * 65 + wn + nt * 16 + r] = acc[mt][nt][e];
  __syncthreads();
#pragma unroll
  for (int it = 0; it < 4; ++it) {
    int id = it * 256 + tid;
    int rl = id >> 4, jl = id & 15;
    int brow = m0 + rl;
    int j = nn * 16 + jl;
    float gi = Cs[rl * 65 + jl * 4 + 0] + b_lstm[j];
    float gf = Cs[rl * 65 + jl * 4 + 1] + b_lstm[512 + j];
    float gg = Cs[rl * 65 + jl * 4 + 2] + b_lstm[1024 + j];
    float go = Cs[rl * 65 + jl * 4 + 3] + b_lstm[1536 + j];
    float hold = h[brow * 512 + j];
    float cnew = sigm(gf) * hold + sigm(gi) * ftanh(gg);
    float hnew = sigm(go) * ftanh(cnew);
    h[brow * 512 + j] = hnew;
    hbf[brow * 512 + j] = f2bf(hnew);
    xin_nxt[brow * 800 + 288 + j] = f2bf(cnew);
  }
}

__global__ __launch_bounds__(256) void k_head(const unsigned short* __restrict__ hbf,
                                              const unsigned short* __restrict__ Wk2T,
                                              const float* __restrict__ bias2,
                                              float* __restrict__ Mk,
                                              float* __restrict__ logits,
                                              const float* __restrict__ h,
                                              const float* __restrict__ Wg,
                                              const float* __restrict__ bg,
                                              const float* __restrict__ wk_tbl,
                                              const float* __restrict__ wck_tbl,
                                              unsigned short* __restrict__ xin_nxt,
                                              int t) {
  __shared__ __align__(16) unsigned short As[2][64 * LSTR];
  __shared__ __align__(16) unsigned short Bs[2][64 * LSTR];
  __shared__ float wkS[33];
  __shared__ float red[256];
  int bid = blockIdx.x;
  int tid = threadIdx.x;
  if (bid < 40) {
    int mi = bid / 5, ni = bid - mi * 5;
    int m0 = mi * 64, n0 = ni * 64;
    int lane = tid & 63, wid = tid >> 6;
    int wm = (wid >> 1) * 32, wn = (wid & 1) * 32;
    int q = lane >> 4, r = lane & 15;
    int ldrow = tid >> 2, ldc = (tid & 3) * 8;
    const uint4* Ag = reinterpret_cast<const uint4*>(hbf + (size_t)(m0 + ldrow) * 512);
    const uint4* Bg = reinterpret_cast<const uint4*>(Wk2T + (size_t)(n0 + ldrow) * 512);
    uint4 ra = Ag[ldc >> 3], rb = Bg[ldc >> 3];
    f32x4 acc[2][2] = {};
    int s = 0;
    *reinterpret_cast<uint4*>(&As[0][ldrow * LSTR + ldc]) = ra;
    *reinterpret_cast<uint4*>(&Bs[0][ldrow * LSTR + ldc]) = rb;
    __syncthreads();
    for (int kk = 0; kk < 16; ++kk) {
      if (kk < 15) {
        int k0 = (kk + 1) * 32;
        ra = Ag[(k0 + ldc) >> 3];
        rb = Bg[(k0 + ldc) >> 3];
      }
      short8 a0 = *reinterpret_cast<const short8*>(&As[s][(wm + r) * LSTR + q * 8]);
      short8 a1 = *reinterpret_cast<const short8*>(&As[s][(wm + 16 + r) * LSTR + q * 8]);
      short8 b0 = *reinterpret_cast<const short8*>(&Bs[s][(wn + r) * LSTR + q * 8]);
      short8 b1 = *reinterpret_cast<const short8*>(&Bs[s][(wn + 16 + r) * LSTR + q * 8]);
      acc[0][0] = __builtin_amdgcn_mfma_f32_16x16x32_bf16(a0, b0, acc[0][0], 0, 0, 0);
      acc[0][1] = __builtin_amdgcn_mfma_f32_16x16x32_bf16(a0, b1, acc[0][1], 0, 0, 0);
      acc[1][0] = __builtin_amdgcn_mfma_f32_16x16x32_bf16(a1, b0, acc[1][0], 0, 0, 0);
      acc[1][1] = __builtin_amdgcn_mfma_f32_16x16x32_bf16(a1, b1, acc[1][1], 0, 0, 0);
      if (kk < 15) {
        *reinterpret_cast<uint4*>(&As[s ^ 1][ldrow * LSTR + ldc]) = ra;
        *reinterpret_cast<uint4*>(&Bs[s ^ 1][ldrow * LSTR + ldc]) = rb;
        s ^= 1;
      }
      __syncthreads();
    }
#pragma unroll
    for (int mt = 0; mt < 2; ++mt)
#pragma unroll
      for (int nt = 0; nt < 2; ++nt)
#pragma unroll
        for (int e = 0; e < 4; ++e) {
          int row = m0 + wm + mt * 16 + q * 4 + e;
          int np = n0 + wn + nt * 16 + r;
          float v = acc[mt][nt][e] + bias2[np];
          if (np < 256) Mk[(size_t)(row * 33 + t) * 256 + np] = fmaxf(v, 0.f);
          else if (np >= 257 && np < 261) logits[row * 4 + (np - 257)] = v;
        }
  } else {
    if (t == 0 || t == 32) return;
    int b = bid - 40;
    float s = h[b * 512 + tid] * Wg[tid] + h[b * 512 + 256 + tid] * Wg[256 + tid];
    red[tid] = s;
    if (tid < t) wkS[tid] = wk_tbl[((size_t)b * 33 + t) * 33 + tid];
    __syncthreads();
    for (int off = 128; off > 0; off >>= 1) {
      if (tid < off) red[tid] += red[tid + off];
      __syncthreads();
    }
    float g = 1.f / (1.f + __expf(-(red[0] + bg[0])));
    float acc = 0.f;
    for (int n = 0; n < t; ++n) acc += wkS[n] * Mk[((size_t)b * 33 + n) * 256 + tid];
    xin_nxt[b * 800 + tid] = f2bf(g * acc);
    if (tid == 0) xin_nxt[b * 800 + 256] = f2bf(g * wck_tbl[b * 33 + t]);
  }
}

__global__ void k_softmax(const float* __restrict__ logits, float* __restrict__ out) {
  int tid = threadIdx.x;
  for (int r2 = tid; r2 < 512; r2 += 256) {
    float a = logits[r2 * 4], b = logits[r2 * 4 + 1], c = logits[r2 * 4 + 2], d = logits[r2 * 4 + 3];
    float m = fmaxf(fmaxf(a, b), fmaxf(c, d));
    float ea = __expf(a - m), eb = __expf(b - m), ec = __expf(c - m), ed = __expf(d - m);
    float s = ea + eb + ec + ed;
    out[r2 * 4] = ea / s; out[r2 * 4 + 1] = eb / s;
    out[r2 * 4 + 2] = ec / s; out[r2 * 4 + 3] = ed / s;
  }
}

extern "C" void kernel_launch(void* const* d_in, const int* in_sizes, int n_in,
                              void* d_out, int out_size, void* d_ws, size_t ws_size,
                              hipStream_t stream) {
  const float* x_seq = (const float*)d_in[0];
  const float* W_enc = (const float*)d_in[1];
  const float* b_enc = (const float*)d_in[2];
  const float* W_lstm = (const float*)d_in[3];
  const float* U_lstm = (const float*)d_in[4];
  const float* b_lstm = (const float*)d_in[5];
  const float* W_key = (const float*)d_in[6];
  const float* b_key = (const float*)d_in[7];
  const float* W_g = (const float*)d_in[8];
  const float* b_g = (const float*)d_in[9];
  const float* W_y = (const float*)d_in[10];
  const float* b_y = (const float*)d_in[11];
  const float* gamma = (const float*)d_in[12];
  const float* beta = (const float*)d_in[13];
  const float* cg_ = (const float*)d_in[14];
  const float* cb = (const float*)d_in[15];

  char* p = (char*)d_ws;
  auto alloc = [&](size_t bytes) {
    char* r = p;
    p += (bytes + 255) & ~(size_t)255;
    return r;
  };
  float* zbuf = (float*)alloc((size_t)16384 * 128 * 4);
  float* z_full = (float*)alloc((size_t)512 * 33 * 128 * 4);
  unsigned short* WcombT = (unsigned short*)alloc((size_t)2048 * 800 * 2);
  unsigned short* WencT = (unsigned short*)alloc((size_t)128 * 1024 * 2);
  unsigned short* Wk2T = (unsigned short*)alloc((size_t)320 * 512 * 2);
  float* bias2 = (float*)alloc(320 * 4);
  unsigned short* xinA = (unsigned short*)alloc((size_t)512 * 800 * 2);
  unsigned short* xinB = (unsigned short*)alloc((size_t)512 * 800 * 2);
  float* h = (float*)alloc((size_t)512 * 512 * 4);
  unsigned short* hbf = (unsigned short*)alloc((size_t)512 * 512 * 2);
  float* Mk = (float*)alloc((size_t)512 * 33 * 256 * 4);
  float* logits = (float*)alloc((size_t)512 * 4 * 4);
  float* wk_tbl = (float*)alloc((size_t)512 * 33 * 33 * 4);
  float* wck_tbl = (float*)alloc((size_t)512 * 33 * 4);
  unsigned* bar = (unsigned*)alloc(1024);
  float* outp = (float*)d_out;

  const int prep_total = 2048 * 800 + 320 * 512 + 128 * 1024 + 320 + 2 * 512 * 800 +
                         512 * 512 + 512 * 128 + 256;
  k_prep<<<(prep_total + 255) / 256, 256, 0, stream>>>(
      W_lstm, U_lstm, W_enc, W_key, W_g, W_y, b_key, b_g, b_y,
      WcombT, Wk2T, WencT, bias2, xinA, xinB, h, z_full, bar);
  k_enc<<<256, 512, 0, stream>>>(x_seq, WencT, b_enc, zbuf);
  k_ln<<<256, 256, 0, stream>>>(zbuf, gamma, beta, z_full);
  k_attnpre<<<512, 256, 0, stream>>>(z_full, cg_, cb, wk_tbl, wck_tbl);

  void* cargs[16];
  cargs[0] = &xinA;  cargs[1] = &xinB;   cargs[2] = &WcombT; cargs[3] = &b_lstm;
  cargs[4] = &h;     cargs[5] = &hbf;    cargs[6] = &Wk2T;   cargs[7] = &bias2;
  cargs[8] = &Mk;    cargs[9] = &logits; cargs[10] = &W_g;   cargs[11] = &b_g;
  cargs[12] = &wk_tbl; cargs[13] = &wck_tbl; cargs[14] = &outp; cargs[15] = &bar;
  hipError_t ce = hipLaunchCooperativeKernel((const void*)k_loop, dim3(256), dim3(256),
                                             cargs, 0u, stream);
  if (ce != hipSuccess) {
    // fallback: per-step launches (previous verified path)
    for (int t = 0; t < 33; ++t) {
      unsigned short* cur = (t & 1) ? xinB : xinA;
      unsigned short* nxt = (t & 1) ? xinA : xinB;
      k_gates<<<dim3(32, 8), 256, 0, stream>>>(cur, WcombT, b_lstm, h, hbf, nxt);
      k_head<<<552, 256, 0, stream>>>(hbf, Wk2T, bias2, Mk, logits, h,
                                      W_g, b_g, wk_tbl, wck_tbl, nxt, t);
    }
    k_softmax<<<1, 256, 0, stream>>>(logits, outp);
  }
}

// Round 4
// 840.901 us; speedup vs baseline: 3.0784x; 2.1376x over previous
//
#include <hip/hip_runtime.h>

typedef __attribute__((ext_vector_type(8))) short short8;
typedef __attribute__((ext_vector_type(4))) float f32x4;
typedef __attribute__((ext_vector_type(8))) unsigned short ushort8;
typedef __attribute__((ext_vector_type(4))) unsigned short ushort4v;

__device__ __forceinline__ unsigned short f2bf(float f) {
  union { float f; unsigned u; } v; v.f = f;
  unsigned u = v.u;
  u += 0x7fffu + ((u >> 16) & 1u);
  return (unsigned short)(u >> 16);
}
__device__ __forceinline__ float sigm(float x) { return 1.f / (1.f + __expf(-x)); }
__device__ __forceinline__ float ftanh(float x) { return 1.f - 2.f / (__expf(2.f * x) + 1.f); }

// async global->LDS, 16B per lane. LDS dest must be WAVE-UNIFORM base; HW adds lane*16.
__device__ __forceinline__ void gl16(const unsigned short* g, unsigned short* l) {
  __builtin_amdgcn_global_load_lds((const __attribute__((address_space(1))) void*)g,
                                   (__attribute__((address_space(3))) void*)l, 16, 0, 0);
}

// ---- coherent (system-scope, performed at Infinity Cache) access helpers ----
__device__ __forceinline__ uint4 ld16_sys(const void* base, int off) {
  uint4 r;
  asm volatile("global_load_dwordx4 %0, %1, %2 sc0 sc1"
               : "=v"(r) : "v"(off), "s"(base) : "memory");
  return r;
}
__device__ __forceinline__ uint4 ld16_asm(const void* base, int off) {  // plain, asm-counted
  uint4 r;
  asm volatile("global_load_dwordx4 %0, %1, %2"
               : "=v"(r) : "v"(off), "s"(base) : "memory");
  return r;
}
__device__ __forceinline__ float ldf_sys(const void* base, int off) {
  float r;
  asm volatile("global_load_dword %0, %1, %2 sc0 sc1"
               : "=v"(r) : "v"(off), "s"(base) : "memory");
  return r;
}
__device__ __forceinline__ void stf_sys(void* base, int off, float v) {
  asm volatile("global_store_dword %0, %1, %2 sc0 sc1"
               :: "v"(off), "v"(v), "s"(base) : "memory");
}
__device__ __forceinline__ void sth_sys(void* base, int off, unsigned short v) {
  asm volatile("global_store_short %0, %1, %2 sc0 sc1"
               :: "v"(off), "v"(v), "s"(base) : "memory");
}
#define WAITVM(N)                                          \
  asm volatile("s_waitcnt vmcnt(" #N ")" ::: "memory");    \
  __builtin_amdgcn_sched_barrier(0)

// Fence-free grid barrier: data exchange is via sc0/sc1 accesses (coherent at
// the mall), so no L2 writeback/invalidate is needed. bar[0]=cnt, bar[64]=gen.
__device__ __forceinline__ void gbar(unsigned* cnt, unsigned* gen) {
  asm volatile("s_waitcnt vmcnt(0)" ::: "memory");  // drain asm sc1 stores (all threads)
  __syncthreads();
  if (threadIdx.x == 0) {
    unsigned g = __hip_atomic_load(gen, __ATOMIC_RELAXED, __HIP_MEMORY_SCOPE_AGENT);
    unsigned a = __hip_atomic_fetch_add(cnt, 1u, __ATOMIC_RELAXED, __HIP_MEMORY_SCOPE_AGENT);
    if (a == 255u) {
      __hip_atomic_store(cnt, 0u, __ATOMIC_RELAXED, __HIP_MEMORY_SCOPE_AGENT);
      __hip_atomic_store(gen, g + 1u, __ATOMIC_RELAXED, __HIP_MEMORY_SCOPE_AGENT);
    } else {
      while (__hip_atomic_load(gen, __ATOMIC_RELAXED, __HIP_MEMORY_SCOPE_AGENT) == g)
        __builtin_amdgcn_s_sleep(2);
    }
  }
  __syncthreads();
}

#define LSTR 40  // LDS row stride (elems) for the prologue GEMM

// ---------------------------------------------------------------------------
// Prep: build bf16 transposed/permuted weights, zero state buffers + barrier.
// ---------------------------------------------------------------------------
__global__ void k_prep(const float* __restrict__ W_lstm, const float* __restrict__ U_lstm,
                       const float* __restrict__ W_enc, const float* __restrict__ W_key,
                       const float* __restrict__ W_g, const float* __restrict__ W_y,
                       const float* __restrict__ b_key, const float* __restrict__ b_g,
                       const float* __restrict__ b_y,
                       unsigned short* __restrict__ WcombT, unsigned short* __restrict__ Wk2T,
                       unsigned short* __restrict__ WencT, float* __restrict__ bias2,
                       unsigned short* __restrict__ xinA, unsigned short* __restrict__ xinB,
                       float* __restrict__ h, float* __restrict__ z_full,
                       unsigned* __restrict__ bar) {
  const int N1 = 2048 * 800, N2 = 320 * 512, N3 = 128 * 1024, N4 = 320,
            N5 = 512 * 800, N7 = 512 * 512, N8 = 512 * 128, N9 = 256;
  int i = blockIdx.x * 256 + threadIdx.x;
  if (i < N1) {
    int np = i / 800, k = i - np * 800;
    int j = np >> 2, gate = np & 3, n = gate * 512 + j;
    float v = 0.f;
    if (k < 257) v = W_lstm[k * 2048 + n];
    else if (k >= 288) v = U_lstm[(k - 288) * 2048 + n];
    WcombT[i] = f2bf(v);
    return;
  }
  i -= N1;
  if (i < N2) {
    int n = i / 512, k = i - n * 512;
    float v = 0.f;
    if (n < 256) v = W_key[k * 256 + n];
    else if (n == 256) v = W_g[k];
    else if (n < 261) v = W_y[k * 4 + (n - 257)];
    Wk2T[i] = f2bf(v);
    return;
  }
  i -= N2;
  if (i < N3) {
    int n = i / 1024, k = i - n * 1024;
    WencT[i] = f2bf(W_enc[k * 128 + n]);
    return;
  }
  i -= N3;
  if (i < N4) {
    float v = (i < 256) ? b_key[i] : (i == 256 ? b_g[0] : (i < 261 ? b_y[i - 257] : 0.f));
    bias2[i] = v;
    return;
  }
  i -= N4;
  if (i < N5) { xinA[i] = 0; return; }
  i -= N5;
  if (i < N5) { xinB[i] = 0; return; }
  i -= N5;
  if (i < N7) { h[i] = 0.f; return; }
  i -= N7;
  if (i < N8) {
    int b = i >> 7, z = i & 127;
    z_full[(b * 33 + 32) * 128 + z] = 0.f;  // null slot
    return;
  }
  i -= N8;
  if (i < N9) bar[i] = 0;
}

// ---------------------------------------------------------------------------
// Encoder GEMM (proven): 64Mx128N tile, BK=32, K=1024, 512 threads.
// ---------------------------------------------------------------------------
__global__ __launch_bounds__(512) void k_enc(const float* __restrict__ x,
                                             const unsigned short* __restrict__ WencT,
                                             const float* __restrict__ b_enc,
                                             float* __restrict__ zbuf) {
  __shared__ __align__(16) unsigned short As[2][64 * LSTR];
  __shared__ __align__(16) unsigned short Bs[2][128 * LSTR];
  int tid = threadIdx.x;
  int m0 = blockIdx.x * 64;
  int lane = tid & 63, wid = tid >> 6;
  int wm = (wid >> 2) * 32, wn = (wid & 3) * 32;
  int q = lane >> 4, r = lane & 15;
  int ldrowA = tid >> 3, ldcA = (tid & 7) * 4;
  int ldrowB = tid >> 2, ldcB = (tid & 3) * 8;
  const float4* Ag = reinterpret_cast<const float4*>(x + (size_t)(m0 + ldrowA) * 1024);
  const uint4* Bg = reinterpret_cast<const uint4*>(WencT + (size_t)ldrowB * 1024);
  float4 ra = Ag[ldcA >> 2];
  uint4 rb = Bg[ldcB >> 3];
  f32x4 acc[2][2] = {};
  int s = 0;
  {
    ushort4v t4;
    t4[0] = f2bf(ra.x); t4[1] = f2bf(ra.y); t4[2] = f2bf(ra.z); t4[3] = f2bf(ra.w);
    *reinterpret_cast<ushort4v*>(&As[0][ldrowA * LSTR + ldcA]) = t4;
    *reinterpret_cast<uint4*>(&Bs[0][ldrowB * LSTR + ldcB]) = rb;
  }
  __syncthreads();
  for (int kk = 0; kk < 32; ++kk) {
    if (kk < 31) {
      int k0 = (kk + 1) * 32;
      ra = Ag[(k0 + ldcA) >> 2];
      rb = Bg[(k0 + ldcB) >> 3];
    }
    short8 a0 = *reinterpret_cast<const short8*>(&As[s][(wm + r) * LSTR + q * 8]);
    short8 a1 = *reinterpret_cast<const short8*>(&As[s][(wm + 16 + r) * LSTR + q * 8]);
    short8 b0 = *reinterpret_cast<const short8*>(&Bs[s][(wn + r) * LSTR + q * 8]);
    short8 b1 = *reinterpret_cast<const short8*>(&Bs[s][(wn + 16 + r) * LSTR + q * 8]);
    acc[0][0] = __builtin_amdgcn_mfma_f32_16x16x32_bf16(a0, b0, acc[0][0], 0, 0, 0);
    acc[0][1] = __builtin_amdgcn_mfma_f32_16x16x32_bf16(a0, b1, acc[0][1], 0, 0, 0);
    acc[1][0] = __builtin_amdgcn_mfma_f32_16x16x32_bf16(a1, b0, acc[1][0], 0, 0, 0);
    acc[1][1] = __builtin_amdgcn_mfma_f32_16x16x32_bf16(a1, b1, acc[1][1], 0, 0, 0);
    if (kk < 31) {
      ushort4v t4;
      t4[0] = f2bf(ra.x); t4[1] = f2bf(ra.y); t4[2] = f2bf(ra.z); t4[3] = f2bf(ra.w);
      *reinterpret_cast<ushort4v*>(&As[s ^ 1][ldrowA * LSTR + ldcA]) = t4;
      *reinterpret_cast<uint4*>(&Bs[s ^ 1][ldrowB * LSTR + ldcB]) = rb;
      s ^= 1;
    }
    __syncthreads();
  }
#pragma unroll
  for (int mt = 0; mt < 2; ++mt)
#pragma unroll
    for (int nt = 0; nt < 2; ++nt)
#pragma unroll
      for (int e = 0; e < 4; ++e) {
        int row = m0 + wm + mt * 16 + q * 4 + e;
        int col = wn + nt * 16 + r;
        zbuf[(size_t)row * 128 + col] = fmaxf(acc[mt][nt][e] + b_enc[col], 0.f);
      }
}

// ---------------------------------------------------------------------------
// LayerNorm over the BATCH axis per (t,z).
// ---------------------------------------------------------------------------
__global__ __launch_bounds__(256) void k_ln(const float* __restrict__ zbuf,
                                            const float* __restrict__ gamma,
                                            const float* __restrict__ beta,
                                            float* __restrict__ z_full) {
  int bid = blockIdx.x;
  int tstep = bid >> 3;
  int z0 = (bid & 7) * 16;
  int tid = threadIdx.x;
  int zl = tid & 15, bg = tid >> 4;
  __shared__ float ps[256], qs[256];
  __shared__ float muS[16], rsS[16];
  float s = 0.f, ss = 0.f;
  for (int ii = 0; ii < 32; ++ii) {
    int b = bg * 32 + ii;
    float v = zbuf[(size_t)(b * 32 + tstep) * 128 + z0 + zl];
    s += v; ss += v * v;
  }
  ps[tid] = s; qs[tid] = ss;
  __syncthreads();
  if (tid < 16) {
    float S = 0.f, Q = 0.f;
    for (int g2 = 0; g2 < 16; ++g2) { S += ps[g2 * 16 + tid]; Q += qs[g2 * 16 + tid]; }
    float mu = S / 512.f;
    float var = Q / 512.f - mu * mu;
    muS[tid] = mu;
    rsS[tid] = rsqrtf(var + 1e-8f);
  }
  __syncthreads();
  float ga = gamma[z0 + zl], be = beta[z0 + zl];
  float mu = muS[zl], rs = rsS[zl];
  for (int ii = 0; ii < 32; ++ii) {
    int b = bg * 32 + ii;
    float v = zbuf[(size_t)(b * 32 + tstep) * 128 + z0 + zl];
    z_full[(size_t)(b * 33 + tstep) * 128 + z0 + zl] = (v - mu) * rs * ga + be;
  }
}

// ---------------------------------------------------------------------------
// Attention precompute (w_k and wck for all t, once).
// ---------------------------------------------------------------------------
__global__ __launch_bounds__(256) void k_attnpre(const float* __restrict__ z_full,
                                                 const float* __restrict__ cgain,
                                                 const float* __restrict__ cbias,
                                                 float* __restrict__ wk_tbl,
                                                 float* __restrict__ wck_tbl) {
  __shared__ float zs[33 * 128];
  __shared__ float sim[33 * 33];
  int b = blockIdx.x, tid = threadIdx.x;
  const float* zb = z_full + (size_t)b * 33 * 128;
  for (int i = tid; i < 33 * 128; i += 256) zs[i] = zb[i];
  __syncthreads();
  for (int p = tid; p < 33 * 33; p += 256) {
    int t = p / 33, n = p - t * 33;
    float s = 0.f;
    if (n < t) {
#pragma unroll 8
      for (int k2 = 0; k2 < 128; ++k2) s += zs[t * 128 + k2] * zs[n * 128 + k2];
    }
    sim[p] = s;
  }
  __syncthreads();
  if (tid >= 1 && tid < 33) {
    int t = tid;
    float cg = cgain[0], cb2 = cbias[0];
    float m = -3.0e38f;
    for (int n = 0; n < t; ++n) m = fmaxf(m, sim[t * 33 + n]);
    float ssum = 0.f;
    for (int n = 0; n < t; ++n) ssum += __expf(sim[t * 33 + n] - m);
    float inv = 1.f / ssum;
    float wck = 0.f;
    for (int n = 0; n < t; ++n) {
      float wk = __expf(sim[t * 33 + n] - m) * inv;
      wk_tbl[((size_t)b * 33 + t) * 33 + n] = wk;
      float ck = 1.f / (1.f + __expf(-(sim[t * 33 + n] * cg + cb2)));
      wck += wk * ck;
    }
    wck_tbl[b * 33 + t] = wck;
  }
}

// ---------------------------------------------------------------------------
// Persistent kernel, fence-free barriers + coherent sc0/sc1 data exchange.
// 256 blocks x 256 threads, 1 block/CU.
//   Bres: gates weights pinned in LDS, stride 808 (2-way banks, free)
//   A-tile: reg-staged sc1 loads -> ds_write, stride 168 (2-way banks)
//   head GEMM: LDS-free, reg fragments, depth-3 pipeline, counted vmcnt
// ---------------------------------------------------------------------------
__global__ __launch_bounds__(256) void k_loop(
    unsigned short* __restrict__ xinA, unsigned short* __restrict__ xinB,
    const unsigned short* __restrict__ WT, const float* __restrict__ b_lstm,
    float* __restrict__ h, unsigned short* __restrict__ hbf,
    const unsigned short* __restrict__ Wk2T, const float* __restrict__ bias2,
    float* __restrict__ Mk, float* __restrict__ logits,
    const float* __restrict__ Wg, const float* __restrict__ bg,
    const float* __restrict__ wk_tbl, const float* __restrict__ wck_tbl,
    float* __restrict__ out, unsigned* __restrict__ bar) {
  __shared__ __align__(16) unsigned short Bres[64 * 808];  // 103424 B, resident
  __shared__ __align__(16) unsigned char scr[43136];       // A0 / A1 (stride-168), Cs, wkS
  unsigned* cnt = bar;
  unsigned* gen = bar + 64;
  const int tid = threadIdx.x, bid = blockIdx.x;
  const int lane = tid & 63, w = tid >> 6;
  const int q = lane >> 4, r = lane & 15;
  const int wm = (w >> 1) * 32, wn = (w & 1) * 32;
  const int nn = bid & 31, mi = bid >> 5;  // gates tile
  const int m0 = mi * 64, n0g = nn * 64;

  // ---- pin B slice (static): 64 rows x 808 (800 data + 8 pad), via gl16 with
  // wave-uniform LDS base + per-lane pre-swizzled global source. 6464 granules.
  for (int l = 0; l < 26; ++l) {
    int gw = l * 256 + w * 64;  // wave-uniform granule base
    if (gw < 6464) {
      int g = gw + lane;
      int row = g / 101, cg = g - row * 101;
      int col = (cg >= 100) ? 792 : cg * 8;  // pad granule: load junk (unread)
      gl16(WT + (size_t)(n0g + row) * 800 + col, Bres + gw * 8);
    }
  }

  // per-thread A-stage coords: 1280 data granules = 5 x 256 (row-major 64x160)
  int srow[5], scol[5];
#pragma unroll
  for (int l = 0; l < 5; ++l) {
    int idx = l * 256 + tid;
    srow[l] = idx / 20;
    scol[l] = (idx - srow[l] * 20) * 8;
  }
  unsigned short* A0 = (unsigned short*)scr;             // 64*168*2 = 21504 B
  unsigned short* A1 = (unsigned short*)(scr + 21504);   // 21504 B

  const int jl = tid & 15, jg = nn * 16 + jl, rl0 = tid >> 4;
  const float bL0 = b_lstm[jg], bL1 = b_lstm[512 + jg],
              bL2 = b_lstm[1024 + jg], bL3 = b_lstm[1536 + jg];
  float hreg[4] = {0.f, 0.f, 0.f, 0.f};

  const int mi2 = bid / 5, ni2 = bid - mi2 * 5;  // head-GEMM tile (bid<40)

  asm volatile("s_waitcnt vmcnt(0)" ::: "memory");
  __syncthreads();

  for (int t = 0; t < 33; ++t) {
    const unsigned short* cur = (t & 1) ? xinB : xinA;
    unsigned short* nxt = (t & 1) ? xinA : xinB;

    // ====== phase A: gates GEMM (64x64, K=800=5x160) + LSTM cell =============
    uint4 R[5];
#pragma unroll
    for (int l = 0; l < 5; ++l)  // prologue: chunk 0 (coherent: xin is remote-written)
      R[l] = ld16_sys(cur, ((m0 + srow[l]) * 800 + scol[l]) * 2);
    asm volatile("s_waitcnt vmcnt(0)" ::: "memory");
    __builtin_amdgcn_sched_barrier(0);
#pragma unroll
    for (int l = 0; l < 5; ++l)
      *(uint4*)&A0[srow[l] * 168 + scol[l]] = R[l];
    __syncthreads();

    f32x4 acc[2][2] = {};
    for (int c = 0; c < 5; ++c) {
      const unsigned short* Ac = (c & 1) ? A1 : A0;
      unsigned short* An = (c & 1) ? A0 : A1;
      if (c < 4) {
#pragma unroll
        for (int l = 0; l < 5; ++l)
          R[l] = ld16_sys(cur, ((m0 + srow[l]) * 800 + (c + 1) * 160 + scol[l]) * 2);
      }
#pragma unroll
      for (int ks = 0; ks < 5; ++ks) {
        short8 a0 = *(const short8*)&Ac[(wm + r) * 168 + ks * 32 + q * 8];
        short8 a1 = *(const short8*)&Ac[(wm + 16 + r) * 168 + ks * 32 + q * 8];
        short8 b0 = *(const short8*)&Bres[(wn + r) * 808 + c * 160 + ks * 32 + q * 8];
        short8 b1 = *(const short8*)&Bres[(wn + 16 + r) * 808 + c * 160 + ks * 32 + q * 8];
        acc[0][0] = __builtin_amdgcn_mfma_f32_16x16x32_bf16(a0, b0, acc[0][0], 0, 0, 0);
        acc[0][1] = __builtin_amdgcn_mfma_f32_16x16x32_bf16(a0, b1, acc[0][1], 0, 0, 0);
        acc[1][0] = __builtin_amdgcn_mfma_f32_16x16x32_bf16(a1, b0, acc[1][0], 0, 0, 0);
        acc[1][1] = __builtin_amdgcn_mfma_f32_16x16x32_bf16(a1, b1, acc[1][1], 0, 0, 0);
      }
      if (c < 4) {
        asm volatile("s_waitcnt vmcnt(0)" ::: "memory");
        __builtin_amdgcn_sched_barrier(0);
#pragma unroll
        for (int l = 0; l < 5; ++l)
          *(uint4*)&An[srow[l] * 168 + scol[l]] = R[l];
        __syncthreads();
      }
    }
    __syncthreads();  // drain last buffer reads before Cs overwrites A0

    // ---- fused LSTM cell (h-carry in registers; coherent stores) ----
    float* Cs = (float*)scr;
#pragma unroll
    for (int mt = 0; mt < 2; ++mt)
#pragma unroll
      for (int nt = 0; nt < 2; ++nt)
#pragma unroll
        for (int e = 0; e < 4; ++e)
          Cs[(wm + mt * 16 + q * 4 + e) * 65 + wn + nt * 16 + r] = acc[mt][nt][e];
    __syncthreads();
#pragma unroll
    for (int it = 0; it < 4; ++it) {
      int rl = it * 16 + rl0;
      int brow = m0 + rl;
      float gi = Cs[rl * 65 + jl * 4 + 0] + bL0;
      float gf = Cs[rl * 65 + jl * 4 + 1] + bL1;
      float gc = Cs[rl * 65 + jl * 4 + 2] + bL2;
      float go = Cs[rl * 65 + jl * 4 + 3] + bL3;
      float cnew = sigm(gf) * hreg[it] + sigm(gi) * ftanh(gc);
      float hnew = sigm(go) * ftanh(cnew);
      hreg[it] = hnew;
      stf_sys(h, (brow * 512 + jg) * 4, hnew);
      sth_sys(hbf, (brow * 512 + jg) * 2, f2bf(hnew));
      sth_sys(nxt, (brow * 800 + 288 + jg) * 2, f2bf(cnew));
    }
    gbar(cnt, gen);

    // ====== phase B ==========================================================
    if (bid < 40) {
      // head GEMM 64x64, K=512: LDS-free, depth-3 reg pipeline, counted vmcnt.
      int m0b = mi2 * 64, n0b = ni2 * 64;
      int aoff0 = ((m0b + wm + r) * 512 + q * 8) * 2;
      int aoff1 = aoff0 + 16 * 1024;
      int boff0 = ((n0b + wn + r) * 512 + q * 8) * 2;
      int boff1 = boff0 + 16 * 1024;
      uint4 ab[4][2], bb[4][2];
      f32x4 acc2[2][2] = {};
#pragma unroll
      for (int j = 0; j < 3; ++j) {
        ab[j][0] = ld16_sys(hbf, aoff0 + j * 64);   // hbf: remote-written -> sc1
        ab[j][1] = ld16_sys(hbf, aoff1 + j * 64);
        bb[j][0] = ld16_asm(Wk2T, boff0 + j * 64);  // Wk2T: static -> plain (L2)
        bb[j][1] = ld16_asm(Wk2T, boff1 + j * 64);
      }
#pragma unroll
      for (int kk = 0; kk < 16; ++kk) {
        if (kk < 13) {
          int j = kk + 3;
          ab[j & 3][0] = ld16_sys(hbf, aoff0 + j * 64);
          ab[j & 3][1] = ld16_sys(hbf, aoff1 + j * 64);
          bb[j & 3][0] = ld16_asm(Wk2T, boff0 + j * 64);
          bb[j & 3][1] = ld16_asm(Wk2T, boff1 + j * 64);
        }
        if (kk < 13) { WAITVM(12); }
        else if (kk == 13) { WAITVM(8); }
        else if (kk == 14) { WAITVM(4); }
        else { WAITVM(0); }
        short8 a0 = *(const short8*)&ab[kk & 3][0];
        short8 a1 = *(const short8*)&ab[kk & 3][1];
        short8 b0s = *(const short8*)&bb[kk & 3][0];
        short8 b1s = *(const short8*)&bb[kk & 3][1];
        acc2[0][0] = __builtin_amdgcn_mfma_f32_16x16x32_bf16(a0, b0s, acc2[0][0], 0, 0, 0);
        acc2[0][1] = __builtin_amdgcn_mfma_f32_16x16x32_bf16(a0, b1s, acc2[0][1], 0, 0, 0);
        acc2[1][0] = __builtin_amdgcn_mfma_f32_16x16x32_bf16(a1, b0s, acc2[1][0], 0, 0, 0);
        acc2[1][1] = __builtin_amdgcn_mfma_f32_16x16x32_bf16(a1, b1s, acc2[1][1], 0, 0, 0);
      }
#pragma unroll
      for (int mt = 0; mt < 2; ++mt)
#pragma unroll
        for (int nt = 0; nt < 2; ++nt)
#pragma unroll
          for (int e2 = 0; e2 < 4; ++e2) {
            int row = m0b + wm + mt * 16 + q * 4 + e2;
            int np = n0b + wn + nt * 16 + r;
            float v = acc2[mt][nt][e2] + bias2[np];
            if (np < 256)
              stf_sys(Mk, ((row * 33 + t) * 256 + np) * 4, fmaxf(v, 0.f));
            else if (np >= 257 && np < 261)
              stf_sys(logits, (row * 4 + (np - 257)) * 4, v);
          }
    } else if (t > 0 && t < 32) {
      // attention read. h: sc1 (stale-L2 hazard). Mk: plain (first-touch-after-
      // write lines -> coherent; L2-cached across later steps). wk_tbl: static.
      float* wkS = (float*)scr;
      float* red4 = (float*)(scr + 512);
      int b0 = bid - 40, b1 = b0 + 216, b2 = b0 + 432;
      bool v2 = (b2 < 512);
      int b2s = v2 ? b2 : b0;
      float hv[3][2];
      hv[0][0] = ldf_sys(h, (b0 * 512 + tid) * 4);
      hv[0][1] = ldf_sys(h, (b0 * 512 + 256 + tid) * 4);
      hv[1][0] = ldf_sys(h, (b1 * 512 + tid) * 4);
      hv[1][1] = ldf_sys(h, (b1 * 512 + 256 + tid) * 4);
      hv[2][0] = ldf_sys(h, (b2s * 512 + tid) * 4);
      hv[2][1] = ldf_sys(h, (b2s * 512 + 256 + tid) * 4);
      asm volatile("s_waitcnt vmcnt(0)" ::: "memory");
      __builtin_amdgcn_sched_barrier(0);
      float wg0 = Wg[tid], wg1 = Wg[256 + tid], bgv = bg[0];
#pragma unroll
      for (int rr = 0; rr < 3; ++rr) {
        int b = (rr == 0) ? b0 : (rr == 1) ? b1 : b2s;
        bool wr = (rr < 2) || v2;
        float sd = hv[rr][0] * wg0 + hv[rr][1] * wg1;
#pragma unroll
        for (int off = 32; off > 0; off >>= 1) sd += __shfl_down(sd, off);
        if (lane == 0) red4[w] = sd;
        if (tid < t) wkS[tid] = wk_tbl[((size_t)b * 33 + t) * 33 + tid];
        __syncthreads();
        float g = 1.f / (1.f + __expf(-(red4[0] + red4[1] + red4[2] + red4[3] + bgv)));
        float p0 = 0.f, p1 = 0.f, p2 = 0.f, p3 = 0.f;
        int n = 0;
        for (; n + 4 <= t; n += 4) {
          p0 += wkS[n] * Mk[((size_t)b * 33 + n) * 256 + tid];
          p1 += wkS[n + 1] * Mk[((size_t)b * 33 + n + 1) * 256 + tid];
          p2 += wkS[n + 2] * Mk[((size_t)b * 33 + n + 2) * 256 + tid];
          p3 += wkS[n + 3] * Mk[((size_t)b * 33 + n + 3) * 256 + tid];
        }
        for (; n < t; ++n) p0 += wkS[n] * Mk[((size_t)b * 33 + n) * 256 + tid];
        if (wr) {
          sth_sys(nxt, (b * 800 + tid) * 2, f2bf(g * ((p0 + p1) + (p2 + p3))));
          if (tid == 0) sth_sys(nxt, (b * 800 + 256) * 2, f2bf(g * wck_tbl[b * 33 + t]));
        }
        __syncthreads();
      }
    }
    gbar(cnt, gen);
  }
  // final 4-wide softmax (block 0; logits lines are first-touch here -> coherent)
  if (bid == 0) {
    for (int r2 = tid; r2 < 512; r2 += 256) {
      float a = logits[r2 * 4], b2 = logits[r2 * 4 + 1],
            c2 = logits[r2 * 4 + 2], d2 = logits[r2 * 4 + 3];
      float m = fmaxf(fmaxf(a, b2), fmaxf(c2, d2));
      float ea = __expf(a - m), eb = __expf(b2 - m), ec = __expf(c2 - m), ed = __expf(d2 - m);
      float ssum = ea + eb + ec + ed;
      out[r2 * 4] = ea / ssum; out[r2 * 4 + 1] = eb / ssum;
      out[r2 * 4 + 2] = ec / ssum; out[r2 * 4 + 3] = ed / ssum;
    }
  }
}

// ---------------------------------------------------------------------------
// Fallback per-step kernels (used only if cooperative-style launch fails).
// ---------------------------------------------------------------------------
__global__ __launch_bounds__(256) void k_gates(const unsigned short* __restrict__ xin,
                                               const unsigned short* __restrict__ WT,
                                               const float* __restrict__ b_lstm,
                                               float* __restrict__ h,
                                               unsigned short* __restrict__ hbf,
                                               unsigned short* __restrict__ xin_nxt) {
  __shared__ __align__(16) unsigned short As[2][64 * LSTR];
  __shared__ __align__(16) unsigned short Bs[2][64 * LSTR];
  __shared__ float Cs[64 * 65];
  int tid = threadIdx.x;
  int nn = blockIdx.x;
  int m0 = blockIdx.y * 64;
  int n0 = nn * 64;
  int lane = tid & 63, wid = tid >> 6;
  int wm = (wid >> 1) * 32, wn = (wid & 1) * 32;
  int q = lane >> 4, r = lane & 15;
  int ldrow = tid >> 2, ldc = (tid & 3) * 8;
  const uint4* Ag = reinterpret_cast<const uint4*>(xin + (size_t)(m0 + ldrow) * 800);
  const uint4* Bg = reinterpret_cast<const uint4*>(WT + (size_t)(n0 + ldrow) * 800);
  uint4 ra = Ag[ldc >> 3], rb = Bg[ldc >> 3];
  f32x4 acc[2][2] = {};
  int s = 0;
  *reinterpret_cast<uint4*>(&As[0][ldrow * LSTR + ldc]) = ra;
  *reinterpret_cast<uint4*>(&Bs[0][ldrow * LSTR + ldc]) = rb;
  __syncthreads();
  for (int kk = 0; kk < 25; ++kk) {
    if (kk < 24) {
      int k0 = (kk + 1) * 32;
      ra = Ag[(k0 + ldc) >> 3];
      rb = Bg[(k0 + ldc) >> 3];
    }
    short8 a0 = *reinterpret_cast<const short8*>(&As[s][(wm + r) * LSTR + q * 8]);
    short8 a1 = *reinterpret_cast<const short8*>(&As[s][(wm + 16 + r) * LSTR + q * 8]);
    short8 b0 = *reinterpret_cast<const short8*>(&Bs[s][(wn + r) * LSTR + q * 8]);
    short8 b1 = *reinterpret_cast<const short8*>(&Bs[s][(wn + 16 + r) * LSTR + q * 8]);
    acc[0][0] = __builtin_amdgcn_mfma_f32_16x16x32_bf16(a0, b0, acc[0][0], 0, 0, 0);
    acc[0][1] = __builtin_amdgcn_mfma_f32_16x16x32_bf16(a0, b1, acc[0][1], 0, 0, 0);
    acc[1][0] = __builtin_amdgcn_mfma_f32_16x16x32_bf16(a1, b0, acc[1][0], 0, 0, 0);
    acc[1][1] = __builtin_amdgcn_mfma_f32_16x16x32_bf16(a1, b1, acc[1][1], 0, 0, 0);
    if (kk < 24) {
      *reinterpret_cast<uint4*>(&As[s ^ 1][ldrow * LSTR + ldc]) = ra;
      *reinterpret_cast<uint4*>(&Bs[s ^ 1][ldrow * LSTR + ldc]) = rb;
      s ^= 1;
    }
    __syncthreads();
  }
#pragma unroll
  for (int mt = 0; mt < 2; ++mt)
#pragma unroll
    for (int nt = 0; nt < 2; ++nt)
#pragma unroll
      for (int e = 0; e < 4; ++e)
        Cs[(wm + mt * 16 + q * 4 + e) * 65 + wn + nt * 16 + r] = acc[mt][nt][e];
  __syncthreads();
#pragma unroll
  for (int it = 0; it < 4; ++it) {
    int id = it * 256 + tid;
    int rl = id >> 4, jl = id & 15;
    int brow = m0 + rl;
    int j = nn * 16 + jl;
    float gi = Cs[rl * 65 + jl * 4 + 0] + b_lstm[j];
    float gf = Cs[rl * 65 + jl * 4 + 1] + b_lstm[512 + j];
    float gg = Cs[rl * 65 + jl * 4 + 2] + b_lstm[1024 + j];
    float go = Cs[rl * 65 + jl * 4 + 3] + b_lstm[1536 + j];
    float hold = h[brow * 512 + j];
    float cnew = sigm(gf) * hold + sigm(gi) * ftanh(gg);
    float hnew = sigm(go) * ftanh(cnew);
    h[brow * 512 + j] = hnew;
    hbf[brow * 512 + j] = f2bf(hnew);
    xin_nxt[brow * 800 + 288 + j] = f2bf(cnew);
  }
}

__global__ __launch_bounds__(256) void k_head(const unsigned short* __restrict__ hbf,
                                              const unsigned short* __restrict__ Wk2T,
                                              const float* __restrict__ bias2,
                                              float* __restrict__ Mk,
                                              float* __restrict__ logits,
                                              const float* __restrict__ h,
                                              const float* __restrict__ Wg,
                                              const float* __restrict__ bg,
                                              const float* __restrict__ wk_tbl,
                                              const float* __restrict__ wck_tbl,
                                              unsigned short* __restrict__ xin_nxt,
                                              int t) {
  __shared__ __align__(16) unsigned short As[2][64 * LSTR];
  __shared__ __align__(16) unsigned short Bs[2][64 * LSTR];
  __shared__ float wkS[33];
  __shared__ float red[256];
  int bid = blockIdx.x;
  int tid = threadIdx.x;
  if (bid < 40) {
    int mi = bid / 5, ni = bid - mi * 5;
    int m0 = mi * 64, n0 = ni * 64;
    int lane = tid & 63, wid = tid >> 6;
    int wm = (wid >> 1) * 32, wn = (wid & 1) * 32;
    int q = lane >> 4, r = lane & 15;
    int ldrow = tid >> 2, ldc = (tid & 3) * 8;
    const uint4* Ag = reinterpret_cast<const uint4*>(hbf + (size_t)(m0 + ldrow) * 512);
    const uint4* Bg = reinterpret_cast<const uint4*>(Wk2T + (size_t)(n0 + ldrow) * 512);
    uint4 ra = Ag[ldc >> 3], rb = Bg[ldc >> 3];
    f32x4 acc[2][2] = {};
    int s = 0;
    *reinterpret_cast<uint4*>(&As[0][ldrow * LSTR + ldc]) = ra;
    *reinterpret_cast<uint4*>(&Bs[0][ldrow * LSTR + ldc]) = rb;
    __syncthreads();
    for (int kk = 0; kk < 16; ++kk) {
      if (kk < 15) {
        int k0 = (kk + 1) * 32;
        ra = Ag[(k0 + ldc) >> 3];
        rb = Bg[(k0 + ldc) >> 3];
      }
      short8 a0 = *reinterpret_cast<const short8*>(&As[s][(wm + r) * LSTR + q * 8]);
      short8 a1 = *reinterpret_cast<const short8*>(&As[s][(wm + 16 + r) * LSTR + q * 8]);
      short8 b0 = *reinterpret_cast<const short8*>(&Bs[s][(wn + r) * LSTR + q * 8]);
      short8 b1 = *reinterpret_cast<const short8*>(&Bs[s][(wn + 16 + r) * LSTR + q * 8]);
      acc[0][0] = __builtin_amdgcn_mfma_f32_16x16x32_bf16(a0, b0, acc[0][0], 0, 0, 0);
      acc[0][1] = __builtin_amdgcn_mfma_f32_16x16x32_bf16(a0, b1, acc[0][1], 0, 0, 0);
      acc[1][0] = __builtin_amdgcn_mfma_f32_16x16x32_bf16(a1, b0, acc[1][0], 0, 0, 0);
      acc[1][1] = __builtin_amdgcn_mfma_f32_16x16x32_bf16(a1, b1, acc[1][1], 0, 0, 0);
      if (kk < 15) {
        *reinterpret_cast<uint4*>(&As[s ^ 1][ldrow * LSTR + ldc]) = ra;
        *reinterpret_cast<uint4*>(&Bs[s ^ 1][ldrow * LSTR + ldc]) = rb;
        s ^= 1;
      }
      __syncthreads();
    }
#pragma unroll
    for (int mt = 0; mt < 2; ++mt)
#pragma unroll
      for (int nt = 0; nt < 2; ++nt)
#pragma unroll
        for (int e = 0; e < 4; ++e) {
          int row = m0 + wm + mt * 16 + q * 4 + e;
          int np = n0 + wn + nt * 16 + r;
          float v = acc[mt][nt][e] + bias2[np];
          if (np < 256) Mk[(size_t)(row * 33 + t) * 256 + np] = fmaxf(v, 0.f);
          else if (np >= 257 && np < 261) logits[row * 4 + (np - 257)] = v;
        }
  } else {
    if (t == 0 || t == 32) return;
    int b = bid - 40;
    float s = h[b * 512 + tid] * Wg[tid] + h[b * 512 + 256 + tid] * Wg[256 + tid];
    red[tid] = s;
    if (tid < t) wkS[tid] = wk_tbl[((size_t)b * 33 + t) * 33 + tid];
    __syncthreads();
    for (int off = 128; off > 0; off >>= 1) {
      if (tid < off) red[tid] += red[tid + off];
      __syncthreads();
    }
    float g = 1.f / (1.f + __expf(-(red[0] + bg[0])));
    float acc = 0.f;
    for (int n = 0; n < t; ++n) acc += wkS[n] * Mk[((size_t)b * 33 + n) * 256 + tid];
    xin_nxt[b * 800 + tid] = f2bf(g * acc);
    if (tid == 0) xin_nxt[b * 800 + 256] = f2bf(g * wck_tbl[b * 33 + t]);
  }
}

__global__ void k_softmax(const float* __restrict__ logits, float* __restrict__ out) {
  int tid = threadIdx.x;
  for (int r2 = tid; r2 < 512; r2 += 256) {
    float a = logits[r2 * 4], b = logits[r2 * 4 + 1], c = logits[r2 * 4 + 2], d = logits[r2 * 4 + 3];
    float m = fmaxf(fmaxf(a, b), fmaxf(c, d));
    float ea = __expf(a - m), eb = __expf(b - m), ec = __expf(c - m), ed = __expf(d - m);
    float s = ea + eb + ec + ed;
    out[r2 * 4] = ea / s; out[r2 * 4 + 1] = eb / s;
    out[r2 * 4 + 2] = ec / s; out[r2 * 4 + 3] = ed / s;
  }
}

extern "C" void kernel_launch(void* const* d_in, const int* in_sizes, int n_in,
                              void* d_out, int out_size, void* d_ws, size_t ws_size,
                              hipStream_t stream) {
  const float* x_seq = (const float*)d_in[0];
  const float* W_enc = (const float*)d_in[1];
  const float* b_enc = (const float*)d_in[2];
  const float* W_lstm = (const float*)d_in[3];
  const float* U_lstm = (const float*)d_in[4];
  const float* b_lstm = (const float*)d_in[5];
  const float* W_key = (const float*)d_in[6];
  const float* b_key = (const float*)d_in[7];
  const float* W_g = (const float*)d_in[8];
  const float* b_g = (const float*)d_in[9];
  const float* W_y = (const float*)d_in[10];
  const float* b_y = (const float*)d_in[11];
  const float* gamma = (const float*)d_in[12];
  const float* beta = (const float*)d_in[13];
  const float* cg_ = (const float*)d_in[14];
  const float* cb = (const float*)d_in[15];

  char* p = (char*)d_ws;
  auto alloc = [&](size_t bytes) {
    char* r = p;
    p += (bytes + 255) & ~(size_t)255;
    return r;
  };
  float* zbuf = (float*)alloc((size_t)16384 * 128 * 4);
  float* z_full = (float*)alloc((size_t)512 * 33 * 128 * 4);
  unsigned short* WcombT = (unsigned short*)alloc((size_t)2048 * 800 * 2);
  unsigned short* WencT = (unsigned short*)alloc((size_t)128 * 1024 * 2);
  unsigned short* Wk2T = (unsigned short*)alloc((size_t)320 * 512 * 2);
  float* bias2 = (float*)alloc(320 * 4);
  unsigned short* xinA = (unsigned short*)alloc((size_t)512 * 800 * 2);
  unsigned short* xinB = (unsigned short*)alloc((size_t)512 * 800 * 2);
  float* h = (float*)alloc((size_t)512 * 512 * 4);
  unsigned short* hbf = (unsigned short*)alloc((size_t)512 * 512 * 2);
  float* Mk = (float*)alloc((size_t)512 * 33 * 256 * 4);
  float* logits = (float*)alloc((size_t)512 * 4 * 4);
  float* wk_tbl = (float*)alloc((size_t)512 * 33 * 33 * 4);
  float* wck_tbl = (float*)alloc((size_t)512 * 33 * 4);
  unsigned* bar = (unsigned*)alloc(1024);
  float* outp = (float*)d_out;

  const int prep_total = 2048 * 800 + 320 * 512 + 128 * 1024 + 320 + 2 * 512 * 800 +
                         512 * 512 + 512 * 128 + 256;
  k_prep<<<(prep_total + 255) / 256, 256, 0, stream>>>(
      W_lstm, U_lstm, W_enc, W_key, W_g, W_y, b_key, b_g, b_y,
      WcombT, Wk2T, WencT, bias2, xinA, xinB, h, z_full, bar);
  k_enc<<<256, 512, 0, stream>>>(x_seq, WencT, b_enc, zbuf);
  k_ln<<<256, 256, 0, stream>>>(zbuf, gamma, beta, z_full);
  k_attnpre<<<512, 256, 0, stream>>>(z_full, cg_, cb, wk_tbl, wck_tbl);

  void* cargs[16];
  cargs[0] = &xinA;  cargs[1] = &xinB;   cargs[2] = &WcombT; cargs[3] = &b_lstm;
  cargs[4] = &h;     cargs[5] = &hbf;    cargs[6] = &Wk2T;   cargs[7] = &bias2;
  cargs[8] = &Mk;    cargs[9] = &logits; cargs[10] = &W_g;   cargs[11] = &b_g;
  cargs[12] = &wk_tbl; cargs[13] = &wck_tbl; cargs[14] = &outp; cargs[15] = &bar;
  hipError_t ce = hipLaunchCooperativeKernel((const void*)k_loop, dim3(256), dim3(256),
                                             cargs, 0u, stream);
  if (ce != hipSuccess) {
    // fallback: per-step launches (previous verified path)
    for (int t = 0; t < 33; ++t) {
      unsigned short* cur = (t & 1) ? xinB : xinA;
      unsigned short* nxt = (t & 1) ? xinA : xinB;
      k_gates<<<dim3(32, 8), 256, 0, stream>>>(cur, WcombT, b_lstm, h, hbf, nxt);
      k_head<<<552, 256, 0, stream>>>(hbf, Wk2T, bias2, Mk, logits, h,
                                      W_g, b_g, wk_tbl, wck_tbl, nxt, t);
    }
    k_softmax<<<1, 256, 0, stream>>>(logits, outp);
  }
}

// Round 6
// 782.738 us; speedup vs baseline: 3.3071x; 1.0743x over previous
//
#include <hip/hip_runtime.h>

typedef __attribute__((ext_vector_type(8))) short short8;
typedef __attribute__((ext_vector_type(4))) float f32x4;
typedef __attribute__((ext_vector_type(8))) unsigned short ushort8;
typedef __attribute__((ext_vector_type(4))) unsigned short ushort4v;

__device__ __forceinline__ unsigned short f2bf(float f) {
  union { float f; unsigned u; } v; v.f = f;
  unsigned u = v.u;
  u += 0x7fffu + ((u >> 16) & 1u);
  return (unsigned short)(u >> 16);
}
__device__ __forceinline__ float sigm(float x) { return 1.f / (1.f + __expf(-x)); }
__device__ __forceinline__ float ftanh(float x) { return 1.f - 2.f / (__expf(2.f * x) + 1.f); }

// async global->LDS, 16B per lane. LDS dest must be WAVE-UNIFORM base; HW adds lane*16.
__device__ __forceinline__ void gl16(const unsigned short* g, unsigned short* l) {
  __builtin_amdgcn_global_load_lds((const __attribute__((address_space(1))) void*)g,
                                   (__attribute__((address_space(3))) void*)l, 16, 0, 0);
}

// ---- coherent (system-scope, performed at Infinity Cache) access helpers ----
__device__ __forceinline__ uint4 ld16_sys(const void* base, int off) {
  uint4 r;
  asm volatile("global_load_dwordx4 %0, %1, %2 sc0 sc1"
               : "=v"(r) : "v"(off), "s"(base) : "memory");
  return r;
}
__device__ __forceinline__ uint4 ld16_asm(const void* base, int off) {  // plain, asm-counted
  uint4 r;
  asm volatile("global_load_dwordx4 %0, %1, %2"
               : "=v"(r) : "v"(off), "s"(base) : "memory");
  return r;
}
__device__ __forceinline__ float ldf_sys(const void* base, int off) {
  float r;
  asm volatile("global_load_dword %0, %1, %2 sc0 sc1"
               : "=v"(r) : "v"(off), "s"(base) : "memory");
  return r;
}
__device__ __forceinline__ unsigned ldu_sys(const void* base, int off) {
  unsigned r;
  asm volatile("global_load_dword %0, %1, %2 sc0 sc1"
               : "=v"(r) : "v"(off), "s"(base) : "memory");
  return r;
}
__device__ __forceinline__ void stf_sys(void* base, int off, float v) {
  asm volatile("global_store_dword %0, %1, %2 sc0 sc1"
               :: "v"(off), "v"(v), "s"(base) : "memory");
}
__device__ __forceinline__ void stu_sys(void* base, int off, unsigned v) {
  asm volatile("global_store_dword %0, %1, %2 sc0 sc1"
               :: "v"(off), "v"(v), "s"(base) : "memory");
}
__device__ __forceinline__ void sth_sys(void* base, int off, unsigned short v) {
  asm volatile("global_store_short %0, %1, %2 sc0 sc1"
               :: "v"(off), "v"(v), "s"(base) : "memory");
}
#define WAITVM(N)                                          \
  asm volatile("s_waitcnt vmcnt(" #N ")" ::: "memory");    \
  __builtin_amdgcn_sched_barrier(0)

// Atomic-free flag barrier (no collective builtins): block b sc1-stores its
// generation into flags[b*16]; thread tid spins on block tid's slot. v>=gen
// tolerates fast blocks racing ahead. Data stores drained (vmcnt 0) pre-flag.
__device__ __forceinline__ void gbar(unsigned* flags, unsigned gen) {
  asm volatile("s_waitcnt vmcnt(0)" ::: "memory");  // all data stores acked at mall
  __syncthreads();
  if (threadIdx.x == 0) stu_sys(flags, (int)(blockIdx.x * 64), gen);
  int off = (int)(threadIdx.x * 64);
  for (;;) {
    unsigned v = ldu_sys(flags, off);
    asm volatile("s_waitcnt vmcnt(0)" ::: "memory");
    if (v >= gen) break;
    __builtin_amdgcn_s_sleep(1);
  }
  __syncthreads();
}

#define LSTR 40  // LDS row stride (elems) for the prologue GEMM

// ---------------------------------------------------------------------------
// Prep: build bf16 transposed/permuted weights, zero state buffers + flags.
// ---------------------------------------------------------------------------
__global__ void k_prep(const float* __restrict__ W_lstm, const float* __restrict__ U_lstm,
                       const float* __restrict__ W_enc, const float* __restrict__ W_key,
                       const float* __restrict__ W_g, const float* __restrict__ W_y,
                       const float* __restrict__ b_key, const float* __restrict__ b_g,
                       const float* __restrict__ b_y,
                       unsigned short* __restrict__ WcombT, unsigned short* __restrict__ Wk2T,
                       unsigned short* __restrict__ WencT, float* __restrict__ bias2,
                       unsigned short* __restrict__ xinA, unsigned short* __restrict__ xinB,
                       float* __restrict__ h, float* __restrict__ z_full,
                       unsigned* __restrict__ bar) {
  const int N1 = 2048 * 800, N2 = 320 * 512, N3 = 128 * 1024, N4 = 320,
            N5 = 512 * 800, N7 = 512 * 512, N8 = 512 * 128, N9 = 4096;
  int i = blockIdx.x * 256 + threadIdx.x;
  if (i < N1) {
    int np = i / 800, k = i - np * 800;
    int j = np >> 2, gate = np & 3, n = gate * 512 + j;
    float v = 0.f;
    if (k < 257) v = W_lstm[k * 2048 + n];
    else if (k >= 288) v = U_lstm[(k - 288) * 2048 + n];
    WcombT[i] = f2bf(v);
    return;
  }
  i -= N1;
  if (i < N2) {
    int n = i / 512, k = i - n * 512;
    float v = 0.f;
    if (n < 256) v = W_key[k * 256 + n];
    else if (n == 256) v = W_g[k];
    else if (n < 261) v = W_y[k * 4 + (n - 257)];
    Wk2T[i] = f2bf(v);
    return;
  }
  i -= N2;
  if (i < N3) {
    int n = i / 1024, k = i - n * 1024;
    WencT[i] = f2bf(W_enc[k * 128 + n]);
    return;
  }
  i -= N3;
  if (i < N4) {
    float v = (i < 256) ? b_key[i] : (i == 256 ? b_g[0] : (i < 261 ? b_y[i - 257] : 0.f));
    bias2[i] = v;
    return;
  }
  i -= N4;
  if (i < N5) { xinA[i] = 0; return; }
  i -= N5;
  if (i < N5) { xinB[i] = 0; return; }
  i -= N5;
  if (i < N7) { h[i] = 0.f; return; }
  i -= N7;
  if (i < N8) {
    int b = i >> 7, z = i & 127;
    z_full[(b * 33 + 32) * 128 + z] = 0.f;  // null slot
    return;
  }
  i -= N8;
  if (i < N9) bar[i] = 0;
}

// ---------------------------------------------------------------------------
// Encoder GEMM (proven): 64Mx128N tile, BK=32, K=1024, 512 threads.
// ---------------------------------------------------------------------------
__global__ __launch_bounds__(512) void k_enc(const float* __restrict__ x,
                                             const unsigned short* __restrict__ WencT,
                                             const float* __restrict__ b_enc,
                                             float* __restrict__ zbuf) {
  __shared__ __align__(16) unsigned short As[2][64 * LSTR];
  __shared__ __align__(16) unsigned short Bs[2][128 * LSTR];
  int tid = threadIdx.x;
  int m0 = blockIdx.x * 64;
  int lane = tid & 63, wid = tid >> 6;
  int wm = (wid >> 2) * 32, wn = (wid & 3) * 32;
  int q = lane >> 4, r = lane & 15;
  int ldrowA = tid >> 3, ldcA = (tid & 7) * 4;
  int ldrowB = tid >> 2, ldcB = (tid & 3) * 8;
  const float4* Ag = reinterpret_cast<const float4*>(x + (size_t)(m0 + ldrowA) * 1024);
  const uint4* Bg = reinterpret_cast<const uint4*>(WencT + (size_t)ldrowB * 1024);
  float4 ra = Ag[ldcA >> 2];
  uint4 rb = Bg[ldcB >> 3];
  f32x4 acc[2][2] = {};
  int s = 0;
  {
    ushort4v t4;
    t4[0] = f2bf(ra.x); t4[1] = f2bf(ra.y); t4[2] = f2bf(ra.z); t4[3] = f2bf(ra.w);
    *reinterpret_cast<ushort4v*>(&As[0][ldrowA * LSTR + ldcA]) = t4;
    *reinterpret_cast<uint4*>(&Bs[0][ldrowB * LSTR + ldcB]) = rb;
  }
  __syncthreads();
  for (int kk = 0; kk < 32; ++kk) {
    if (kk < 31) {
      int k0 = (kk + 1) * 32;
      ra = Ag[(k0 + ldcA) >> 2];
      rb = Bg[(k0 + ldcB) >> 3];
    }
    short8 a0 = *reinterpret_cast<const short8*>(&As[s][(wm + r) * LSTR + q * 8]);
    short8 a1 = *reinterpret_cast<const short8*>(&As[s][(wm + 16 + r) * LSTR + q * 8]);
    short8 b0 = *reinterpret_cast<const short8*>(&Bs[s][(wn + r) * LSTR + q * 8]);
    short8 b1 = *reinterpret_cast<const short8*>(&Bs[s][(wn + 16 + r) * LSTR + q * 8]);
    acc[0][0] = __builtin_amdgcn_mfma_f32_16x16x32_bf16(a0, b0, acc[0][0], 0, 0, 0);
    acc[0][1] = __builtin_amdgcn_mfma_f32_16x16x32_bf16(a0, b1, acc[0][1], 0, 0, 0);
    acc[1][0] = __builtin_amdgcn_mfma_f32_16x16x32_bf16(a1, b0, acc[1][0], 0, 0, 0);
    acc[1][1] = __builtin_amdgcn_mfma_f32_16x16x32_bf16(a1, b1, acc[1][1], 0, 0, 0);
    if (kk < 31) {
      ushort4v t4;
      t4[0] = f2bf(ra.x); t4[1] = f2bf(ra.y); t4[2] = f2bf(ra.z); t4[3] = f2bf(ra.w);
      *reinterpret_cast<ushort4v*>(&As[s ^ 1][ldrowA * LSTR + ldcA]) = t4;
      *reinterpret_cast<uint4*>(&Bs[s ^ 1][ldrowB * LSTR + ldcB]) = rb;
      s ^= 1;
    }
    __syncthreads();
  }
#pragma unroll
  for (int mt = 0; mt < 2; ++mt)
#pragma unroll
    for (int nt = 0; nt < 2; ++nt)
#pragma unroll
      for (int e = 0; e < 4; ++e) {
        int row = m0 + wm + mt * 16 + q * 4 + e;
        int col = wn + nt * 16 + r;
        zbuf[(size_t)row * 128 + col] = fmaxf(acc[mt][nt][e] + b_enc[col], 0.f);
      }
}

// ---------------------------------------------------------------------------
// LayerNorm over the BATCH axis per (t,z).
// ---------------------------------------------------------------------------
__global__ __launch_bounds__(256) void k_ln(const float* __restrict__ zbuf,
                                            const float* __restrict__ gamma,
                                            const float* __restrict__ beta,
                                            float* __restrict__ z_full) {
  int bid = blockIdx.x;
  int tstep = bid >> 3;
  int z0 = (bid & 7) * 16;
  int tid = threadIdx.x;
  int zl = tid & 15, bg = tid >> 4;
  __shared__ float ps[256], qs[256];
  __shared__ float muS[16], rsS[16];
  float s = 0.f, ss = 0.f;
  for (int ii = 0; ii < 32; ++ii) {
    int b = bg * 32 + ii;
    float v = zbuf[(size_t)(b * 32 + tstep) * 128 + z0 + zl];
    s += v; ss += v * v;
  }
  ps[tid] = s; qs[tid] = ss;
  __syncthreads();
  if (tid < 16) {
    float S = 0.f, Q = 0.f;
    for (int g2 = 0; g2 < 16; ++g2) { S += ps[g2 * 16 + tid]; Q += qs[g2 * 16 + tid]; }
    float mu = S / 512.f;
    float var = Q / 512.f - mu * mu;
    muS[tid] = mu;
    rsS[tid] = rsqrtf(var + 1e-8f);
  }
  __syncthreads();
  float ga = gamma[z0 + zl], be = beta[z0 + zl];
  float mu = muS[zl], rs = rsS[zl];
  for (int ii = 0; ii < 32; ++ii) {
    int b = bg * 32 + ii;
    float v = zbuf[(size_t)(b * 32 + tstep) * 128 + z0 + zl];
    z_full[(size_t)(b * 33 + tstep) * 128 + z0 + zl] = (v - mu) * rs * ga + be;
  }
}

// ---------------------------------------------------------------------------
// Attention precompute (w_k and wck for all t, once).
// ---------------------------------------------------------------------------
__global__ __launch_bounds__(256) void k_attnpre(const float* __restrict__ z_full,
                                                 const float* __restrict__ cgain,
                                                 const float* __restrict__ cbias,
                                                 float* __restrict__ wk_tbl,
                                                 float* __restrict__ wck_tbl) {
  __shared__ float zs[33 * 128];
  __shared__ float sim[33 * 33];
  int b = blockIdx.x, tid = threadIdx.x;
  const float* zb = z_full + (size_t)b * 33 * 128;
  for (int i = tid; i < 33 * 128; i += 256) zs[i] = zb[i];
  __syncthreads();
  for (int p = tid; p < 33 * 33; p += 256) {
    int t = p / 33, n = p - t * 33;
    float s = 0.f;
    if (n < t) {
#pragma unroll 8
      for (int k2 = 0; k2 < 128; ++k2) s += zs[t * 128 + k2] * zs[n * 128 + k2];
    }
    sim[p] = s;
  }
  __syncthreads();
  if (tid >= 1 && tid < 33) {
    int t = tid;
    float cg = cgain[0], cb2 = cbias[0];
    float m = -3.0e38f;
    for (int n = 0; n < t; ++n) m = fmaxf(m, sim[t * 33 + n]);
    float ssum = 0.f;
    for (int n = 0; n < t; ++n) ssum += __expf(sim[t * 33 + n] - m);
    float inv = 1.f / ssum;
    float wck = 0.f;
    for (int n = 0; n < t; ++n) {
      float wk = __expf(sim[t * 33 + n] - m) * inv;
      wk_tbl[((size_t)b * 33 + t) * 33 + n] = wk;
      float ck = 1.f / (1.f + __expf(-(sim[t * 33 + n] * cg + cb2)));
      wck += wk * ck;
    }
    wck_tbl[b * 33 + t] = wck;
  }
}

// ---------------------------------------------------------------------------
// Persistent kernel: round-4-proven body; only the grid barrier changed
// (atomic sense-reversing -> per-block flag + per-thread spin).
// ---------------------------------------------------------------------------
__global__ __launch_bounds__(256) void k_loop(
    unsigned short* __restrict__ xinA, unsigned short* __restrict__ xinB,
    const unsigned short* __restrict__ WT, const float* __restrict__ b_lstm,
    float* __restrict__ h, unsigned short* __restrict__ hbf,
    const unsigned short* __restrict__ Wk2T, const float* __restrict__ bias2,
    float* __restrict__ Mk, float* __restrict__ logits,
    const float* __restrict__ Wg, const float* __restrict__ bg,
    const float* __restrict__ wk_tbl, const float* __restrict__ wck_tbl,
    float* __restrict__ out, unsigned* __restrict__ bar) {
  __shared__ __align__(16) unsigned short Bres[64 * 808];  // 103424 B, resident
  __shared__ __align__(16) unsigned char scr[43136];       // A0/A1, Cs, wkS
  const int tid = threadIdx.x, bid = blockIdx.x;
  const int lane = tid & 63, w = tid >> 6;
  const int q = lane >> 4, r = lane & 15;
  const int wm = (w >> 1) * 32, wn = (w & 1) * 32;
  const int nn = bid & 31, mi = bid >> 5;  // gates tile
  const int m0 = mi * 64, n0g = nn * 64;
  unsigned gen = 0;

  // ---- pin B slice (static): 64 rows x 808 (800 data + 8 pad), via gl16 with
  // wave-uniform LDS base + per-lane pre-swizzled global source. 6464 granules.
  for (int l = 0; l < 26; ++l) {
    int gw = l * 256 + w * 64;  // wave-uniform granule base
    if (gw < 6464) {
      int g = gw + lane;
      int row = g / 101, cg = g - row * 101;
      int col = (cg >= 100) ? 792 : cg * 8;  // pad granule: load junk (unread)
      gl16(WT + (size_t)(n0g + row) * 800 + col, Bres + gw * 8);
    }
  }

  // per-thread A-stage coords: 1280 data granules = 5 x 256 (row-major 64x160)
  int srow[5], scol[5];
#pragma unroll
  for (int l = 0; l < 5; ++l) {
    int idx = l * 256 + tid;
    srow[l] = idx / 20;
    scol[l] = (idx - srow[l] * 20) * 8;
  }
  unsigned short* A0 = (unsigned short*)scr;             // 64*168*2 = 21504 B
  unsigned short* A1 = (unsigned short*)(scr + 21504);   // 21504 B

  const int jl = tid & 15, jg = nn * 16 + jl, rl0 = tid >> 4;
  const float bL0 = b_lstm[jg], bL1 = b_lstm[512 + jg],
              bL2 = b_lstm[1024 + jg], bL3 = b_lstm[1536 + jg];
  float hreg[4] = {0.f, 0.f, 0.f, 0.f};

  const int mi2 = bid / 5, ni2 = bid - mi2 * 5;  // head-GEMM tile (bid<40)

  asm volatile("s_waitcnt vmcnt(0)" ::: "memory");
  __syncthreads();

  for (int t = 0; t < 33; ++t) {
    const unsigned short* cur = (t & 1) ? xinB : xinA;
    unsigned short* nxt = (t & 1) ? xinA : xinB;

    // ====== phase A: gates GEMM (64x64, K=800=5x160) + LSTM cell =============
    uint4 R[5];
#pragma unroll
    for (int l = 0; l < 5; ++l)  // prologue: chunk 0 (coherent: xin is remote-written)
      R[l] = ld16_sys(cur, ((m0 + srow[l]) * 800 + scol[l]) * 2);
    asm volatile("s_waitcnt vmcnt(0)" ::: "memory");
    __builtin_amdgcn_sched_barrier(0);
#pragma unroll
    for (int l = 0; l < 5; ++l)
      *(uint4*)&A0[srow[l] * 168 + scol[l]] = R[l];
    __syncthreads();

    f32x4 acc[2][2] = {};
    for (int c = 0; c < 5; ++c) {
      const unsigned short* Ac = (c & 1) ? A1 : A0;
      unsigned short* An = (c & 1) ? A0 : A1;
      if (c < 4) {
#pragma unroll
        for (int l = 0; l < 5; ++l)
          R[l] = ld16_sys(cur, ((m0 + srow[l]) * 800 + (c + 1) * 160 + scol[l]) * 2);
      }
#pragma unroll
      for (int ks = 0; ks < 5; ++ks) {
        short8 a0 = *(const short8*)&Ac[(wm + r) * 168 + ks * 32 + q * 8];
        short8 a1 = *(const short8*)&Ac[(wm + 16 + r) * 168 + ks * 32 + q * 8];
        short8 b0 = *(const short8*)&Bres[(wn + r) * 808 + c * 160 + ks * 32 + q * 8];
        short8 b1 = *(const short8*)&Bres[(wn + 16 + r) * 808 + c * 160 + ks * 32 + q * 8];
        acc[0][0] = __builtin_amdgcn_mfma_f32_16x16x32_bf16(a0, b0, acc[0][0], 0, 0, 0);
        acc[0][1] = __builtin_amdgcn_mfma_f32_16x16x32_bf16(a0, b1, acc[0][1], 0, 0, 0);
        acc[1][0] = __builtin_amdgcn_mfma_f32_16x16x32_bf16(a1, b0, acc[1][0], 0, 0, 0);
        acc[1][1] = __builtin_amdgcn_mfma_f32_16x16x32_bf16(a1, b1, acc[1][1], 0, 0, 0);
      }
      if (c < 4) {
        asm volatile("s_waitcnt vmcnt(0)" ::: "memory");
        __builtin_amdgcn_sched_barrier(0);
#pragma unroll
        for (int l = 0; l < 5; ++l)
          *(uint4*)&An[srow[l] * 168 + scol[l]] = R[l];
        __syncthreads();
      }
    }
    __syncthreads();  // drain last buffer reads before Cs overwrites A0

    // ---- fused LSTM cell (h-carry in registers; coherent stores) ----
    float* Cs = (float*)scr;
#pragma unroll
    for (int mt = 0; mt < 2; ++mt)
#pragma unroll
      for (int nt = 0; nt < 2; ++nt)
#pragma unroll
        for (int e = 0; e < 4; ++e)
          Cs[(wm + mt * 16 + q * 4 + e) * 65 + wn + nt * 16 + r] = acc[mt][nt][e];
    __syncthreads();
#pragma unroll
    for (int it = 0; it < 4; ++it) {
      int rl = it * 16 + rl0;
      int brow = m0 + rl;
      float gi = Cs[rl * 65 + jl * 4 + 0] + bL0;
      float gf = Cs[rl * 65 + jl * 4 + 1] + bL1;
      float gc = Cs[rl * 65 + jl * 4 + 2] + bL2;
      float go = Cs[rl * 65 + jl * 4 + 3] + bL3;
      float cnew = sigm(gf) * hreg[it] + sigm(gi) * ftanh(gc);
      float hnew = sigm(go) * ftanh(cnew);
      hreg[it] = hnew;
      stf_sys(h, (brow * 512 + jg) * 4, hnew);
      sth_sys(hbf, (brow * 512 + jg) * 2, f2bf(hnew));
      sth_sys(nxt, (brow * 800 + 288 + jg) * 2, f2bf(cnew));
    }
    ++gen; gbar(bar, gen);

    // ====== phase B ==========================================================
    if (bid < 40) {
      // head GEMM 64x64, K=512: LDS-free, depth-3 reg pipeline, counted vmcnt.
      int m0b = mi2 * 64, n0b = ni2 * 64;
      int aoff0 = ((m0b + wm + r) * 512 + q * 8) * 2;
      int aoff1 = aoff0 + 16 * 1024;
      int boff0 = ((n0b + wn + r) * 512 + q * 8) * 2;
      int boff1 = boff0 + 16 * 1024;
      uint4 ab[4][2], bb[4][2];
      f32x4 acc2[2][2] = {};
#pragma unroll
      for (int j = 0; j < 3; ++j) {
        ab[j][0] = ld16_sys(hbf, aoff0 + j * 64);   // hbf: remote-written -> sc1
        ab[j][1] = ld16_sys(hbf, aoff1 + j * 64);
        bb[j][0] = ld16_asm(Wk2T, boff0 + j * 64);  // Wk2T: static -> plain (L2)
        bb[j][1] = ld16_asm(Wk2T, boff1 + j * 64);
      }
#pragma unroll
      for (int kk = 0; kk < 16; ++kk) {
        if (kk < 13) {
          int j = kk + 3;
          ab[j & 3][0] = ld16_sys(hbf, aoff0 + j * 64);
          ab[j & 3][1] = ld16_sys(hbf, aoff1 + j * 64);
          bb[j & 3][0] = ld16_asm(Wk2T, boff0 + j * 64);
          bb[j & 3][1] = ld16_asm(Wk2T, boff1 + j * 64);
        }
        if (kk < 13) { WAITVM(12); }
        else if (kk == 13) { WAITVM(8); }
        else if (kk == 14) { WAITVM(4); }
        else { WAITVM(0); }
        short8 a0 = *(const short8*)&ab[kk & 3][0];
        short8 a1 = *(const short8*)&ab[kk & 3][1];
        short8 b0s = *(const short8*)&bb[kk & 3][0];
        short8 b1s = *(const short8*)&bb[kk & 3][1];
        acc2[0][0] = __builtin_amdgcn_mfma_f32_16x16x32_bf16(a0, b0s, acc2[0][0], 0, 0, 0);
        acc2[0][1] = __builtin_amdgcn_mfma_f32_16x16x32_bf16(a0, b1s, acc2[0][1], 0, 0, 0);
        acc2[1][0] = __builtin_amdgcn_mfma_f32_16x16x32_bf16(a1, b0s, acc2[1][0], 0, 0, 0);
        acc2[1][1] = __builtin_amdgcn_mfma_f32_16x16x32_bf16(a1, b1s, acc2[1][1], 0, 0, 0);
      }
#pragma unroll
      for (int mt = 0; mt < 2; ++mt)
#pragma unroll
        for (int nt = 0; nt < 2; ++nt)
#pragma unroll
          for (int e2 = 0; e2 < 4; ++e2) {
            int row = m0b + wm + mt * 16 + q * 4 + e2;
            int np = n0b + wn + nt * 16 + r;
            float v = acc2[mt][nt][e2] + bias2[np];
            if (np < 256)
              stf_sys(Mk, ((row * 33 + t) * 256 + np) * 4, fmaxf(v, 0.f));
            else if (np >= 257 && np < 261)
              stf_sys(logits, (row * 4 + (np - 257)) * 4, v);
          }
    } else if (t > 0 && t < 32) {
      // attention read: g gate + weighted = sum_{n<t} wk * Mk -> key_r for t+1
      float* wkS = (float*)scr;
      float* red4 = (float*)(scr + 512);
      for (int rr = 0; rr < 3; ++rr) {
        int b = (bid - 40) + 216 * rr;
        if (b < 512) {
          float ha = ldf_sys(h, (b * 512 + tid) * 4);
          float hb = ldf_sys(h, (b * 512 + 256 + tid) * 4);
          asm volatile("s_waitcnt vmcnt(0)" ::: "memory");
          float sd = ha * Wg[tid] + hb * Wg[256 + tid];
#pragma unroll
          for (int off = 32; off > 0; off >>= 1) sd += __shfl_down(sd, off);
          if (lane == 0) red4[w] = sd;
          if (tid < t) wkS[tid] = wk_tbl[((size_t)b * 33 + t) * 33 + tid];
          __syncthreads();
          float g = 1.f / (1.f + __expf(-(red4[0] + red4[1] + red4[2] + red4[3] + bg[0])));
          float p0 = 0.f, p1 = 0.f, p2 = 0.f, p3 = 0.f;
          int n = 0;
          for (; n + 4 <= t; n += 4) {
            p0 += wkS[n] * Mk[((size_t)b * 33 + n) * 256 + tid];
            p1 += wkS[n + 1] * Mk[((size_t)b * 33 + n + 1) * 256 + tid];
            p2 += wkS[n + 2] * Mk[((size_t)b * 33 + n + 2) * 256 + tid];
            p3 += wkS[n + 3] * Mk[((size_t)b * 33 + n + 3) * 256 + tid];
          }
          for (; n < t; ++n) p0 += wkS[n] * Mk[((size_t)b * 33 + n) * 256 + tid];
          sth_sys(nxt, (b * 800 + tid) * 2, f2bf(g * ((p0 + p1) + (p2 + p3))));
          if (tid == 0) sth_sys(nxt, (b * 800 + 256) * 2, f2bf(g * wck_tbl[b * 33 + t]));
          __syncthreads();
        }
      }
    }
    ++gen; gbar(bar, gen);
  }
  // final 4-wide softmax (block 0; logits lines are first-touch here -> coherent)
  if (bid == 0) {
    for (int r2 = tid; r2 < 512; r2 += 256) {
      float a = ldf_sys(logits, r2 * 16);
      float b2 = ldf_sys(logits, r2 * 16 + 4);
      float c2 = ldf_sys(logits, r2 * 16 + 8);
      float d2 = ldf_sys(logits, r2 * 16 + 12);
      asm volatile("s_waitcnt vmcnt(0)" ::: "memory");
      float m = fmaxf(fmaxf(a, b2), fmaxf(c2, d2));
      float ea = __expf(a - m), eb = __expf(b2 - m), ec = __expf(c2 - m), ed = __expf(d2 - m);
      float ssum = ea + eb + ec + ed;
      out[r2 * 4] = ea / ssum; out[r2 * 4 + 1] = eb / ssum;
      out[r2 * 4 + 2] = ec / ssum; out[r2 * 4 + 3] = ed / ssum;
    }
  }
}

// ---------------------------------------------------------------------------
// Fallback per-step kernels (used only if cooperative-style launch fails).
// ---------------------------------------------------------------------------
__global__ __launch_bounds__(256) void k_gates(const unsigned short* __restrict__ xin,
                                               const unsigned short* __restrict__ WT,
                                               const float* __restrict__ b_lstm,
                                               float* __restrict__ h,
                                               unsigned short* __restrict__ hbf,
                                               unsigned short* __restrict__ xin_nxt) {
  __shared__ __align__(16) unsigned short As[2][64 * LSTR];
  __shared__ __align__(16) unsigned short Bs[2][64 * LSTR];
  __shared__ float Cs[64 * 65];
  int tid = threadIdx.x;
  int nn = blockIdx.x;
  int m0 = blockIdx.y * 64;
  int n0 = nn * 64;
  int lane = tid & 63, wid = tid >> 6;
  int wm = (wid >> 1) * 32, wn = (wid & 1) * 32;
  int q = lane >> 4, r = lane & 15;
  int ldrow = tid >> 2, ldc = (tid & 3) * 8;
  const uint4* Ag = reinterpret_cast<const uint4*>(xin + (size_t)(m0 + ldrow) * 800);
  const uint4* Bg = reinterpret_cast<const uint4*>(WT + (size_t)(n0 + ldrow) * 800);
  uint4 ra = Ag[ldc >> 3], rb = Bg[ldc >> 3];
  f32x4 acc[2][2] = {};
  int s = 0;
  *reinterpret_cast<uint4*>(&As[0][ldrow * LSTR + ldc]) = ra;
  *reinterpret_cast<uint4*>(&Bs[0][ldrow * LSTR + ldc]) = rb;
  __syncthreads();
  for (int kk = 0; kk < 25; ++kk) {
    if (kk < 24) {
      int k0 = (kk + 1) * 32;
      ra = Ag[(k0 + ldc) >> 3];
      rb = Bg[(k0 + ldc) >> 3];
    }
    short8 a0 = *reinterpret_cast<const short8*>(&As[s][(wm + r) * LSTR + q * 8]);
    short8 a1 = *reinterpret_cast<const short8*>(&As[s][(wm + 16 + r) * LSTR + q * 8]);
    short8 b0 = *reinterpret_cast<const short8*>(&Bs[s][(wn + r) * LSTR + q * 8]);
    short8 b1 = *reinterpret_cast<const short8*>(&Bs[s][(wn + 16 + r) * LSTR + q * 8]);
    acc[0][0] = __builtin_amdgcn_mfma_f32_16x16x32_bf16(a0, b0, acc[0][0], 0, 0, 0);
    acc[0][1] = __builtin_amdgcn_mfma_f32_16x16x32_bf16(a0, b1, acc[0][1], 0, 0, 0);
    acc[1][0] = __builtin_amdgcn_mfma_f32_16x16x32_bf16(a1, b0, acc[1][0], 0, 0, 0);
    acc[1][1] = __builtin_amdgcn_mfma_f32_16x16x32_bf16(a1, b1, acc[1][1], 0, 0, 0);
    if (kk < 24) {
      *reinterpret_cast<uint4*>(&As[s ^ 1][ldrow * LSTR + ldc]) = ra;
      *reinterpret_cast<uint4*>(&Bs[s ^ 1][ldrow * LSTR + ldc]) = rb;
      s ^= 1;
    }
    __syncthreads();
  }
#pragma unroll
  for (int mt = 0; mt < 2; ++mt)
#pragma unroll
    for (int nt = 0; nt < 2; ++nt)
#pragma unroll
      for (int e = 0; e < 4; ++e)
        Cs[(wm + mt * 16 + q * 4 + e) * 65 + wn + nt * 16 + r] = acc[mt][nt][e];
  __syncthreads();
#pragma unroll
  for (int it = 0; it < 4; ++it) {
    int id = it * 256 + tid;
    int rl = id >> 4, jl = id & 15;
    int brow = m0 + rl;
    int j = nn * 16 + jl;
    float gi = Cs[rl * 65 + jl * 4 + 0] + b_lstm[j];
    float gf = Cs[rl * 65 + jl * 4 + 1] + b_lstm[512 + j];
    float gg = Cs[rl * 65 + jl * 4 + 2] + b_lstm[1024 + j];
    float go = Cs[rl * 65 + jl * 4 + 3] + b_lstm[1536 + j];
    float hold = h[brow * 512 + j];
    float cnew = sigm(gf) * hold + sigm(gi) * ftanh(gg);
    float hnew = sigm(go) * ftanh(cnew);
    h[brow * 512 + j] = hnew;
    hbf[brow * 512 + j] = f2bf(hnew);
    xin_nxt[brow * 800 + 288 + j] = f2bf(cnew);
  }
}

__global__ __launch_bounds__(256) void k_head(const unsigned short* __restrict__ hbf,
                                              const unsigned short* __restrict__ Wk2T,
                                              const float* __restrict__ bias2,
                                              float* __restrict__ Mk,
                                              float* __restrict__ logits,
                                              const float* __restrict__ h,
                                              const float* __restrict__ Wg,
                                              const float* __restrict__ bg,
                                              const float* __restrict__ wk_tbl,
                                              const float* __restrict__ wck_tbl,
                                              unsigned short* __restrict__ xin_nxt,
                                              int t) {
  __shared__ __align__(16) unsigned short As[2][64 * LSTR];
  __shared__ __align__(16) unsigned short Bs[2][64 * LSTR];
  __shared__ float wkS[33];
  __shared__ float red[256];
  int bid = blockIdx.x;
  int tid = threadIdx.x;
  if (bid < 40) {
    int mi = bid / 5, ni = bid - mi * 5;
    int m0 = mi * 64, n0 = ni * 64;
    int lane = tid & 63, wid = tid >> 6;
    int wm = (wid >> 1) * 32, wn = (wid & 1) * 32;
    int q = lane >> 4, r = lane & 15;
    int ldrow = tid >> 2, ldc = (tid & 3) * 8;
    const uint4* Ag = reinterpret_cast<const uint4*>(hbf + (size_t)(m0 + ldrow) * 512);
    const uint4* Bg = reinterpret_cast<const uint4*>(Wk2T + (size_t)(n0 + ldrow) * 512);
    uint4 ra = Ag[ldc >> 3], rb = Bg[ldc >> 3];
    f32x4 acc[2][2] = {};
    int s = 0;
    *reinterpret_cast<uint4*>(&As[0][ldrow * LSTR + ldc]) = ra;
    *reinterpret_cast<uint4*>(&Bs[0][ldrow * LSTR + ldc]) = rb;
    __syncthreads();
    for (int kk = 0; kk < 16; ++kk) {
      if (kk < 15) {
        int k0 = (kk + 1) * 32;
        ra = Ag[(k0 + ldc) >> 3];
        rb = Bg[(k0 + ldc) >> 3];
      }
      short8 a0 = *reinterpret_cast<const short8*>(&As[s][(wm + r) * LSTR + q * 8]);
      short8 a1 = *reinterpret_cast<const short8*>(&As[s][(wm + 16 + r) * LSTR + q * 8]);
      short8 b0 = *reinterpret_cast<const short8*>(&Bs[s][(wn + r) * LSTR + q * 8]);
      short8 b1 = *reinterpret_cast<const short8*>(&Bs[s][(wn + 16 + r) * LSTR + q * 8]);
      acc[0][0] = __builtin_amdgcn_mfma_f32_16x16x32_bf16(a0, b0, acc[0][0], 0, 0, 0);
      acc[0][1] = __builtin_amdgcn_mfma_f32_16x16x32_bf16(a0, b1, acc[0][1], 0, 0, 0);
      acc[1][0] = __builtin_amdgcn_mfma_f32_16x16x32_bf16(a1, b0, acc[1][0], 0, 0, 0);
      acc[1][1] = __builtin_amdgcn_mfma_f32_16x16x32_bf16(a1, b1, acc[1][1], 0, 0, 0);
      if (kk < 15) {
        *reinterpret_cast<uint4*>(&As[s ^ 1][ldrow * LSTR + ldc]) = ra;
        *reinterpret_cast<uint4*>(&Bs[s ^ 1][ldrow * LSTR + ldc]) = rb;
        s ^= 1;
      }
      __syncthreads();
    }
#pragma unroll
    for (int mt = 0; mt < 2; ++mt)
#pragma unroll
      for (int nt = 0; nt < 2; ++nt)
#pragma unroll
        for (int e = 0; e < 4; ++e) {
          int row = m0 + wm + mt * 16 + q * 4 + e;
          int np = n0 + wn + nt * 16 + r;
          float v = acc[mt][nt][e] + bias2[np];
          if (np < 256) Mk[(size_t)(row * 33 + t) * 256 + np] = fmaxf(v, 0.f);
          else if (np >= 257 && np < 261) logits[row * 4 + (np - 257)] = v;
        }
  } else {
    if (t == 0 || t == 32) return;
    int b = bid - 40;
    float s = h[b * 512 + tid] * Wg[tid] + h[b * 512 + 256 + tid] * Wg[256 + tid];
    red[tid] = s;
    if (tid < t) wkS[tid] = wk_tbl[((size_t)b * 33 + t) * 33 + tid];
    __syncthreads();
    for (int off = 128; off > 0; off >>= 1) {
      if (tid < off) red[tid] += red[tid + off];
      __syncthreads();
    }
    float g = 1.f / (1.f + __expf(-(red[0] + bg[0])));
    float acc = 0.f;
    for (int n = 0; n < t; ++n) acc += wkS[n] * Mk[((size_t)b * 33 + n) * 256 + tid];
    xin_nxt[b * 800 + tid] = f2bf(g * acc);
    if (tid == 0) xin_nxt[b * 800 + 256] = f2bf(g * wck_tbl[b * 33 + t]);
  }
}

__global__ void k_softmax(const float* __restrict__ logits, float* __restrict__ out) {
  int tid = threadIdx.x;
  for (int r2 = tid; r2 < 512; r2 += 256) {
    float a = logits[r2 * 4], b = logits[r2 * 4 + 1], c = logits[r2 * 4 + 2], d = logits[r2 * 4 + 3];
    float m = fmaxf(fmaxf(a, b), fmaxf(c, d));
    float ea = __expf(a - m), eb = __expf(b - m), ec = __expf(c - m), ed = __expf(d - m);
    float s = ea + eb + ec + ed;
    out[r2 * 4] = ea / s; out[r2 * 4 + 1] = eb / s;
    out[r2 * 4 + 2] = ec / s; out[r2 * 4 + 3] = ed / s;
  }
}

extern "C" void kernel_launch(void* const* d_in, const int* in_sizes, int n_in,
                              void* d_out, int out_size, void* d_ws, size_t ws_size,
                              hipStream_t stream) {
  const float* x_seq = (const float*)d_in[0];
  const float* W_enc = (const float*)d_in[1];
  const float* b_enc = (const float*)d_in[2];
  const float* W_lstm = (const float*)d_in[3];
  const float* U_lstm = (const float*)d_in[4];
  const float* b_lstm = (const float*)d_in[5];
  const float* W_key = (const float*)d_in[6];
  const float* b_key = (const float*)d_in[7];
  const float* W_g = (const float*)d_in[8];
  const float* b_g = (const float*)d_in[9];
  const float* W_y = (const float*)d_in[10];
  const float* b_y = (const float*)d_in[11];
  const float* gamma = (const float*)d_in[12];
  const float* beta = (const float*)d_in[13];
  const float* cg_ = (const float*)d_in[14];
  const float* cb = (const float*)d_in[15];

  char* p = (char*)d_ws;
  auto alloc = [&](size_t bytes) {
    char* r = p;
    p += (bytes + 255) & ~(size_t)255;
    return r;
  };
  float* zbuf = (float*)alloc((size_t)16384 * 128 * 4);
  float* z_full = (float*)alloc((size_t)512 * 33 * 128 * 4);
  unsigned short* WcombT = (unsigned short*)alloc((size_t)2048 * 800 * 2);
  unsigned short* WencT = (unsigned short*)alloc((size_t)128 * 1024 * 2);
  unsigned short* Wk2T = (unsigned short*)alloc((size_t)320 * 512 * 2);
  float* bias2 = (float*)alloc(320 * 4);
  unsigned short* xinA = (unsigned short*)alloc((size_t)512 * 800 * 2);
  unsigned short* xinB = (unsigned short*)alloc((size_t)512 * 800 * 2);
  float* h = (float*)alloc((size_t)512 * 512 * 4);
  unsigned short* hbf = (unsigned short*)alloc((size_t)512 * 512 * 2);
  float* Mk = (float*)alloc((size_t)512 * 33 * 256 * 4);
  float* logits = (float*)alloc((size_t)512 * 4 * 4);
  float* wk_tbl = (float*)alloc((size_t)512 * 33 * 33 * 4);
  float* wck_tbl = (float*)alloc((size_t)512 * 33 * 4);
  unsigned* bar = (unsigned*)alloc(16384);
  float* outp = (float*)d_out;

  const int prep_total = 2048 * 800 + 320 * 512 + 128 * 1024 + 320 + 2 * 512 * 800 +
                         512 * 512 + 512 * 128 + 4096;
  k_prep<<<(prep_total + 255) / 256, 256, 0, stream>>>(
      W_lstm, U_lstm, W_enc, W_key, W_g, W_y, b_key, b_g, b_y,
      WcombT, Wk2T, WencT, bias2, xinA, xinB, h, z_full, bar);
  k_enc<<<256, 512, 0, stream>>>(x_seq, WencT, b_enc, zbuf);
  k_ln<<<256, 256, 0, stream>>>(zbuf, gamma, beta, z_full);
  k_attnpre<<<512, 256, 0, stream>>>(z_full, cg_, cb, wk_tbl, wck_tbl);

  void* cargs[16];
  cargs[0] = &xinA;  cargs[1] = &xinB;   cargs[2] = &WcombT; cargs[3] = &b_lstm;
  cargs[4] = &h;     cargs[5] = &hbf;    cargs[6] = &Wk2T;   cargs[7] = &bias2;
  cargs[8] = &Mk;    cargs[9] = &logits; cargs[10] = &W_g;   cargs[11] = &b_g;
  cargs[12] = &wk_tbl; cargs[13] = &wck_tbl; cargs[14] = &outp; cargs[15] = &bar;
  hipError_t ce = hipLaunchCooperativeKernel((const void*)k_loop, dim3(256), dim3(256),
                                             cargs, 0u, stream);
  if (ce != hipSuccess) {
    // fallback: per-step launches (previous verified path)
    for (int t = 0; t < 33; ++t) {
      unsigned short* cur = (t & 1) ? xinB : xinA;
      unsigned short* nxt = (t & 1) ? xinA : xinB;
      k_gates<<<dim3(32, 8), 256, 0, stream>>>(cur, WcombT, b_lstm, h, hbf, nxt);
      k_head<<<552, 256, 0, stream>>>(hbf, Wk2T, bias2, Mk, logits, h,
                                      W_g, b_g, wk_tbl, wck_tbl, nxt, t);
    }
    k_softmax<<<1, 256, 0, stream>>>(logits, outp);
  }
}

// Round 7
// 777.495 us; speedup vs baseline: 3.3294x; 1.0067x over previous
//
#include <hip/hip_runtime.h>

typedef __attribute__((ext_vector_type(8))) short short8;
typedef __attribute__((ext_vector_type(4))) float f32x4;
typedef __attribute__((ext_vector_type(8))) unsigned short ushort8;
typedef __attribute__((ext_vector_type(4))) unsigned short ushort4v;

__device__ __forceinline__ unsigned short f2bf(float f) {
  union { float f; unsigned u; } v; v.f = f;
  unsigned u = v.u;
  u += 0x7fffu + ((u >> 16) & 1u);
  return (unsigned short)(u >> 16);
}
__device__ __forceinline__ float sigm(float x) { return 1.f / (1.f + __expf(-x)); }
__device__ __forceinline__ float ftanh(float x) { return 1.f - 2.f / (__expf(2.f * x) + 1.f); }

// async global->LDS, 16B per lane. LDS dest must be WAVE-UNIFORM base; HW adds lane*16.
__device__ __forceinline__ void gl16(const unsigned short* g, unsigned short* l) {
  __builtin_amdgcn_global_load_lds((const __attribute__((address_space(1))) void*)g,
                                   (__attribute__((address_space(3))) void*)l, 16, 0, 0);
}

// ---- coherent (system-scope, performed at Infinity Cache) access helpers ----
__device__ __forceinline__ uint4 ld16_sys(const void* base, int off) {
  uint4 r;
  asm volatile("global_load_dwordx4 %0, %1, %2 sc0 sc1"
               : "=v"(r) : "v"(off), "s"(base) : "memory");
  return r;
}
__device__ __forceinline__ uint4 ld16_asm(const void* base, int off) {  // plain, asm-counted
  uint4 r;
  asm volatile("global_load_dwordx4 %0, %1, %2"
               : "=v"(r) : "v"(off), "s"(base) : "memory");
  return r;
}
__device__ __forceinline__ float ldf_sys(const void* base, int off) {
  float r;
  asm volatile("global_load_dword %0, %1, %2 sc0 sc1"
               : "=v"(r) : "v"(off), "s"(base) : "memory");
  return r;
}
__device__ __forceinline__ unsigned ldu_sys(const void* base, int off) {
  unsigned r;
  asm volatile("global_load_dword %0, %1, %2 sc0 sc1"
               : "=v"(r) : "v"(off), "s"(base) : "memory");
  return r;
}
__device__ __forceinline__ void stf_sys(void* base, int off, float v) {
  asm volatile("global_store_dword %0, %1, %2 sc0 sc1"
               :: "v"(off), "v"(v), "s"(base) : "memory");
}
__device__ __forceinline__ void stu_sys(void* base, int off, unsigned v) {
  asm volatile("global_store_dword %0, %1, %2 sc0 sc1"
               :: "v"(off), "v"(v), "s"(base) : "memory");
}
__device__ __forceinline__ void sth_sys(void* base, int off, unsigned short v) {
  asm volatile("global_store_short %0, %1, %2 sc0 sc1"
               :: "v"(off), "v"(v), "s"(base) : "memory");
}
#define WAITVM(N)                                          \
  asm volatile("s_waitcnt vmcnt(" #N ")" ::: "memory");    \
  __builtin_amdgcn_sched_barrier(0)

// Atomic-free flag barrier (proven round 6): block b sc1-stores its generation
// into flags[b*16]; thread tid spins on block tid's slot. v>=gen tolerates
// fast blocks racing ahead. Data stores drained (vmcnt 0) before the flag.
__device__ __forceinline__ void gbar(unsigned* flags, unsigned gen) {
  asm volatile("s_waitcnt vmcnt(0)" ::: "memory");  // all data stores acked at mall
  __syncthreads();
  if (threadIdx.x == 0) stu_sys(flags, (int)(blockIdx.x * 64), gen);
  int off = (int)(threadIdx.x * 64);
  for (;;) {
    unsigned v = ldu_sys(flags, off);
    asm volatile("s_waitcnt vmcnt(0)" ::: "memory");
    if (v >= gen) break;
    __builtin_amdgcn_s_sleep(1);
  }
  __syncthreads();
}

#define LSTR 40  // LDS row stride (elems) for the prologue GEMM

// ---------------------------------------------------------------------------
// Prep: build bf16 transposed/permuted weights, zero state buffers + flags.
// ---------------------------------------------------------------------------
__global__ void k_prep(const float* __restrict__ W_lstm, const float* __restrict__ U_lstm,
                       const float* __restrict__ W_enc, const float* __restrict__ W_key,
                       const float* __restrict__ W_g, const float* __restrict__ W_y,
                       const float* __restrict__ b_key, const float* __restrict__ b_g,
                       const float* __restrict__ b_y,
                       unsigned short* __restrict__ WcombT, unsigned short* __restrict__ Wk2T,
                       unsigned short* __restrict__ WencT, float* __restrict__ bias2,
                       unsigned short* __restrict__ xinA, unsigned short* __restrict__ xinB,
                       float* __restrict__ h, float* __restrict__ z_full,
                       unsigned* __restrict__ bar) {
  const int N1 = 2048 * 800, N2 = 320 * 512, N3 = 128 * 1024, N4 = 320,
            N5 = 512 * 800, N7 = 512 * 512, N8 = 512 * 128, N9 = 4096;
  int i = blockIdx.x * 256 + threadIdx.x;
  if (i < N1) {
    int np = i / 800, k = i - np * 800;
    int j = np >> 2, gate = np & 3, n = gate * 512 + j;
    float v = 0.f;
    if (k < 257) v = W_lstm[k * 2048 + n];
    else if (k >= 288) v = U_lstm[(k - 288) * 2048 + n];
    WcombT[i] = f2bf(v);
    return;
  }
  i -= N1;
  if (i < N2) {
    int n = i / 512, k = i - n * 512;
    float v = 0.f;
    if (n < 256) v = W_key[k * 256 + n];
    else if (n == 256) v = W_g[k];
    else if (n < 261) v = W_y[k * 4 + (n - 257)];
    Wk2T[i] = f2bf(v);
    return;
  }
  i -= N2;
  if (i < N3) {
    int n = i / 1024, k = i - n * 1024;
    WencT[i] = f2bf(W_enc[k * 128 + n]);
    return;
  }
  i -= N3;
  if (i < N4) {
    float v = (i < 256) ? b_key[i] : (i == 256 ? b_g[0] : (i < 261 ? b_y[i - 257] : 0.f));
    bias2[i] = v;
    return;
  }
  i -= N4;
  if (i < N5) { xinA[i] = 0; return; }
  i -= N5;
  if (i < N5) { xinB[i] = 0; return; }
  i -= N5;
  if (i < N7) { h[i] = 0.f; return; }
  i -= N7;
  if (i < N8) {
    int b = i >> 7, z = i & 127;
    z_full[(b * 33 + 32) * 128 + z] = 0.f;  // null slot
    return;
  }
  i -= N8;
  if (i < N9) bar[i] = 0;
}

// ---------------------------------------------------------------------------
// Encoder GEMM (proven): 64Mx128N tile, BK=32, K=1024, 512 threads.
// ---------------------------------------------------------------------------
__global__ __launch_bounds__(512) void k_enc(const float* __restrict__ x,
                                             const unsigned short* __restrict__ WencT,
                                             const float* __restrict__ b_enc,
                                             float* __restrict__ zbuf) {
  __shared__ __align__(16) unsigned short As[2][64 * LSTR];
  __shared__ __align__(16) unsigned short Bs[2][128 * LSTR];
  int tid = threadIdx.x;
  int m0 = blockIdx.x * 64;
  int lane = tid & 63, wid = tid >> 6;
  int wm = (wid >> 2) * 32, wn = (wid & 3) * 32;
  int q = lane >> 4, r = lane & 15;
  int ldrowA = tid >> 3, ldcA = (tid & 7) * 4;
  int ldrowB = tid >> 2, ldcB = (tid & 3) * 8;
  const float4* Ag = reinterpret_cast<const float4*>(x + (size_t)(m0 + ldrowA) * 1024);
  const uint4* Bg = reinterpret_cast<const uint4*>(WencT + (size_t)ldrowB * 1024);
  float4 ra = Ag[ldcA >> 2];
  uint4 rb = Bg[ldcB >> 3];
  f32x4 acc[2][2] = {};
  int s = 0;
  {
    ushort4v t4;
    t4[0] = f2bf(ra.x); t4[1] = f2bf(ra.y); t4[2] = f2bf(ra.z); t4[3] = f2bf(ra.w);
    *reinterpret_cast<ushort4v*>(&As[0][ldrowA * LSTR + ldcA]) = t4;
    *reinterpret_cast<uint4*>(&Bs[0][ldrowB * LSTR + ldcB]) = rb;
  }
  __syncthreads();
  for (int kk = 0; kk < 32; ++kk) {
    if (kk < 31) {
      int k0 = (kk + 1) * 32;
      ra = Ag[(k0 + ldcA) >> 2];
      rb = Bg[(k0 + ldcB) >> 3];
    }
    short8 a0 = *reinterpret_cast<const short8*>(&As[s][(wm + r) * LSTR + q * 8]);
    short8 a1 = *reinterpret_cast<const short8*>(&As[s][(wm + 16 + r) * LSTR + q * 8]);
    short8 b0 = *reinterpret_cast<const short8*>(&Bs[s][(wn + r) * LSTR + q * 8]);
    short8 b1 = *reinterpret_cast<const short8*>(&Bs[s][(wn + 16 + r) * LSTR + q * 8]);
    acc[0][0] = __builtin_amdgcn_mfma_f32_16x16x32_bf16(a0, b0, acc[0][0], 0, 0, 0);
    acc[0][1] = __builtin_amdgcn_mfma_f32_16x16x32_bf16(a0, b1, acc[0][1], 0, 0, 0);
    acc[1][0] = __builtin_amdgcn_mfma_f32_16x16x32_bf16(a1, b0, acc[1][0], 0, 0, 0);
    acc[1][1] = __builtin_amdgcn_mfma_f32_16x16x32_bf16(a1, b1, acc[1][1], 0, 0, 0);
    if (kk < 31) {
      ushort4v t4;
      t4[0] = f2bf(ra.x); t4[1] = f2bf(ra.y); t4[2] = f2bf(ra.z); t4[3] = f2bf(ra.w);
      *reinterpret_cast<ushort4v*>(&As[s ^ 1][ldrowA * LSTR + ldcA]) = t4;
      *reinterpret_cast<uint4*>(&Bs[s ^ 1][ldrowB * LSTR + ldcB]) = rb;
      s ^= 1;
    }
    __syncthreads();
  }
#pragma unroll
  for (int mt = 0; mt < 2; ++mt)
#pragma unroll
    for (int nt = 0; nt < 2; ++nt)
#pragma unroll
      for (int e = 0; e < 4; ++e) {
        int row = m0 + wm + mt * 16 + q * 4 + e;
        int col = wn + nt * 16 + r;
        zbuf[(size_t)row * 128 + col] = fmaxf(acc[mt][nt][e] + b_enc[col], 0.f);
      }
}

// ---------------------------------------------------------------------------
// LayerNorm over the BATCH axis per (t,z).
// ---------------------------------------------------------------------------
__global__ __launch_bounds__(256) void k_ln(const float* __restrict__ zbuf,
                                            const float* __restrict__ gamma,
                                            const float* __restrict__ beta,
                                            float* __restrict__ z_full) {
  int bid = blockIdx.x;
  int tstep = bid >> 3;
  int z0 = (bid & 7) * 16;
  int tid = threadIdx.x;
  int zl = tid & 15, bg = tid >> 4;
  __shared__ float ps[256], qs[256];
  __shared__ float muS[16], rsS[16];
  float s = 0.f, ss = 0.f;
  for (int ii = 0; ii < 32; ++ii) {
    int b = bg * 32 + ii;
    float v = zbuf[(size_t)(b * 32 + tstep) * 128 + z0 + zl];
    s += v; ss += v * v;
  }
  ps[tid] = s; qs[tid] = ss;
  __syncthreads();
  if (tid < 16) {
    float S = 0.f, Q = 0.f;
    for (int g2 = 0; g2 < 16; ++g2) { S += ps[g2 * 16 + tid]; Q += qs[g2 * 16 + tid]; }
    float mu = S / 512.f;
    float var = Q / 512.f - mu * mu;
    muS[tid] = mu;
    rsS[tid] = rsqrtf(var + 1e-8f);
  }
  __syncthreads();
  float ga = gamma[z0 + zl], be = beta[z0 + zl];
  float mu = muS[zl], rs = rsS[zl];
  for (int ii = 0; ii < 32; ++ii) {
    int b = bg * 32 + ii;
    float v = zbuf[(size_t)(b * 32 + tstep) * 128 + z0 + zl];
    z_full[(size_t)(b * 33 + tstep) * 128 + z0 + zl] = (v - mu) * rs * ga + be;
  }
}

// ---------------------------------------------------------------------------
// Attention precompute (w_k and wck for all t, once).
// ---------------------------------------------------------------------------
__global__ __launch_bounds__(256) void k_attnpre(const float* __restrict__ z_full,
                                                 const float* __restrict__ cgain,
                                                 const float* __restrict__ cbias,
                                                 float* __restrict__ wk_tbl,
                                                 float* __restrict__ wck_tbl) {
  __shared__ float zs[33 * 128];
  __shared__ float sim[33 * 33];
  int b = blockIdx.x, tid = threadIdx.x;
  const float* zb = z_full + (size_t)b * 33 * 128;
  for (int i = tid; i < 33 * 128; i += 256) zs[i] = zb[i];
  __syncthreads();
  for (int p = tid; p < 33 * 33; p += 256) {
    int t = p / 33, n = p - t * 33;
    float s = 0.f;
    if (n < t) {
#pragma unroll 8
      for (int k2 = 0; k2 < 128; ++k2) s += zs[t * 128 + k2] * zs[n * 128 + k2];
    }
    sim[p] = s;
  }
  __syncthreads();
  if (tid >= 1 && tid < 33) {
    int t = tid;
    float cg = cgain[0], cb2 = cbias[0];
    float m = -3.0e38f;
    for (int n = 0; n < t; ++n) m = fmaxf(m, sim[t * 33 + n]);
    float ssum = 0.f;
    for (int n = 0; n < t; ++n) ssum += __expf(sim[t * 33 + n] - m);
    float inv = 1.f / ssum;
    float wck = 0.f;
    for (int n = 0; n < t; ++n) {
      float wk = __expf(sim[t * 33 + n] - m) * inv;
      wk_tbl[((size_t)b * 33 + t) * 33 + n] = wk;
      float ck = 1.f / (1.f + __expf(-(sim[t * 33 + n] * cg + cb2)));
      wck += wk * ck;
    }
    wck_tbl[b * 33 + t] = wck;
  }
}

// ---------------------------------------------------------------------------
// Persistent kernel: round-6-proven body; ONE change — phase A issues all 25
// A-tile loads upfront with counted-vmcnt drains (one exposed mall latency
// instead of five).
// ---------------------------------------------------------------------------
__global__ __launch_bounds__(256) void k_loop(
    unsigned short* __restrict__ xinA, unsigned short* __restrict__ xinB,
    const unsigned short* __restrict__ WT, const float* __restrict__ b_lstm,
    float* __restrict__ h, unsigned short* __restrict__ hbf,
    const unsigned short* __restrict__ Wk2T, const float* __restrict__ bias2,
    float* __restrict__ Mk, float* __restrict__ logits,
    const float* __restrict__ Wg, const float* __restrict__ bg,
    const float* __restrict__ wk_tbl, const float* __restrict__ wck_tbl,
    float* __restrict__ out, unsigned* __restrict__ bar) {
  __shared__ __align__(16) unsigned short Bres[64 * 808];  // 103424 B, resident
  __shared__ __align__(16) unsigned char scr[43136];       // A0/A1, Cs, wkS
  const int tid = threadIdx.x, bid = blockIdx.x;
  const int lane = tid & 63, w = tid >> 6;
  const int q = lane >> 4, r = lane & 15;
  const int wm = (w >> 1) * 32, wn = (w & 1) * 32;
  const int nn = bid & 31, mi = bid >> 5;  // gates tile
  const int m0 = mi * 64, n0g = nn * 64;
  unsigned gen = 0;

  // ---- pin B slice (static): 64 rows x 808 (800 data + 8 pad), via gl16 with
  // wave-uniform LDS base + per-lane pre-swizzled global source. 6464 granules.
  for (int l = 0; l < 26; ++l) {
    int gw = l * 256 + w * 64;  // wave-uniform granule base
    if (gw < 6464) {
      int g = gw + lane;
      int row = g / 101, cg = g - row * 101;
      int col = (cg >= 100) ? 792 : cg * 8;  // pad granule: load junk (unread)
      gl16(WT + (size_t)(n0g + row) * 800 + col, Bres + gw * 8);
    }
  }

  // per-thread A-stage coords: 1280 data granules = 5 x 256 (row-major 64x160)
  int srow[5], scol[5];
#pragma unroll
  for (int l = 0; l < 5; ++l) {
    int idx = l * 256 + tid;
    srow[l] = idx / 20;
    scol[l] = (idx - srow[l] * 20) * 8;
  }
  unsigned short* A0 = (unsigned short*)scr;             // 64*168*2 = 21504 B
  unsigned short* A1 = (unsigned short*)(scr + 21504);   // 21504 B

  const int jl = tid & 15, jg = nn * 16 + jl, rl0 = tid >> 4;
  const float bL0 = b_lstm[jg], bL1 = b_lstm[512 + jg],
              bL2 = b_lstm[1024 + jg], bL3 = b_lstm[1536 + jg];
  float hreg[4] = {0.f, 0.f, 0.f, 0.f};

  const int mi2 = bid / 5, ni2 = bid - mi2 * 5;  // head-GEMM tile (bid<40)

  asm volatile("s_waitcnt vmcnt(0)" ::: "memory");
  __syncthreads();

  for (int t = 0; t < 33; ++t) {
    const unsigned short* cur = (t & 1) ? xinB : xinA;
    unsigned short* nxt = (t & 1) ? xinA : xinB;

    // ====== phase A: gates GEMM (64x64, K=800=5x160) + LSTM cell =============
    // issue ALL 25 A-tile loads upfront (one mall latency; counted drains)
    uint4 R[25];
#pragma unroll
    for (int c = 0; c < 5; ++c)
#pragma unroll
      for (int l = 0; l < 5; ++l)
        R[c * 5 + l] = ld16_sys(cur, ((m0 + srow[l]) * 800 + c * 160 + scol[l]) * 2);
    WAITVM(20);  // chunk 0 landed
#pragma unroll
    for (int l = 0; l < 5; ++l)
      *(uint4*)&A0[srow[l] * 168 + scol[l]] = R[l];
    __syncthreads();

    f32x4 acc[2][2] = {};
#pragma unroll
    for (int c = 0; c < 5; ++c) {
      const unsigned short* Ac = (c & 1) ? A1 : A0;
      unsigned short* An = (c & 1) ? A0 : A1;
#pragma unroll
      for (int ks = 0; ks < 5; ++ks) {
        short8 a0 = *(const short8*)&Ac[(wm + r) * 168 + ks * 32 + q * 8];
        short8 a1 = *(const short8*)&Ac[(wm + 16 + r) * 168 + ks * 32 + q * 8];
        short8 b0 = *(const short8*)&Bres[(wn + r) * 808 + c * 160 + ks * 32 + q * 8];
        short8 b1 = *(const short8*)&Bres[(wn + 16 + r) * 808 + c * 160 + ks * 32 + q * 8];
        acc[0][0] = __builtin_amdgcn_mfma_f32_16x16x32_bf16(a0, b0, acc[0][0], 0, 0, 0);
        acc[0][1] = __builtin_amdgcn_mfma_f32_16x16x32_bf16(a0, b1, acc[0][1], 0, 0, 0);
        acc[1][0] = __builtin_amdgcn_mfma_f32_16x16x32_bf16(a1, b0, acc[1][0], 0, 0, 0);
        acc[1][1] = __builtin_amdgcn_mfma_f32_16x16x32_bf16(a1, b1, acc[1][1], 0, 0, 0);
      }
      if (c < 4) {
        if (c == 0)      { WAITVM(15); }
        else if (c == 1) { WAITVM(10); }
        else if (c == 2) { WAITVM(5); }
        else             { WAITVM(0); }
#pragma unroll
        for (int l = 0; l < 5; ++l)
          *(uint4*)&An[srow[l] * 168 + scol[l]] = R[(c + 1) * 5 + l];
        __syncthreads();
      }
    }
    __syncthreads();  // drain last buffer reads before Cs overwrites A0

    // ---- fused LSTM cell (h-carry in registers; coherent stores) ----
    float* Cs = (float*)scr;
#pragma unroll
    for (int mt = 0; mt < 2; ++mt)
#pragma unroll
      for (int nt = 0; nt < 2; ++nt)
#pragma unroll
        for (int e = 0; e < 4; ++e)
          Cs[(wm + mt * 16 + q * 4 + e) * 65 + wn + nt * 16 + r] = acc[mt][nt][e];
    __syncthreads();
#pragma unroll
    for (int it = 0; it < 4; ++it) {
      int rl = it * 16 + rl0;
      int brow = m0 + rl;
      float gi = Cs[rl * 65 + jl * 4 + 0] + bL0;
      float gf = Cs[rl * 65 + jl * 4 + 1] + bL1;
      float gc = Cs[rl * 65 + jl * 4 + 2] + bL2;
      float go = Cs[rl * 65 + jl * 4 + 3] + bL3;
      float cnew = sigm(gf) * hreg[it] + sigm(gi) * ftanh(gc);
      float hnew = sigm(go) * ftanh(cnew);
      hreg[it] = hnew;
      stf_sys(h, (brow * 512 + jg) * 4, hnew);
      sth_sys(hbf, (brow * 512 + jg) * 2, f2bf(hnew));
      sth_sys(nxt, (brow * 800 + 288 + jg) * 2, f2bf(cnew));
    }
    ++gen; gbar(bar, gen);

    // ====== phase B ==========================================================
    if (bid < 40) {
      // head GEMM 64x64, K=512: LDS-free, depth-3 reg pipeline, counted vmcnt.
      int m0b = mi2 * 64, n0b = ni2 * 64;
      int aoff0 = ((m0b + wm + r) * 512 + q * 8) * 2;
      int aoff1 = aoff0 + 16 * 1024;
      int boff0 = ((n0b + wn + r) * 512 + q * 8) * 2;
      int boff1 = boff0 + 16 * 1024;
      uint4 ab[4][2], bb[4][2];
      f32x4 acc2[2][2] = {};
#pragma unroll
      for (int j = 0; j < 3; ++j) {
        ab[j][0] = ld16_sys(hbf, aoff0 + j * 64);   // hbf: remote-written -> sc1
        ab[j][1] = ld16_sys(hbf, aoff1 + j * 64);
        bb[j][0] = ld16_asm(Wk2T, boff0 + j * 64);  // Wk2T: static -> plain (L2)
        bb[j][1] = ld16_asm(Wk2T, boff1 + j * 64);
      }
#pragma unroll
      for (int kk = 0; kk < 16; ++kk) {
        if (kk < 13) {
          int j = kk + 3;
          ab[j & 3][0] = ld16_sys(hbf, aoff0 + j * 64);
          ab[j & 3][1] = ld16_sys(hbf, aoff1 + j * 64);
          bb[j & 3][0] = ld16_asm(Wk2T, boff0 + j * 64);
          bb[j & 3][1] = ld16_asm(Wk2T, boff1 + j * 64);
        }
        if (kk < 13) { WAITVM(12); }
        else if (kk == 13) { WAITVM(8); }
        else if (kk == 14) { WAITVM(4); }
        else { WAITVM(0); }
        short8 a0 = *(const short8*)&ab[kk & 3][0];
        short8 a1 = *(const short8*)&ab[kk & 3][1];
        short8 b0s = *(const short8*)&bb[kk & 3][0];
        short8 b1s = *(const short8*)&bb[kk & 3][1];
        acc2[0][0] = __builtin_amdgcn_mfma_f32_16x16x32_bf16(a0, b0s, acc2[0][0], 0, 0, 0);
        acc2[0][1] = __builtin_amdgcn_mfma_f32_16x16x32_bf16(a0, b1s, acc2[0][1], 0, 0, 0);
        acc2[1][0] = __builtin_amdgcn_mfma_f32_16x16x32_bf16(a1, b0s, acc2[1][0], 0, 0, 0);
        acc2[1][1] = __builtin_amdgcn_mfma_f32_16x16x32_bf16(a1, b1s, acc2[1][1], 0, 0, 0);
      }
#pragma unroll
      for (int mt = 0; mt < 2; ++mt)
#pragma unroll
        for (int nt = 0; nt < 2; ++nt)
#pragma unroll
          for (int e2 = 0; e2 < 4; ++e2) {
            int row = m0b + wm + mt * 16 + q * 4 + e2;
            int np = n0b + wn + nt * 16 + r;
            float v = acc2[mt][nt][e2] + bias2[np];
            if (np < 256)
              stf_sys(Mk, ((row * 33 + t) * 256 + np) * 4, fmaxf(v, 0.f));
            else if (np >= 257 && np < 261)
              stf_sys(logits, (row * 4 + (np - 257)) * 4, v);
          }
    } else if (t > 0 && t < 32) {
      // attention read: g gate + weighted = sum_{n<t} wk * Mk -> key_r for t+1
      float* wkS = (float*)scr;
      float* red4 = (float*)(scr + 512);
      for (int rr = 0; rr < 3; ++rr) {
        int b = (bid - 40) + 216 * rr;
        if (b < 512) {
          float ha = ldf_sys(h, (b * 512 + tid) * 4);
          float hb = ldf_sys(h, (b * 512 + 256 + tid) * 4);
          asm volatile("s_waitcnt vmcnt(0)" ::: "memory");
          float sd = ha * Wg[tid] + hb * Wg[256 + tid];
#pragma unroll
          for (int off = 32; off > 0; off >>= 1) sd += __shfl_down(sd, off);
          if (lane == 0) red4[w] = sd;
          if (tid < t) wkS[tid] = wk_tbl[((size_t)b * 33 + t) * 33 + tid];
          __syncthreads();
          float g = 1.f / (1.f + __expf(-(red4[0] + red4[1] + red4[2] + red4[3] + bg[0])));
          float p0 = 0.f, p1 = 0.f, p2 = 0.f, p3 = 0.f;
          int n = 0;
          for (; n + 4 <= t; n += 4) {
            p0 += wkS[n] * Mk[((size_t)b * 33 + n) * 256 + tid];
            p1 += wkS[n + 1] * Mk[((size_t)b * 33 + n + 1) * 256 + tid];
            p2 += wkS[n + 2] * Mk[((size_t)b * 33 + n + 2) * 256 + tid];
            p3 += wkS[n + 3] * Mk[((size_t)b * 33 + n + 3) * 256 + tid];
          }
          for (; n < t; ++n) p0 += wkS[n] * Mk[((size_t)b * 33 + n) * 256 + tid];
          sth_sys(nxt, (b * 800 + tid) * 2, f2bf(g * ((p0 + p1) + (p2 + p3))));
          if (tid == 0) sth_sys(nxt, (b * 800 + 256) * 2, f2bf(g * wck_tbl[b * 33 + t]));
          __syncthreads();
        }
      }
    }
    ++gen; gbar(bar, gen);
  }
  // final 4-wide softmax (block 0; logits lines are first-touch here -> coherent)
  if (bid == 0) {
    for (int r2 = tid; r2 < 512; r2 += 256) {
      float a = ldf_sys(logits, r2 * 16);
      float b2 = ldf_sys(logits, r2 * 16 + 4);
      float c2 = ldf_sys(logits, r2 * 16 + 8);
      float d2 = ldf_sys(logits, r2 * 16 + 12);
      asm volatile("s_waitcnt vmcnt(0)" ::: "memory");
      float m = fmaxf(fmaxf(a, b2), fmaxf(c2, d2));
      float ea = __expf(a - m), eb = __expf(b2 - m), ec = __expf(c2 - m), ed = __expf(d2 - m);
      float ssum = ea + eb + ec + ed;
      out[r2 * 4] = ea / ssum; out[r2 * 4 + 1] = eb / ssum;
      out[r2 * 4 + 2] = ec / ssum; out[r2 * 4 + 3] = ed / ssum;
    }
  }
}

// ---------------------------------------------------------------------------
// Fallback per-step kernels (used only if cooperative-style launch fails).
// ---------------------------------------------------------------------------
__global__ __launch_bounds__(256) void k_gates(const unsigned short* __restrict__ xin,
                                               const unsigned short* __restrict__ WT,
                                               const float* __restrict__ b_lstm,
                                               float* __restrict__ h,
                                               unsigned short* __restrict__ hbf,
                                               unsigned short* __restrict__ xin_nxt) {
  __shared__ __align__(16) unsigned short As[2][64 * LSTR];
  __shared__ __align__(16) unsigned short Bs[2][64 * LSTR];
  __shared__ float Cs[64 * 65];
  int tid = threadIdx.x;
  int nn = blockIdx.x;
  int m0 = blockIdx.y * 64;
  int n0 = nn * 64;
  int lane = tid & 63, wid = tid >> 6;
  int wm = (wid >> 1) * 32, wn = (wid & 1) * 32;
  int q = lane >> 4, r = lane & 15;
  int ldrow = tid >> 2, ldc = (tid & 3) * 8;
  const uint4* Ag = reinterpret_cast<const uint4*>(xin + (size_t)(m0 + ldrow) * 800);
  const uint4* Bg = reinterpret_cast<const uint4*>(WT + (size_t)(n0 + ldrow) * 800);
  uint4 ra = Ag[ldc >> 3], rb = Bg[ldc >> 3];
  f32x4 acc[2][2] = {};
  int s = 0;
  *reinterpret_cast<uint4*>(&As[0][ldrow * LSTR + ldc]) = ra;
  *reinterpret_cast<uint4*>(&Bs[0][ldrow * LSTR + ldc]) = rb;
  __syncthreads();
  for (int kk = 0; kk < 25; ++kk) {
    if (kk < 24) {
      int k0 = (kk + 1) * 32;
      ra = Ag[(k0 + ldc) >> 3];
      rb = Bg[(k0 + ldc) >> 3];
    }
    short8 a0 = *reinterpret_cast<const short8*>(&As[s][(wm + r) * LSTR + q * 8]);
    short8 a1 = *reinterpret_cast<const short8*>(&As[s][(wm + 16 + r) * LSTR + q * 8]);
    short8 b0 = *reinterpret_cast<const short8*>(&Bs[s][(wn + r) * LSTR + q * 8]);
    short8 b1 = *reinterpret_cast<const short8*>(&Bs[s][(wn + 16 + r) * LSTR + q * 8]);
    acc[0][0] = __builtin_amdgcn_mfma_f32_16x16x32_bf16(a0, b0, acc[0][0], 0, 0, 0);
    acc[0][1] = __builtin_amdgcn_mfma_f32_16x16x32_bf16(a0, b1, acc[0][1], 0, 0, 0);
    acc[1][0] = __builtin_amdgcn_mfma_f32_16x16x32_bf16(a1, b0, acc[1][0], 0, 0, 0);
    acc[1][1] = __builtin_amdgcn_mfma_f32_16x16x32_bf16(a1, b1, acc[1][1], 0, 0, 0);
    if (kk < 24) {
      *reinterpret_cast<uint4*>(&As[s ^ 1][ldrow * LSTR + ldc]) = ra;
      *reinterpret_cast<uint4*>(&Bs[s ^ 1][ldrow * LSTR + ldc]) = rb;
      s ^= 1;
    }
    __syncthreads();
  }
#pragma unroll
  for (int mt = 0; mt < 2; ++mt)
#pragma unroll
    for (int nt = 0; nt < 2; ++nt)
#pragma unroll
      for (int e = 0; e < 4; ++e)
        Cs[(wm + mt * 16 + q * 4 + e) * 65 + wn + nt * 16 + r] = acc[mt][nt][e];
  __syncthreads();
#pragma unroll
  for (int it = 0; it < 4; ++it) {
    int id = it * 256 + tid;
    int rl = id >> 4, jl = id & 15;
    int brow = m0 + rl;
    int j = nn * 16 + jl;
    float gi = Cs[rl * 65 + jl * 4 + 0] + b_lstm[j];
    float gf = Cs[rl * 65 + jl * 4 + 1] + b_lstm[512 + j];
    float gg = Cs[rl * 65 + jl * 4 + 2] + b_lstm[1024 + j];
    float go = Cs[rl * 65 + jl * 4 + 3] + b_lstm[1536 + j];
    float hold = h[brow * 512 + j];
    float cnew = sigm(gf) * hold + sigm(gi) * ftanh(gg);
    float hnew = sigm(go) * ftanh(cnew);
    h[brow * 512 + j] = hnew;
    hbf[brow * 512 + j] = f2bf(hnew);
    xin_nxt[brow * 800 + 288 + j] = f2bf(cnew);
  }
}

__global__ __launch_bounds__(256) void k_head(const unsigned short* __restrict__ hbf,
                                              const unsigned short* __restrict__ Wk2T,
                                              const float* __restrict__ bias2,
                                              float* __restrict__ Mk,
                                              float* __restrict__ logits,
                                              const float* __restrict__ h,
                                              const float* __restrict__ Wg,
                                              const float* __restrict__ bg,
                                              const float* __restrict__ wk_tbl,
                                              const float* __restrict__ wck_tbl,
                                              unsigned short* __restrict__ xin_nxt,
                                              int t) {
  __shared__ __align__(16) unsigned short As[2][64 * LSTR];
  __shared__ __align__(16) unsigned short Bs[2][64 * LSTR];
  __shared__ float wkS[33];
  __shared__ float red[256];
  int bid = blockIdx.x;
  int tid = threadIdx.x;
  if (bid < 40) {
    int mi = bid / 5, ni = bid - mi * 5;
    int m0 = mi * 64, n0 = ni * 64;
    int lane = tid & 63, wid = tid >> 6;
    int wm = (wid >> 1) * 32, wn = (wid & 1) * 32;
    int q = lane >> 4, r = lane & 15;
    int ldrow = tid >> 2, ldc = (tid & 3) * 8;
    const uint4* Ag = reinterpret_cast<const uint4*>(hbf + (size_t)(m0 + ldrow) * 512);
    const uint4* Bg = reinterpret_cast<const uint4*>(Wk2T + (size_t)(n0 + ldrow) * 512);
    uint4 ra = Ag[ldc >> 3], rb = Bg[ldc >> 3];
    f32x4 acc[2][2] = {};
    int s = 0;
    *reinterpret_cast<uint4*>(&As[0][ldrow * LSTR + ldc]) = ra;
    *reinterpret_cast<uint4*>(&Bs[0][ldrow * LSTR + ldc]) = rb;
    __syncthreads();
    for (int kk = 0; kk < 16; ++kk) {
      if (kk < 15) {
        int k0 = (kk + 1) * 32;
        ra = Ag[(k0 + ldc) >> 3];
        rb = Bg[(k0 + ldc) >> 3];
      }
      short8 a0 = *reinterpret_cast<const short8*>(&As[s][(wm + r) * LSTR + q * 8]);
      short8 a1 = *reinterpret_cast<const short8*>(&As[s][(wm + 16 + r) * LSTR + q * 8]);
      short8 b0 = *reinterpret_cast<const short8*>(&Bs[s][(wn + r) * LSTR + q * 8]);
      short8 b1 = *reinterpret_cast<const short8*>(&Bs[s][(wn + 16 + r) * LSTR + q * 8]);
      acc[0][0] = __builtin_amdgcn_mfma_f32_16x16x32_bf16(a0, b0, acc[0][0], 0, 0, 0);
      acc[0][1] = __builtin_amdgcn_mfma_f32_16x16x32_bf16(a0, b1, acc[0][1], 0, 0, 0);
      acc[1][0] = __builtin_amdgcn_mfma_f32_16x16x32_bf16(a1, b0, acc[1][0], 0, 0, 0);
      acc[1][1] = __builtin_amdgcn_mfma_f32_16x16x32_bf16(a1, b1, acc[1][1], 0, 0, 0);
      if (kk < 15) {
        *reinterpret_cast<uint4*>(&As[s ^ 1][ldrow * LSTR + ldc]) = ra;
        *reinterpret_cast<uint4*>(&Bs[s ^ 1][ldrow * LSTR + ldc]) = rb;
        s ^= 1;
      }
      __syncthreads();
    }
#pragma unroll
    for (int mt = 0; mt < 2; ++mt)
#pragma unroll
      for (int nt = 0; nt < 2; ++nt)
#pragma unroll
        for (int e = 0; e < 4; ++e) {
          int row = m0 + wm + mt * 16 + q * 4 + e;
          int np = n0 + wn + nt * 16 + r;
          float v = acc[mt][nt][e] + bias2[np];
          if (np < 256) Mk[(size_t)(row * 33 + t) * 256 + np] = fmaxf(v, 0.f);
          else if (np >= 257 && np < 261) logits[row * 4 + (np - 257)] = v;
        }
  } else {
    if (t == 0 || t == 32) return;
    int b = bid - 40;
    float s = h[b * 512 + tid] * Wg[tid] + h[b * 512 + 256 + tid] * Wg[256 + tid];
    red[tid] = s;
    if (tid < t) wkS[tid] = wk_tbl[((size_t)b * 33 + t) * 33 + tid];
    __syncthreads();
    for (int off = 128; off > 0; off >>= 1) {
      if (tid < off) red[tid] += red[tid + off];
      __syncthreads();
    }
    float g = 1.f / (1.f + __expf(-(red[0] + bg[0])));
    float acc = 0.f;
    for (int n = 0; n < t; ++n) acc += wkS[n] * Mk[((size_t)b * 33 + n) * 256 + tid];
    xin_nxt[b * 800 + tid] = f2bf(g * acc);
    if (tid == 0) xin_nxt[b * 800 + 256] = f2bf(g * wck_tbl[b * 33 + t]);
  }
}

__global__ void k_softmax(const float* __restrict__ logits, float* __restrict__ out) {
  int tid = threadIdx.x;
  for (int r2 = tid; r2 < 512; r2 += 256) {
    float a = logits[r2 * 4], b = logits[r2 * 4 + 1], c = logits[r2 * 4 + 2], d = logits[r2 * 4 + 3];
    float m = fmaxf(fmaxf(a, b), fmaxf(c, d));
    float ea = __expf(a - m), eb = __expf(b - m), ec = __expf(c - m), ed = __expf(d - m);
    float s = ea + eb + ec + ed;
    out[r2 * 4] = ea / s; out[r2 * 4 + 1] = eb / s;
    out[r2 * 4 + 2] = ec / s; out[r2 * 4 + 3] = ed / s;
  }
}

extern "C" void kernel_launch(void* const* d_in, const int* in_sizes, int n_in,
                              void* d_out, int out_size, void* d_ws, size_t ws_size,
                              hipStream_t stream) {
  const float* x_seq = (const float*)d_in[0];
  const float* W_enc = (const float*)d_in[1];
  const float* b_enc = (const float*)d_in[2];
  const float* W_lstm = (const float*)d_in[3];
  const float* U_lstm = (const float*)d_in[4];
  const float* b_lstm = (const float*)d_in[5];
  const float* W_key = (const float*)d_in[6];
  const float* b_key = (const float*)d_in[7];
  const float* W_g = (const float*)d_in[8];
  const float* b_g = (const float*)d_in[9];
  const float* W_y = (const float*)d_in[10];
  const float* b_y = (const float*)d_in[11];
  const float* gamma = (const float*)d_in[12];
  const float* beta = (const float*)d_in[13];
  const float* cg_ = (const float*)d_in[14];
  const float* cb = (const float*)d_in[15];

  char* p = (char*)d_ws;
  auto alloc = [&](size_t bytes) {
    char* r = p;
    p += (bytes + 255) & ~(size_t)255;
    return r;
  };
  float* zbuf = (float*)alloc((size_t)16384 * 128 * 4);
  float* z_full = (float*)alloc((size_t)512 * 33 * 128 * 4);
  unsigned short* WcombT = (unsigned short*)alloc((size_t)2048 * 800 * 2);
  unsigned short* WencT = (unsigned short*)alloc((size_t)128 * 1024 * 2);
  unsigned short* Wk2T = (unsigned short*)alloc((size_t)320 * 512 * 2);
  float* bias2 = (float*)alloc(320 * 4);
  unsigned short* xinA = (unsigned short*)alloc((size_t)512 * 800 * 2);
  unsigned short* xinB = (unsigned short*)alloc((size_t)512 * 800 * 2);
  float* h = (float*)alloc((size_t)512 * 512 * 4);
  unsigned short* hbf = (unsigned short*)alloc((size_t)512 * 512 * 2);
  float* Mk = (float*)alloc((size_t)512 * 33 * 256 * 4);
  float* logits = (float*)alloc((size_t)512 * 4 * 4);
  float* wk_tbl = (float*)alloc((size_t)512 * 33 * 33 * 4);
  float* wck_tbl = (float*)alloc((size_t)512 * 33 * 4);
  unsigned* bar = (unsigned*)alloc(16384);
  float* outp = (float*)d_out;

  const int prep_total = 2048 * 800 + 320 * 512 + 128 * 1024 + 320 + 2 * 512 * 800 +
                         512 * 512 + 512 * 128 + 4096;
  k_prep<<<(prep_total + 255) / 256, 256, 0, stream>>>(
      W_lstm, U_lstm, W_enc, W_key, W_g, W_y, b_key, b_g, b_y,
      WcombT, Wk2T, WencT, bias2, xinA, xinB, h, z_full, bar);
  k_enc<<<256, 512, 0, stream>>>(x_seq, WencT, b_enc, zbuf);
  k_ln<<<256, 256, 0, stream>>>(zbuf, gamma, beta, z_full);
  k_attnpre<<<512, 256, 0, stream>>>(z_full, cg_, cb, wk_tbl, wck_tbl);

  void* cargs[16];
  cargs[0] = &xinA;  cargs[1] = &xinB;   cargs[2] = &WcombT; cargs[3] = &b_lstm;
  cargs[4] = &h;     cargs[5] = &hbf;    cargs[6] = &Wk2T;   cargs[7] = &bias2;
  cargs[8] = &Mk;    cargs[9] = &logits; cargs[10] = &W_g;   cargs[11] = &b_g;
  cargs[12] = &wk_tbl; cargs[13] = &wck_tbl; cargs[14] = &outp; cargs[15] = &bar;
  hipError_t ce = hipLaunchCooperativeKernel((const void*)k_loop, dim3(256), dim3(256),
                                             cargs, 0u, stream);
  if (ce != hipSuccess) {
    // fallback: per-step launches (previous verified path)
    for (int t = 0; t < 33; ++t) {
      unsigned short* cur = (t & 1) ? xinB : xinA;
      unsigned short* nxt = (t & 1) ? xinA : xinB;
      k_gates<<<dim3(32, 8), 256, 0, stream>>>(cur, WcombT, b_lstm, h, hbf, nxt);
      k_head<<<552, 256, 0, stream>>>(hbf, Wk2T, bias2, Mk, logits, h,
                                      W_g, b_g, wk_tbl, wck_tbl, nxt, t);
    }
    k_softmax<<<1, 256, 0, stream>>>(logits, outp);
  }
}

// Round 8
// 738.764 us; speedup vs baseline: 3.5040x; 1.0524x over previous
//
#include <hip/hip_runtime.h>

typedef __attribute__((ext_vector_type(8))) short short8;
typedef __attribute__((ext_vector_type(4))) float f32x4;
typedef __attribute__((ext_vector_type(8))) unsigned short ushort8;
typedef __attribute__((ext_vector_type(4))) unsigned short ushort4v;

__device__ __forceinline__ unsigned short f2bf(float f) {
  union { float f; unsigned u; } v; v.f = f;
  unsigned u = v.u;
  u += 0x7fffu + ((u >> 16) & 1u);
  return (unsigned short)(u >> 16);
}
__device__ __forceinline__ float sigm(float x) { return 1.f / (1.f + __expf(-x)); }
__device__ __forceinline__ float ftanh(float x) { return 1.f - 2.f / (__expf(2.f * x) + 1.f); }

// async global->LDS, 16B per lane. LDS dest must be WAVE-UNIFORM base; HW adds lane*16.
__device__ __forceinline__ void gl16(const unsigned short* g, unsigned short* l) {
  __builtin_amdgcn_global_load_lds((const __attribute__((address_space(1))) void*)g,
                                   (__attribute__((address_space(3))) void*)l, 16, 0, 0);
}

// ---- coherent (system-scope, performed at Infinity Cache) access helpers ----
__device__ __forceinline__ uint4 ld16_sys(const void* base, int off) {
  uint4 r;
  asm volatile("global_load_dwordx4 %0, %1, %2 sc0 sc1"
               : "=v"(r) : "v"(off), "s"(base) : "memory");
  return r;
}
__device__ __forceinline__ uint4 ld16_asm(const void* base, int off) {  // plain, asm-counted
  uint4 r;
  asm volatile("global_load_dwordx4 %0, %1, %2"
               : "=v"(r) : "v"(off), "s"(base) : "memory");
  return r;
}
__device__ __forceinline__ float ldf_sys(const void* base, int off) {
  float r;
  asm volatile("global_load_dword %0, %1, %2 sc0 sc1"
               : "=v"(r) : "v"(off), "s"(base) : "memory");
  return r;
}
__device__ __forceinline__ unsigned ldu_sys(const void* base, int off) {
  unsigned r;
  asm volatile("global_load_dword %0, %1, %2 sc0 sc1"
               : "=v"(r) : "v"(off), "s"(base) : "memory");
  return r;
}
__device__ __forceinline__ void stf_sys(void* base, int off, float v) {
  asm volatile("global_store_dword %0, %1, %2 sc0 sc1"
               :: "v"(off), "v"(v), "s"(base) : "memory");
}
__device__ __forceinline__ void stu_sys(void* base, int off, unsigned v) {
  asm volatile("global_store_dword %0, %1, %2 sc0 sc1"
               :: "v"(off), "v"(v), "s"(base) : "memory");
}
__device__ __forceinline__ void sth_sys(void* base, int off, unsigned short v) {
  asm volatile("global_store_short %0, %1, %2 sc0 sc1"
               :: "v"(off), "v"(v), "s"(base) : "memory");
}
#define WAITVM(N)                                          \
  asm volatile("s_waitcnt vmcnt(" #N ")" ::: "memory");    \
  __builtin_amdgcn_sched_barrier(0)

// Group barrier (32 blocks sharing mi): block stores gen into its own flag
// slot; each thread polls one of the group's 32 slots. Same mechanism as the
// proven round-6 grid barrier, scoped to the group (skew over 32, not 256).
__device__ __forceinline__ void gbar_grp(unsigned* flags, unsigned gen,
                                         int myslot, int pollslot) {
  asm volatile("s_waitcnt vmcnt(0)" ::: "memory");  // data stores acked at mall
  __syncthreads();
  if (threadIdx.x == 0) stu_sys(flags, myslot * 64, gen);
  int off = pollslot * 64;
  for (;;) {
    unsigned v = ldu_sys(flags, off);
    asm volatile("s_waitcnt vmcnt(0)" ::: "memory");
    if (v >= gen) break;
    __builtin_amdgcn_s_sleep(1);
  }
  __syncthreads();
}

#define LSTR 40  // LDS row stride (elems) for the prologue GEMM

// ---------------------------------------------------------------------------
// Prep: build bf16 transposed/permuted weights, zero state buffers + flags.
// ---------------------------------------------------------------------------
__global__ void k_prep(const float* __restrict__ W_lstm, const float* __restrict__ U_lstm,
                       const float* __restrict__ W_enc, const float* __restrict__ W_key,
                       const float* __restrict__ W_g, const float* __restrict__ W_y,
                       const float* __restrict__ b_key, const float* __restrict__ b_g,
                       const float* __restrict__ b_y,
                       unsigned short* __restrict__ WcombT, unsigned short* __restrict__ Wk2T,
                       unsigned short* __restrict__ WencT, float* __restrict__ bias2,
                       unsigned short* __restrict__ xinA, unsigned short* __restrict__ xinB,
                       float* __restrict__ h, float* __restrict__ z_full,
                       unsigned* __restrict__ bar) {
  const int N1 = 2048 * 800, N2 = 320 * 512, N3 = 128 * 1024, N4 = 320,
            N5 = 512 * 800, N7 = 512 * 512, N8 = 512 * 128, N9 = 4096;
  int i = blockIdx.x * 256 + threadIdx.x;
  if (i < N1) {
    int np = i / 800, k = i - np * 800;
    int j = np >> 2, gate = np & 3, n = gate * 512 + j;
    float v = 0.f;
    if (k < 257) v = W_lstm[k * 2048 + n];
    else if (k >= 288) v = U_lstm[(k - 288) * 2048 + n];
    WcombT[i] = f2bf(v);
    return;
  }
  i -= N1;
  if (i < N2) {
    int n = i / 512, k = i - n * 512;
    float v = 0.f;
    if (n < 256) v = W_key[k * 256 + n];
    else if (n == 256) v = W_g[k];
    else if (n < 261) v = W_y[k * 4 + (n - 257)];
    Wk2T[i] = f2bf(v);
    return;
  }
  i -= N2;
  if (i < N3) {
    int n = i / 1024, k = i - n * 1024;
    WencT[i] = f2bf(W_enc[k * 128 + n]);
    return;
  }
  i -= N3;
  if (i < N4) {
    float v = (i < 256) ? b_key[i] : (i == 256 ? b_g[0] : (i < 261 ? b_y[i - 257] : 0.f));
    bias2[i] = v;
    return;
  }
  i -= N4;
  if (i < N5) { xinA[i] = 0; return; }
  i -= N5;
  if (i < N5) { xinB[i] = 0; return; }
  i -= N5;
  if (i < N7) { h[i] = 0.f; return; }
  i -= N7;
  if (i < N8) {
    int b = i >> 7, z = i & 127;
    z_full[(b * 33 + 32) * 128 + z] = 0.f;  // null slot
    return;
  }
  i -= N8;
  if (i < N9) bar[i] = 0;
}

// ---------------------------------------------------------------------------
// Encoder GEMM (proven): 64Mx128N tile, BK=32, K=1024, 512 threads.
// ---------------------------------------------------------------------------
__global__ __launch_bounds__(512) void k_enc(const float* __restrict__ x,
                                             const unsigned short* __restrict__ WencT,
                                             const float* __restrict__ b_enc,
                                             float* __restrict__ zbuf) {
  __shared__ __align__(16) unsigned short As[2][64 * LSTR];
  __shared__ __align__(16) unsigned short Bs[2][128 * LSTR];
  int tid = threadIdx.x;
  int m0 = blockIdx.x * 64;
  int lane = tid & 63, wid = tid >> 6;
  int wm = (wid >> 2) * 32, wn = (wid & 3) * 32;
  int q = lane >> 4, r = lane & 15;
  int ldrowA = tid >> 3, ldcA = (tid & 7) * 4;
  int ldrowB = tid >> 2, ldcB = (tid & 3) * 8;
  const float4* Ag = reinterpret_cast<const float4*>(x + (size_t)(m0 + ldrowA) * 1024);
  const uint4* Bg = reinterpret_cast<const uint4*>(WencT + (size_t)ldrowB * 1024);
  float4 ra = Ag[ldcA >> 2];
  uint4 rb = Bg[ldcB >> 3];
  f32x4 acc[2][2] = {};
  int s = 0;
  {
    ushort4v t4;
    t4[0] = f2bf(ra.x); t4[1] = f2bf(ra.y); t4[2] = f2bf(ra.z); t4[3] = f2bf(ra.w);
    *reinterpret_cast<ushort4v*>(&As[0][ldrowA * LSTR + ldcA]) = t4;
    *reinterpret_cast<uint4*>(&Bs[0][ldrowB * LSTR + ldcB]) = rb;
  }
  __syncthreads();
  for (int kk = 0; kk < 32; ++kk) {
    if (kk < 31) {
      int k0 = (kk + 1) * 32;
      ra = Ag[(k0 + ldcA) >> 2];
      rb = Bg[(k0 + ldcB) >> 3];
    }
    short8 a0 = *reinterpret_cast<const short8*>(&As[s][(wm + r) * LSTR + q * 8]);
    short8 a1 = *reinterpret_cast<const short8*>(&As[s][(wm + 16 + r) * LSTR + q * 8]);
    short8 b0 = *reinterpret_cast<const short8*>(&Bs[s][(wn + r) * LSTR + q * 8]);
    short8 b1 = *reinterpret_cast<const short8*>(&Bs[s][(wn + 16 + r) * LSTR + q * 8]);
    acc[0][0] = __builtin_amdgcn_mfma_f32_16x16x32_bf16(a0, b0, acc[0][0], 0, 0, 0);
    acc[0][1] = __builtin_amdgcn_mfma_f32_16x16x32_bf16(a0, b1, acc[0][1], 0, 0, 0);
    acc[1][0] = __builtin_amdgcn_mfma_f32_16x16x32_bf16(a1, b0, acc[1][0], 0, 0, 0);
    acc[1][1] = __builtin_amdgcn_mfma_f32_16x16x32_bf16(a1, b1, acc[1][1], 0, 0, 0);
    if (kk < 31) {
      ushort4v t4;
      t4[0] = f2bf(ra.x); t4[1] = f2bf(ra.y); t4[2] = f2bf(ra.z); t4[3] = f2bf(ra.w);
      *reinterpret_cast<ushort4v*>(&As[s ^ 1][ldrowA * LSTR + ldcA]) = t4;
      *reinterpret_cast<uint4*>(&Bs[s ^ 1][ldrowB * LSTR + ldcB]) = rb;
      s ^= 1;
    }
    __syncthreads();
  }
#pragma unroll
  for (int mt = 0; mt < 2; ++mt)
#pragma unroll
    for (int nt = 0; nt < 2; ++nt)
#pragma unroll
      for (int e = 0; e < 4; ++e) {
        int row = m0 + wm + mt * 16 + q * 4 + e;
        int col = wn + nt * 16 + r;
        zbuf[(size_t)row * 128 + col] = fmaxf(acc[mt][nt][e] + b_enc[col], 0.f);
      }
}

// ---------------------------------------------------------------------------
// LayerNorm over the BATCH axis per (t,z).
// ---------------------------------------------------------------------------
__global__ __launch_bounds__(256) void k_ln(const float* __restrict__ zbuf,
                                            const float* __restrict__ gamma,
                                            const float* __restrict__ beta,
                                            float* __restrict__ z_full) {
  int bid = blockIdx.x;
  int tstep = bid >> 3;
  int z0 = (bid & 7) * 16;
  int tid = threadIdx.x;
  int zl = tid & 15, bg = tid >> 4;
  __shared__ float ps[256], qs[256];
  __shared__ float muS[16], rsS[16];
  float s = 0.f, ss = 0.f;
  for (int ii = 0; ii < 32; ++ii) {
    int b = bg * 32 + ii;
    float v = zbuf[(size_t)(b * 32 + tstep) * 128 + z0 + zl];
    s += v; ss += v * v;
  }
  ps[tid] = s; qs[tid] = ss;
  __syncthreads();
  if (tid < 16) {
    float S = 0.f, Q = 0.f;
    for (int g2 = 0; g2 < 16; ++g2) { S += ps[g2 * 16 + tid]; Q += qs[g2 * 16 + tid]; }
    float mu = S / 512.f;
    float var = Q / 512.f - mu * mu;
    muS[tid] = mu;
    rsS[tid] = rsqrtf(var + 1e-8f);
  }
  __syncthreads();
  float ga = gamma[z0 + zl], be = beta[z0 + zl];
  float mu = muS[zl], rs = rsS[zl];
  for (int ii = 0; ii < 32; ++ii) {
    int b = bg * 32 + ii;
    float v = zbuf[(size_t)(b * 32 + tstep) * 128 + z0 + zl];
    z_full[(size_t)(b * 33 + tstep) * 128 + z0 + zl] = (v - mu) * rs * ga + be;
  }
}

// ---------------------------------------------------------------------------
// Attention precompute (w_k and wck for all t, once).
// ---------------------------------------------------------------------------
__global__ __launch_bounds__(256) void k_attnpre(const float* __restrict__ z_full,
                                                 const float* __restrict__ cgain,
                                                 const float* __restrict__ cbias,
                                                 float* __restrict__ wk_tbl,
                                                 float* __restrict__ wck_tbl) {
  __shared__ float zs[33 * 128];
  __shared__ float sim[33 * 33];
  int b = blockIdx.x, tid = threadIdx.x;
  const float* zb = z_full + (size_t)b * 33 * 128;
  for (int i = tid; i < 33 * 128; i += 256) zs[i] = zb[i];
  __syncthreads();
  for (int p = tid; p < 33 * 33; p += 256) {
    int t = p / 33, n = p - t * 33;
    float s = 0.f;
    if (n < t) {
#pragma unroll 8
      for (int k2 = 0; k2 < 128; ++k2) s += zs[t * 128 + k2] * zs[n * 128 + k2];
    }
    sim[p] = s;
  }
  __syncthreads();
  if (tid >= 1 && tid < 33) {
    int t = tid;
    float cg = cgain[0], cb2 = cbias[0];
    float m = -3.0e38f;
    for (int n = 0; n < t; ++n) m = fmaxf(m, sim[t * 33 + n]);
    float ssum = 0.f;
    for (int n = 0; n < t; ++n) ssum += __expf(sim[t * 33 + n] - m);
    float inv = 1.f / ssum;
    float wck = 0.f;
    for (int n = 0; n < t; ++n) {
      float wk = __expf(sim[t * 33 + n] - m) * inv;
      wk_tbl[((size_t)b * 33 + t) * 33 + n] = wk;
      float ck = 1.f / (1.f + __expf(-(sim[t * 33 + n] * cg + cb2)));
      wck += wk * ck;
    }
    wck_tbl[b * 33 + t] = wck;
  }
}

// ---------------------------------------------------------------------------
// Persistent kernel: round-6-proven phases; ONE structural change — the
// recurrence decomposes into 8 independent 64-batch groups (mi), so the grid
// barrier becomes a 32-block GROUP barrier and phase B is remapped in-group:
//   nn=0..4: head tiles (m0b=g*64); nn=4 does the t=32 softmax block-locally.
//   nn=5..31: attention reads for the group's 64 batches (3 each).
// ---------------------------------------------------------------------------
__global__ __launch_bounds__(256) void k_loop(
    unsigned short* __restrict__ xinA, unsigned short* __restrict__ xinB,
    const unsigned short* __restrict__ WT, const float* __restrict__ b_lstm,
    float* __restrict__ h, unsigned short* __restrict__ hbf,
    const unsigned short* __restrict__ Wk2T, const float* __restrict__ bias2,
    float* __restrict__ Mk, const float* __restrict__ Wg,
    const float* __restrict__ bg, const float* __restrict__ wk_tbl,
    const float* __restrict__ wck_tbl, float* __restrict__ out,
    unsigned* __restrict__ bar) {
  __shared__ __align__(16) unsigned short Bres[64 * 808];  // 103424 B, resident
  __shared__ __align__(16) unsigned char scr[43136];       // A0/A1, Cs, wkS/ylds
  const int tid = threadIdx.x, bid = blockIdx.x;
  const int lane = tid & 63, w = tid >> 6;
  const int q = lane >> 4, r = lane & 15;
  const int wm = (w >> 1) * 32, wn = (w & 1) * 32;
  const int nn = bid & 31, g = bid >> 5;  // group g owns batches g*64..g*64+63
  const int m0 = g * 64, n0g = nn * 64;
  const int pollslot = (g << 5) + (tid & 31);
  unsigned gen = 0;

  // ---- pin B slice (static): 64 rows x 808 (800 data + 8 pad), via gl16 with
  // wave-uniform LDS base + per-lane pre-swizzled global source. 6464 granules.
  for (int l = 0; l < 26; ++l) {
    int gw = l * 256 + w * 64;  // wave-uniform granule base
    if (gw < 6464) {
      int gg = gw + lane;
      int row = gg / 101, cg = gg - row * 101;
      int col = (cg >= 100) ? 792 : cg * 8;  // pad granule: load junk (unread)
      gl16(WT + (size_t)(n0g + row) * 800 + col, Bres + gw * 8);
    }
  }

  // per-thread A-stage coords: 1280 data granules = 5 x 256 (row-major 64x160)
  int srow[5], scol[5];
#pragma unroll
  for (int l = 0; l < 5; ++l) {
    int idx = l * 256 + tid;
    srow[l] = idx / 20;
    scol[l] = (idx - srow[l] * 20) * 8;
  }
  unsigned short* A0 = (unsigned short*)scr;             // 64*168*2 = 21504 B
  unsigned short* A1 = (unsigned short*)(scr + 21504);   // 21504 B

  const int jl = tid & 15, jg = nn * 16 + jl, rl0 = tid >> 4;
  const float bL0 = b_lstm[jg], bL1 = b_lstm[512 + jg],
              bL2 = b_lstm[1024 + jg], bL3 = b_lstm[1536 + jg];
  float hreg[4] = {0.f, 0.f, 0.f, 0.f};

  asm volatile("s_waitcnt vmcnt(0)" ::: "memory");
  __syncthreads();

  for (int t = 0; t < 33; ++t) {
    const unsigned short* cur = (t & 1) ? xinB : xinA;
    unsigned short* nxt = (t & 1) ? xinA : xinB;

    // ====== phase A: gates GEMM (64x64, K=800=5x160) + LSTM cell =============
    uint4 R[5];
#pragma unroll
    for (int l = 0; l < 5; ++l)  // prologue: chunk 0 (coherent: xin is remote-written)
      R[l] = ld16_sys(cur, ((m0 + srow[l]) * 800 + scol[l]) * 2);
    asm volatile("s_waitcnt vmcnt(0)" ::: "memory");
    __builtin_amdgcn_sched_barrier(0);
#pragma unroll
    for (int l = 0; l < 5; ++l)
      *(uint4*)&A0[srow[l] * 168 + scol[l]] = R[l];
    __syncthreads();

    f32x4 acc[2][2] = {};
    for (int c = 0; c < 5; ++c) {
      const unsigned short* Ac = (c & 1) ? A1 : A0;
      unsigned short* An = (c & 1) ? A0 : A1;
      if (c < 4) {
#pragma unroll
        for (int l = 0; l < 5; ++l)
          R[l] = ld16_sys(cur, ((m0 + srow[l]) * 800 + (c + 1) * 160 + scol[l]) * 2);
      }
#pragma unroll
      for (int ks = 0; ks < 5; ++ks) {
        short8 a0 = *(const short8*)&Ac[(wm + r) * 168 + ks * 32 + q * 8];
        short8 a1 = *(const short8*)&Ac[(wm + 16 + r) * 168 + ks * 32 + q * 8];
        short8 b0 = *(const short8*)&Bres[(wn + r) * 808 + c * 160 + ks * 32 + q * 8];
        short8 b1 = *(const short8*)&Bres[(wn + 16 + r) * 808 + c * 160 + ks * 32 + q * 8];
        acc[0][0] = __builtin_amdgcn_mfma_f32_16x16x32_bf16(a0, b0, acc[0][0], 0, 0, 0);
        acc[0][1] = __builtin_amdgcn_mfma_f32_16x16x32_bf16(a0, b1, acc[0][1], 0, 0, 0);
        acc[1][0] = __builtin_amdgcn_mfma_f32_16x16x32_bf16(a1, b0, acc[1][0], 0, 0, 0);
        acc[1][1] = __builtin_amdgcn_mfma_f32_16x16x32_bf16(a1, b1, acc[1][1], 0, 0, 0);
      }
      if (c < 4) {
        asm volatile("s_waitcnt vmcnt(0)" ::: "memory");
        __builtin_amdgcn_sched_barrier(0);
#pragma unroll
        for (int l = 0; l < 5; ++l)
          *(uint4*)&An[srow[l] * 168 + scol[l]] = R[l];
        __syncthreads();
      }
    }
    __syncthreads();  // drain last buffer reads before Cs overwrites A0

    // ---- fused LSTM cell (h-carry in registers; coherent stores) ----
    float* Cs = (float*)scr;
#pragma unroll
    for (int mt = 0; mt < 2; ++mt)
#pragma unroll
      for (int nt = 0; nt < 2; ++nt)
#pragma unroll
        for (int e = 0; e < 4; ++e)
          Cs[(wm + mt * 16 + q * 4 + e) * 65 + wn + nt * 16 + r] = acc[mt][nt][e];
    __syncthreads();
#pragma unroll
    for (int it = 0; it < 4; ++it) {
      int rl = it * 16 + rl0;
      int brow = m0 + rl;
      float gi = Cs[rl * 65 + jl * 4 + 0] + bL0;
      float gf = Cs[rl * 65 + jl * 4 + 1] + bL1;
      float gc = Cs[rl * 65 + jl * 4 + 2] + bL2;
      float go = Cs[rl * 65 + jl * 4 + 3] + bL3;
      float cnew = sigm(gf) * hreg[it] + sigm(gi) * ftanh(gc);
      float hnew = sigm(go) * ftanh(cnew);
      hreg[it] = hnew;
      stf_sys(h, (brow * 512 + jg) * 4, hnew);
      sth_sys(hbf, (brow * 512 + jg) * 2, f2bf(hnew));
      sth_sys(nxt, (brow * 800 + 288 + jg) * 2, f2bf(cnew));
    }
    ++gen; gbar_grp(bar, gen, bid, pollslot);

    // ====== phase B (in-group) ==============================================
    if (nn < 5) {
      if (nn < 4 || t == 32) {
        // head GEMM 64x64, K=512: LDS-free, depth-3 reg pipeline, counted vmcnt.
        int m0b = g * 64, n0b = nn * 64;
        int aoff0 = ((m0b + wm + r) * 512 + q * 8) * 2;
        int aoff1 = aoff0 + 16 * 1024;
        int boff0 = ((n0b + wn + r) * 512 + q * 8) * 2;
        int boff1 = boff0 + 16 * 1024;
        uint4 ab[4][2], bb[4][2];
        f32x4 acc2[2][2] = {};
#pragma unroll
        for (int j = 0; j < 3; ++j) {
          ab[j][0] = ld16_sys(hbf, aoff0 + j * 64);   // hbf: remote-written -> sc1
          ab[j][1] = ld16_sys(hbf, aoff1 + j * 64);
          bb[j][0] = ld16_asm(Wk2T, boff0 + j * 64);  // Wk2T: static -> plain (L2)
          bb[j][1] = ld16_asm(Wk2T, boff1 + j * 64);
        }
#pragma unroll
        for (int kk = 0; kk < 16; ++kk) {
          if (kk < 13) {
            int j = kk + 3;
            ab[j & 3][0] = ld16_sys(hbf, aoff0 + j * 64);
            ab[j & 3][1] = ld16_sys(hbf, aoff1 + j * 64);
            bb[j & 3][0] = ld16_asm(Wk2T, boff0 + j * 64);
            bb[j & 3][1] = ld16_asm(Wk2T, boff1 + j * 64);
          }
          if (kk < 13) { WAITVM(12); }
          else if (kk == 13) { WAITVM(8); }
          else if (kk == 14) { WAITVM(4); }
          else { WAITVM(0); }
          short8 a0 = *(const short8*)&ab[kk & 3][0];
          short8 a1 = *(const short8*)&ab[kk & 3][1];
          short8 b0s = *(const short8*)&bb[kk & 3][0];
          short8 b1s = *(const short8*)&bb[kk & 3][1];
          acc2[0][0] = __builtin_amdgcn_mfma_f32_16x16x32_bf16(a0, b0s, acc2[0][0], 0, 0, 0);
          acc2[0][1] = __builtin_amdgcn_mfma_f32_16x16x32_bf16(a0, b1s, acc2[0][1], 0, 0, 0);
          acc2[1][0] = __builtin_amdgcn_mfma_f32_16x16x32_bf16(a1, b0s, acc2[1][0], 0, 0, 0);
          acc2[1][1] = __builtin_amdgcn_mfma_f32_16x16x32_bf16(a1, b1s, acc2[1][1], 0, 0, 0);
        }
        if (nn < 4) {
          if (t < 32) {
#pragma unroll
            for (int mt = 0; mt < 2; ++mt)
#pragma unroll
              for (int nt = 0; nt < 2; ++nt)
#pragma unroll
                for (int e2 = 0; e2 < 4; ++e2) {
                  int row = m0b + wm + mt * 16 + q * 4 + e2;
                  int np = n0b + wn + nt * 16 + r;
                  stf_sys(Mk, ((row * 33 + t) * 256 + np) * 4,
                          fmaxf(acc2[mt][nt][e2] + bias2[np], 0.f));
                }
          }
        } else {
          // nn==4, t==32: logits (np 257..260) -> block-local softmax -> out
          float* ylds = (float*)scr;
#pragma unroll
          for (int mt = 0; mt < 2; ++mt)
#pragma unroll
            for (int nt = 0; nt < 2; ++nt)
#pragma unroll
              for (int e2 = 0; e2 < 4; ++e2) {
                int rowl = wm + mt * 16 + q * 4 + e2;
                int np = n0b + wn + nt * 16 + r;
                if (np >= 257 && np < 261)
                  ylds[rowl * 4 + (np - 257)] = acc2[mt][nt][e2] + bias2[np];
              }
          __syncthreads();
          if (tid < 64) {
            float a = ylds[tid * 4], b2 = ylds[tid * 4 + 1],
                  c2 = ylds[tid * 4 + 2], d2 = ylds[tid * 4 + 3];
            float m = fmaxf(fmaxf(a, b2), fmaxf(c2, d2));
            float ea = __expf(a - m), eb = __expf(b2 - m),
                  ec = __expf(c2 - m), ed = __expf(d2 - m);
            float inv = 1.f / (ea + eb + ec + ed);
            int row = m0b + tid;
            out[row * 4] = ea * inv; out[row * 4 + 1] = eb * inv;
            out[row * 4 + 2] = ec * inv; out[row * 4 + 3] = ed * inv;
          }
        }
      }
    } else if (t > 0 && t < 32) {
      // attention read (group batches): g gate + sum_{n<t} wk*Mk -> key_r(t+1)
      float* wkS = (float*)scr;
      float* red4 = (float*)(scr + 512);
      for (int rr = 0; rr < 3; ++rr) {
        int idx = (nn - 5) + 27 * rr;
        if (idx < 64) {
          int b = m0 + idx;
          float ha = ldf_sys(h, (b * 512 + tid) * 4);
          float hb = ldf_sys(h, (b * 512 + 256 + tid) * 4);
          asm volatile("s_waitcnt vmcnt(0)" ::: "memory");
          float sd = ha * Wg[tid] + hb * Wg[256 + tid];
#pragma unroll
          for (int off = 32; off > 0; off >>= 1) sd += __shfl_down(sd, off);
          if (lane == 0) red4[w] = sd;
          if (tid < t) wkS[tid] = wk_tbl[((size_t)b * 33 + t) * 33 + tid];
          __syncthreads();
          float gv = 1.f / (1.f + __expf(-(red4[0] + red4[1] + red4[2] + red4[3] + bg[0])));
          float p0 = 0.f, p1 = 0.f, p2 = 0.f, p3 = 0.f;
          int n = 0;
          for (; n + 4 <= t; n += 4) {
            p0 += wkS[n] * Mk[((size_t)b * 33 + n) * 256 + tid];
            p1 += wkS[n + 1] * Mk[((size_t)b * 33 + n + 1) * 256 + tid];
            p2 += wkS[n + 2] * Mk[((size_t)b * 33 + n + 2) * 256 + tid];
            p3 += wkS[n + 3] * Mk[((size_t)b * 33 + n + 3) * 256 + tid];
          }
          for (; n < t; ++n) p0 += wkS[n] * Mk[((size_t)b * 33 + n) * 256 + tid];
          sth_sys(nxt, (b * 800 + tid) * 2, f2bf(gv * ((p0 + p1) + (p2 + p3))));
          if (tid == 0) sth_sys(nxt, (b * 800 + 256) * 2, f2bf(gv * wck_tbl[b * 33 + t]));
          __syncthreads();
        }
      }
    }
    if (t < 32) { ++gen; gbar_grp(bar, gen, bid, pollslot); }
  }
}

// ---------------------------------------------------------------------------
// Fallback per-step kernels (used only if cooperative-style launch fails).
// ---------------------------------------------------------------------------
__global__ __launch_bounds__(256) void k_gates(const unsigned short* __restrict__ xin,
                                               const unsigned short* __restrict__ WT,
                                               const float* __restrict__ b_lstm,
                                               float* __restrict__ h,
                                               unsigned short* __restrict__ hbf,
                                               unsigned short* __restrict__ xin_nxt) {
  __shared__ __align__(16) unsigned short As[2][64 * LSTR];
  __shared__ __align__(16) unsigned short Bs[2][64 * LSTR];
  __shared__ float Cs[64 * 65];
  int tid = threadIdx.x;
  int nn = blockIdx.x;
  int m0 = blockIdx.y * 64;
  int n0 = nn * 64;
  int lane = tid & 63, wid = tid >> 6;
  int wm = (wid >> 1) * 32, wn = (wid & 1) * 32;
  int q = lane >> 4, r = lane & 15;
  int ldrow = tid >> 2, ldc = (tid & 3) * 8;
  const uint4* Ag = reinterpret_cast<const uint4*>(xin + (size_t)(m0 + ldrow) * 800);
  const uint4* Bg = reinterpret_cast<const uint4*>(WT + (size_t)(n0 + ldrow) * 800);
  uint4 ra = Ag[ldc >> 3], rb = Bg[ldc >> 3];
  f32x4 acc[2][2] = {};
  int s = 0;
  *reinterpret_cast<uint4*>(&As[0][ldrow * LSTR + ldc]) = ra;
  *reinterpret_cast<uint4*>(&Bs[0][ldrow * LSTR + ldc]) = rb;
  __syncthreads();
  for (int kk = 0; kk < 25; ++kk) {
    if (kk < 24) {
      int k0 = (kk + 1) * 32;
      ra = Ag[(k0 + ldc) >> 3];
      rb = Bg[(k0 + ldc) >> 3];
    }
    short8 a0 = *reinterpret_cast<const short8*>(&As[s][(wm + r) * LSTR + q * 8]);
    short8 a1 = *reinterpret_cast<const short8*>(&As[s][(wm + 16 + r) * LSTR + q * 8]);
    short8 b0 = *reinterpret_cast<const short8*>(&Bs[s][(wn + r) * LSTR + q * 8]);
    short8 b1 = *reinterpret_cast<const short8*>(&Bs[s][(wn + 16 + r) * LSTR + q * 8]);
    acc[0][0] = __builtin_amdgcn_mfma_f32_16x16x32_bf16(a0, b0, acc[0][0], 0, 0, 0);
    acc[0][1] = __builtin_amdgcn_mfma_f32_16x16x32_bf16(a0, b1, acc[0][1], 0, 0, 0);
    acc[1][0] = __builtin_amdgcn_mfma_f32_16x16x32_bf16(a1, b0, acc[1][0], 0, 0, 0);
    acc[1][1] = __builtin_amdgcn_mfma_f32_16x16x32_bf16(a1, b1, acc[1][1], 0, 0, 0);
    if (kk < 24) {
      *reinterpret_cast<uint4*>(&As[s ^ 1][ldrow * LSTR + ldc]) = ra;
      *reinterpret_cast<uint4*>(&Bs[s ^ 1][ldrow * LSTR + ldc]) = rb;
      s ^= 1;
    }
    __syncthreads();
  }
#pragma unroll
  for (int mt = 0; mt < 2; ++mt)
#pragma unroll
    for (int nt = 0; nt < 2; ++nt)
#pragma unroll
      for (int e = 0; e < 4; ++e)
        Cs[(wm + mt * 16 + q * 4 + e) * 65 + wn + nt * 16 + r] = acc[mt][nt][e];
  __syncthreads();
#pragma unroll
  for (int it = 0; it < 4; ++it) {
    int id = it * 256 + tid;
    int rl = id >> 4, jl = id & 15;
    int brow = m0 + rl;
    int j = nn * 16 + jl;
    float gi = Cs[rl * 65 + jl * 4 + 0] + b_lstm[j];
    float gf = Cs[rl * 65 + jl * 4 + 1] + b_lstm[512 + j];
    float gg = Cs[rl * 65 + jl * 4 + 2] + b_lstm[1024 + j];
    float go = Cs[rl * 65 + jl * 4 + 3] + b_lstm[1536 + j];
    float hold = h[brow * 512 + j];
    float cnew = sigm(gf) * hold + sigm(gi) * ftanh(gg);
    float hnew = sigm(go) * ftanh(cnew);
    h[brow * 512 + j] = hnew;
    hbf[brow * 512 + j] = f2bf(hnew);
    xin_nxt[brow * 800 + 288 + j] = f2bf(cnew);
  }
}

__global__ __launch_bounds__(256) void k_head(const unsigned short* __restrict__ hbf,
                                              const unsigned short* __restrict__ Wk2T,
                                              const float* __restrict__ bias2,
                                              float* __restrict__ Mk,
                                              float* __restrict__ logits,
                                              const float* __restrict__ h,
                                              const float* __restrict__ Wg,
                                              const float* __restrict__ bg,
                                              const float* __restrict__ wk_tbl,
                                              const float* __restrict__ wck_tbl,
                                              unsigned short* __restrict__ xin_nxt,
                                              int t) {
  __shared__ __align__(16) unsigned short As[2][64 * LSTR];
  __shared__ __align__(16) unsigned short Bs[2][64 * LSTR];
  __shared__ float wkS[33];
  __shared__ float red[256];
  int bid = blockIdx.x;
  int tid = threadIdx.x;
  if (bid < 40) {
    int mi = bid / 5, ni = bid - mi * 5;
    int m0 = mi * 64, n0 = ni * 64;
    int lane = tid & 63, wid = tid >> 6;
    int wm = (wid >> 1) * 32, wn = (wid & 1) * 32;
    int q = lane >> 4, r = lane & 15;
    int ldrow = tid >> 2, ldc = (tid & 3) * 8;
    const uint4* Ag = reinterpret_cast<const uint4*>(hbf + (size_t)(m0 + ldrow) * 512);
    const uint4* Bg = reinterpret_cast<const uint4*>(Wk2T + (size_t)(n0 + ldrow) * 512);
    uint4 ra = Ag[ldc >> 3], rb = Bg[ldc >> 3];
    f32x4 acc[2][2] = {};
    int s = 0;
    *reinterpret_cast<uint4*>(&As[0][ldrow * LSTR + ldc]) = ra;
    *reinterpret_cast<uint4*>(&Bs[0][ldrow * LSTR + ldc]) = rb;
    __syncthreads();
    for (int kk = 0; kk < 16; ++kk) {
      if (kk < 15) {
        int k0 = (kk + 1) * 32;
        ra = Ag[(k0 + ldc) >> 3];
        rb = Bg[(k0 + ldc) >> 3];
      }
      short8 a0 = *reinterpret_cast<const short8*>(&As[s][(wm + r) * LSTR + q * 8]);
      short8 a1 = *reinterpret_cast<const short8*>(&As[s][(wm + 16 + r) * LSTR + q * 8]);
      short8 b0 = *reinterpret_cast<const short8*>(&Bs[s][(wn + r) * LSTR + q * 8]);
      short8 b1 = *reinterpret_cast<const short8*>(&Bs[s][(wn + 16 + r) * LSTR + q * 8]);
      acc[0][0] = __builtin_amdgcn_mfma_f32_16x16x32_bf16(a0, b0, acc[0][0], 0, 0, 0);
      acc[0][1] = __builtin_amdgcn_mfma_f32_16x16x32_bf16(a0, b1, acc[0][1], 0, 0, 0);
      acc[1][0] = __builtin_amdgcn_mfma_f32_16x16x32_bf16(a1, b0, acc[1][0], 0, 0, 0);
      acc[1][1] = __builtin_amdgcn_mfma_f32_16x16x32_bf16(a1, b1, acc[1][1], 0, 0, 0);
      if (kk < 15) {
        *reinterpret_cast<uint4*>(&As[s ^ 1][ldrow * LSTR + ldc]) = ra;
        *reinterpret_cast<uint4*>(&Bs[s ^ 1][ldrow * LSTR + ldc]) = rb;
        s ^= 1;
      }
      __syncthreads();
    }
#pragma unroll
    for (int mt = 0; mt < 2; ++mt)
#pragma unroll
      for (int nt = 0; nt < 2; ++nt)
#pragma unroll
        for (int e = 0; e < 4; ++e) {
          int row = m0 + wm + mt * 16 + q * 4 + e;
          int np = n0 + wn + nt * 16 + r;
          float v = acc[mt][nt][e] + bias2[np];
          if (np < 256) Mk[(size_t)(row * 33 + t) * 256 + np] = fmaxf(v, 0.f);
          else if (np >= 257 && np < 261) logits[row * 4 + (np - 257)] = v;
        }
  } else {
    if (t == 0 || t == 32) return;
    int b = bid - 40;
    float s = h[b * 512 + tid] * Wg[tid] + h[b * 512 + 256 + tid] * Wg[256 + tid];
    red[tid] = s;
    if (tid < t) wkS[tid] = wk_tbl[((size_t)b * 33 + t) * 33 + tid];
    __syncthreads();
    for (int off = 128; off > 0; off >>= 1) {
      if (tid < off) red[tid] += red[tid + off];
      __syncthreads();
    }
    float g = 1.f / (1.f + __expf(-(red[0] + bg[0])));
    float acc = 0.f;
    for (int n = 0; n < t; ++n) acc += wkS[n] * Mk[((size_t)b * 33 + n) * 256 + tid];
    xin_nxt[b * 800 + tid] = f2bf(g * acc);
    if (tid == 0) xin_nxt[b * 800 + 256] = f2bf(g * wck_tbl[b * 33 + t]);
  }
}

__global__ void k_softmax(const float* __restrict__ logits, float* __restrict__ out) {
  int tid = threadIdx.x;
  for (int r2 = tid; r2 < 512; r2 += 256) {
    float a = logits[r2 * 4], b = logits[r2 * 4 + 1], c = logits[r2 * 4 + 2], d = logits[r2 * 4 + 3];
    float m = fmaxf(fmaxf(a, b), fmaxf(c, d));
    float ea = __expf(a - m), eb = __expf(b - m), ec = __expf(c - m), ed = __expf(d - m);
    float s = ea + eb + ec + ed;
    out[r2 * 4] = ea / s; out[r2 * 4 + 1] = eb / s;
    out[r2 * 4 + 2] = ec / s; out[r2 * 4 + 3] = ed / s;
  }
}

extern "C" void kernel_launch(void* const* d_in, const int* in_sizes, int n_in,
                              void* d_out, int out_size, void* d_ws, size_t ws_size,
                              hipStream_t stream) {
  const float* x_seq = (const float*)d_in[0];
  const float* W_enc = (const float*)d_in[1];
  const float* b_enc = (const float*)d_in[2];
  const float* W_lstm = (const float*)d_in[3];
  const float* U_lstm = (const float*)d_in[4];
  const float* b_lstm = (const float*)d_in[5];
  const float* W_key = (const float*)d_in[6];
  const float* b_key = (const float*)d_in[7];
  const float* W_g = (const float*)d_in[8];
  const float* b_g = (const float*)d_in[9];
  const float* W_y = (const float*)d_in[10];
  const float* b_y = (const float*)d_in[11];
  const float* gamma = (const float*)d_in[12];
  const float* beta = (const float*)d_in[13];
  const float* cg_ = (const float*)d_in[14];
  const float* cb = (const float*)d_in[15];

  char* p = (char*)d_ws;
  auto alloc = [&](size_t bytes) {
    char* r = p;
    p += (bytes + 255) & ~(size_t)255;
    return r;
  };
  float* zbuf = (float*)alloc((size_t)16384 * 128 * 4);
  float* z_full = (float*)alloc((size_t)512 * 33 * 128 * 4);
  unsigned short* WcombT = (unsigned short*)alloc((size_t)2048 * 800 * 2);
  unsigned short* WencT = (unsigned short*)alloc((size_t)128 * 1024 * 2);
  unsigned short* Wk2T = (unsigned short*)alloc((size_t)320 * 512 * 2);
  float* bias2 = (float*)alloc(320 * 4);
  unsigned short* xinA = (unsigned short*)alloc((size_t)512 * 800 * 2);
  unsigned short* xinB = (unsigned short*)alloc((size_t)512 * 800 * 2);
  float* h = (float*)alloc((size_t)512 * 512 * 4);
  unsigned short* hbf = (unsigned short*)alloc((size_t)512 * 512 * 2);
  float* Mk = (float*)alloc((size_t)512 * 33 * 256 * 4);
  float* logits = (float*)alloc((size_t)512 * 4 * 4);
  float* wk_tbl = (float*)alloc((size_t)512 * 33 * 33 * 4);
  float* wck_tbl = (float*)alloc((size_t)512 * 33 * 4);
  unsigned* bar = (unsigned*)alloc(16384);
  float* outp = (float*)d_out;

  const int prep_total = 2048 * 800 + 320 * 512 + 128 * 1024 + 320 + 2 * 512 * 800 +
                         512 * 512 + 512 * 128 + 4096;
  k_prep<<<(prep_total + 255) / 256, 256, 0, stream>>>(
      W_lstm, U_lstm, W_enc, W_key, W_g, W_y, b_key, b_g, b_y,
      WcombT, Wk2T, WencT, bias2, xinA, xinB, h, z_full, bar);
  k_enc<<<256, 512, 0, stream>>>(x_seq, WencT, b_enc, zbuf);
  k_ln<<<256, 256, 0, stream>>>(zbuf, gamma, beta, z_full);
  k_attnpre<<<512, 256, 0, stream>>>(z_full, cg_, cb, wk_tbl, wck_tbl);

  void* cargs[15];
  cargs[0] = &xinA;  cargs[1] = &xinB;   cargs[2] = &WcombT; cargs[3] = &b_lstm;
  cargs[4] = &h;     cargs[5] = &hbf;    cargs[6] = &Wk2T;   cargs[7] = &bias2;
  cargs[8] = &Mk;    cargs[9] = &W_g;    cargs[10] = &b_g;   cargs[11] = &wk_tbl;
  cargs[12] = &wck_tbl; cargs[13] = &outp; cargs[14] = &bar;
  hipError_t ce = hipLaunchCooperativeKernel((const void*)k_loop, dim3(256), dim3(256),
                                             cargs, 0u, stream);
  if (ce != hipSuccess) {
    // fallback: per-step launches (previous verified path)
    for (int t = 0; t < 33; ++t) {
      unsigned short* cur = (t & 1) ? xinB : xinA;
      unsigned short* nxt = (t & 1) ? xinA : xinB;
      k_gates<<<dim3(32, 8), 256, 0, stream>>>(cur, WcombT, b_lstm, h, hbf, nxt);
      k_head<<<552, 256, 0, stream>>>(hbf, Wk2T, bias2, Mk, logits, h,
                                      W_g, b_g, wk_tbl, wck_tbl, nxt, t);
    }
    k_softmax<<<1, 256, 0, stream>>>(logits, outp);
  }
}